// Round 5
// baseline (18667.795 us; speedup 1.0000x reference)
//
#include <hip/hip_runtime.h>
#include <hip/hip_bf16.h>
#include <stdint.h>

#define BN 8192
#define TT 128
#define II 64
#define HH 256
#define GG 768
#define KK 12
#define KM_ITERS_N 25
#define UB 64
#define UPB (BN/UB)

// ---------------- threefry2x32 (JAX-exact) ----------------
__device__ __forceinline__ uint32_t rotl32(uint32_t v, int d) {
  return (v << d) | (v >> (32 - d));
}
__device__ __forceinline__ void tf2x32(uint32_t k0, uint32_t k1,
                                       uint32_t x0, uint32_t x1,
                                       uint32_t& o0, uint32_t& o1) {
  uint32_t ks2 = k0 ^ k1 ^ 0x1BD11BDAu;
  x0 += k0; x1 += k1;
#define TFR(r) { x0 += x1; x1 = rotl32(x1, r); x1 ^= x0; }
  TFR(13); TFR(15); TFR(26); TFR(6);   x0 += k1;  x1 += ks2 + 1u;
  TFR(17); TFR(29); TFR(16); TFR(24);  x0 += ks2; x1 += k0 + 2u;
  TFR(13); TFR(15); TFR(26); TFR(6);   x0 += k0;  x1 += k1 + 3u;
  TFR(17); TFR(29); TFR(16); TFR(24);  x0 += k1;  x1 += ks2 + 4u;
  TFR(13); TFR(15); TFR(26); TFR(6);   x0 += ks2; x1 += k0 + 5u;
#undef TFR
  o0 = x0; o1 = x1;
}
__device__ __forceinline__ float bits_to_unit(uint32_t bits) {
  uint32_t u = (bits >> 9) | 0x3f800000u;
  return __uint_as_float(u) - 1.0f;
}

// ---------------- zero ----------------
__global__ void k_zero(float* p, int n) {
  int i = blockIdx.x * blockDim.x + threadIdx.x;
  if (i < n) p[i] = 0.f;
}

// ---------------- simple NT GEMM: C[m,n] = sum_k A[m, aoff+k] * B[n, k] ----------------
#define GM 64
#define GN 64
#define GK 16
__global__ __launch_bounds__(256) void k_mm_nt(const float* __restrict__ A, int lda, int aoff,
                                               const float* __restrict__ Bm,
                                               float* __restrict__ C, int N, int Ktot) {
  __shared__ float As[GM][GK + 1];
  __shared__ float Bs[GN][GK + 1];
  const int tx = threadIdx.x, ty = threadIdx.y;    // 16 x 16
  const int row0 = blockIdx.x * GM, col0 = blockIdx.y * GN;
  const int tflat = ty * 16 + tx;
  float acc[4][4] = {};
  for (int k0 = 0; k0 < Ktot; k0 += GK) {
    for (int l = tflat; l < GM * GK; l += 256) {
      int r = l / GK, kk = l % GK;
      As[r][kk] = A[(size_t)(row0 + r) * lda + aoff + k0 + kk];
    }
    for (int l = tflat; l < GN * GK; l += 256) {
      int r = l / GK, kk = l % GK;
      Bs[r][kk] = Bm[(size_t)(col0 + r) * Ktot + k0 + kk];
    }
    __syncthreads();
#pragma unroll
    for (int kk = 0; kk < GK; ++kk) {
      float a[4], b[4];
#pragma unroll
      for (int i = 0; i < 4; ++i) a[i] = As[ty * 4 + i][kk];
#pragma unroll
      for (int j = 0; j < 4; ++j) b[j] = Bs[tx * 4 + j][kk];
#pragma unroll
      for (int i = 0; i < 4; ++i)
#pragma unroll
        for (int j = 0; j < 4; ++j) acc[i][j] += a[i] * b[j];
    }
    __syncthreads();
  }
#pragma unroll
  for (int i = 0; i < 4; ++i)
#pragma unroll
    for (int j = 0; j < 4; ++j)
      C[(size_t)(row0 + ty * 4 + i) * N + col0 + tx * 4 + j] = acc[i][j];
}

// ---------------- GRU gates (elementwise) ----------------
__global__ __launch_bounds__(256) void k_gates(const float* __restrict__ Gh,
                                               const float* __restrict__ Gx,
                                               const float* __restrict__ bih,
                                               const float* __restrict__ bhh,
                                               float* __restrict__ h) {
  const int idx = blockIdx.x * 256 + threadIdx.x;   // over B*H
  const int b = idx >> 8, d = idx & 255;
  const size_t gb = (size_t)b * GG;
  float hr = Gh[gb + d]            + bhh[d];
  float xr = Gx[gb + d]            + bih[d];
  float hz = Gh[gb + HH + d]       + bhh[HH + d];
  float xz = Gx[gb + HH + d]       + bih[HH + d];
  float hn = Gh[gb + 2 * HH + d]   + bhh[2 * HH + d];
  float xn = Gx[gb + 2 * HH + d]   + bih[2 * HH + d];
  float r = 1.f / (1.f + expf(-(xr + hr)));
  float z = 1.f / (1.f + expf(-(xz + hz)));
  float n = tanhf(xn + r * hn);
  float hold = h[(size_t)b * HH + d];
  h[(size_t)b * HH + d] = (1.f - z) * n + z * hold;
}

// ---------------- PRNG (threefry_partitionable=True semantics) ----------------
__global__ void k_prng_setup(uint32_t* sk) {
  uint32_t k0, k1, s0, s1, t0, t1;
  tf2x32(0u, 7u, 0u, 0u, k0, k1);   // split(key(7))[0] -> new key
  tf2x32(0u, 7u, 0u, 1u, s0, s1);   // split(key(7))[1] -> subkey round 1
  tf2x32(k0, k1, 0u, 1u, t0, t1);   // split(new)[1]    -> subkey round 2
  sk[0] = s0; sk[1] = s1;
  sk[2] = t0; sk[3] = t1;
}

__global__ void k_genkeys(const uint32_t* __restrict__ sk, int which,
                          uint32_t* __restrict__ keys) {
  int i = blockIdx.x * blockDim.x + threadIdx.x;
  if (i < BN) {
    uint32_t o0, o1;
    tf2x32(sk[which * 2], sk[which * 2 + 1], 0u, (uint32_t)i, o0, o1);
    keys[i] = o0 ^ o1;
  }
}

__global__ __launch_bounds__(64) void k_ranksort(const uint32_t* __restrict__ keys,
                                                 const int* __restrict__ vin,
                                                 int* __restrict__ vout) {
  __shared__ uint32_t skey[BN];
  const int tid = threadIdx.x;
  const int gi = blockIdx.x * 64 + tid;
  for (int idx = tid; idx < BN; idx += 64) skey[idx] = keys[idx];
  __syncthreads();
  const uint32_t ki = skey[gi];
  int rank = 0;
  for (int j = 0; j < BN; ++j) {
    uint32_t kj = skey[j];
    rank += (kj < ki) || (kj == ki && j < gi);
  }
  vout[rank] = vin ? vin[gi] : gi;
}

// ---------------- k-means (all decisions in f64) ----------------
__global__ void k_init_centers(const float* __restrict__ h, const int* __restrict__ vals2,
                               float* __restrict__ centers, double* __restrict__ cnorm) {
  const int c = blockIdx.x, d = threadIdx.x;
  const int src = vals2[c];
  float v = h[(size_t)src * HH + d];
  centers[c * HH + d] = v;
  __shared__ double red[HH];
  red[d] = (double)v * (double)v;
  __syncthreads();
  for (int s = 128; s > 0; s >>= 1) {
    if (d < s) red[d] += red[d + s];
    __syncthreads();
  }
  if (d == 0) cnorm[c] = red[0];
}

__global__ __launch_bounds__(128) void k_assign(const float* __restrict__ h,
                                                const float* __restrict__ centers,
                                                const double* __restrict__ cnorm,
                                                int* __restrict__ codes) {
  __shared__ float sc[KK * HH];
  __shared__ double sn[KK];
  const int tid = threadIdx.x;
  for (int idx = tid; idx < KK * HH; idx += 128) sc[idx] = centers[idx];
  if (tid < KK) sn[tid] = cnorm[tid];
  __syncthreads();
  const int b = blockIdx.x * 128 + tid;
  const float4* hp = (const float4*)&h[(size_t)b * HH];
  double acc[KK] = {};
  double xn = 0.0;
  for (int k4 = 0; k4 < HH / 4; ++k4) {
    float4 xv = hp[k4];
    double x0 = xv.x, x1 = xv.y, x2 = xv.z, x3 = xv.w;
    xn += x0 * x0 + x1 * x1 + x2 * x2 + x3 * x3;
#pragma unroll
    for (int c = 0; c < KK; ++c) {
      float4 cv = *(const float4*)&sc[c * HH + k4 * 4];
      acc[c] += x0 * cv.x + x1 * cv.y + x2 * cv.z + x3 * cv.w;
    }
  }
  int best = 0;
  double bd = xn - 2.0 * acc[0] + sn[0];
#pragma unroll
  for (int c = 1; c < KK; ++c) {
    double d2 = xn - 2.0 * acc[c] + sn[c];
    if (d2 < bd) { bd = d2; best = c; }
  }
  codes[b] = best;
}

__global__ __launch_bounds__(256) void k_upd_partial(const float* __restrict__ h,
                                                     const int* __restrict__ codes,
                                                     double* __restrict__ psum,
                                                     float* __restrict__ pcnt) {
  __shared__ double acc[KK * HH];   // 24 KiB
  __shared__ int lc[UPB];
  const int tid = threadIdx.x;
  for (int idx = tid; idx < KK * HH; idx += 256) acc[idx] = 0.0;
  const int p0 = blockIdx.x * UPB;
  for (int idx = tid; idx < UPB; idx += 256) lc[idx] = codes[p0 + idx];
  __syncthreads();
  const int d = tid;
  for (int p = 0; p < UPB; ++p) {
    int c = lc[p];
    acc[c * HH + d] += (double)h[(size_t)(p0 + p) * HH + d];
  }
  if (tid < KK) {
    float cnt = 0.f;
    for (int p = 0; p < UPB; ++p) cnt += (lc[p] == tid) ? 1.f : 0.f;
    pcnt[blockIdx.x * KK + tid] = cnt;
  }
  for (int c = 0; c < KK; ++c)
    psum[((size_t)blockIdx.x * KK + c) * HH + d] = acc[c * HH + d];
}

__global__ void k_upd_final(const double* __restrict__ psum, const float* __restrict__ pcnt,
                            float* __restrict__ centers, double* __restrict__ cnorm) {
  const int c = blockIdx.x, d = threadIdx.x;
  double s = 0.0;
  for (int b = 0; b < UB; ++b) s += psum[((size_t)b * KK + c) * HH + d];
  float cnt = 0.f;
  for (int b = 0; b < UB; ++b) cnt += pcnt[b * KK + c];
  if (cnt <= 0.5f) cnt = 1.f;
  float v = (float)(s / (double)cnt);
  centers[c * HH + d] = v;
  __shared__ double red[HH];
  red[d] = (double)v * (double)v;
  __syncthreads();
  for (int s2 = 128; s2 > 0; s2 >>= 1) {
    if (d < s2) red[d] += red[d + s2];
    __syncthreads();
  }
  if (d == 0) cnorm[c] = red[0];
}

// ---------------- gumbel hard assignment (f64 decisions) ----------------
__global__ __launch_bounds__(128) void k_gumbel(const float* __restrict__ h,
                                                const float* __restrict__ centers,
                                                int* __restrict__ codeg) {
  __shared__ float sc[KK * HH];
  const int tid = threadIdx.x;
  for (int idx = tid; idx < KK * HH; idx += 128) sc[idx] = centers[idx];
  __syncthreads();
  const int b = blockIdx.x * 128 + tid;
  const float4* hp = (const float4*)&h[(size_t)b * HH];
  double acc[KK] = {};
  for (int k4 = 0; k4 < HH / 4; ++k4) {
    float4 xv = hp[k4];
    double x0 = xv.x, x1 = xv.y, x2 = xv.z, x3 = xv.w;
#pragma unroll
    for (int c = 0; c < KK; ++c) {
      float4 cv = *(const float4*)&sc[c * HH + k4 * 4];
      acc[c] += x0 * cv.x + x1 * cv.y + x2 * cv.z + x3 * cv.w;
    }
  }
  int best = 0;
  double bv = -1e300;
#pragma unroll
  for (int c = 0; c < KK; ++c) {
    double e = acc[c] > 0.0 ? acc[c] : 0.0;
    uint32_t j = (uint32_t)(b * KK + c);
    uint32_t o0, o1;
    tf2x32(0u, 42u, 0u, j, o0, o1);
    double U = (double)bits_to_unit(o0 ^ o1);
    double g = -log(-log(U + 1e-20) + 1e-20);
    double v = e + g;
    if (v > bv) { bv = v; best = c; }
  }
  codeg[b] = best;
}

// ---------------- GCN layer (adj = I) ----------------
__global__ void k_gcn(const float* __restrict__ in, const float* __restrict__ w,
                      const float* __restrict__ bias, float* __restrict__ out) {
  const int c = blockIdx.x, d = threadIdx.x;
  __shared__ float si[HH];
  si[d] = in[c * HH + d];
  __syncthreads();
  float acc = 0.f;
  for (int k = 0; k < HH; ++k) acc += si[k] * w[k * HH + d];
  acc += bias[d];
  out[c * HH + d] = acc > 0.f ? acc : 0.f;
}

// ---------------- final blend (FLOAT32 output) ----------------
__global__ __launch_bounds__(256) void k_final(const float* __restrict__ h,
                                               const float* __restrict__ h2,
                                               const int* __restrict__ codeg,
                                               const float* __restrict__ w1,
                                               const float* __restrict__ w1b,
                                               const float* __restrict__ w2,
                                               const float* __restrict__ w2b,
                                               float* __restrict__ out) {
  const int b = blockIdx.x, d = threadIdx.x;
  const int cg = codeg[b];
  const float cd = h2[cg * HH + d];
  const float hd = h[(size_t)b * HH + d];
  __shared__ float r1[HH], r2[HH];
  __shared__ float wan_s;
  r1[d] = cd * w1[d];
  r2[d] = hd * w2[d];
  __syncthreads();
  for (int s = 128; s > 0; s >>= 1) {
    if (d < s) { r1[d] += r1[d + s]; r2[d] += r2[d + s]; }
    __syncthreads();
  }
  if (d == 0) {
    float wa = 1.f / (1.f + expf(-(r1[0] + w1b[0])));
    float wb = 1.f / (1.f + expf(-(r2[0] + w2b[0])));
    wan_s = wa / (wa + wb);
  }
  __syncthreads();
  float wan = wan_s;
  out[(size_t)b * HH + d] = wan * cd + (1.f - wan) * hd;
}

// ---------------- launch ----------------
extern "C" void kernel_launch(void* const* d_in, const int* in_sizes, int n_in,
                              void* d_out, int out_size, void* d_ws, size_t ws_size,
                              hipStream_t stream) {
  const float* x   = (const float*)d_in[0];
  const float* wih = (const float*)d_in[1];
  const float* whh = (const float*)d_in[2];
  const float* bih = (const float*)d_in[3];
  const float* bhh = (const float*)d_in[4];
  const float* g1w = (const float*)d_in[5];
  const float* g1b = (const float*)d_in[6];
  const float* g2w = (const float*)d_in[7];
  const float* g2b = (const float*)d_in[8];
  const float* w1w = (const float*)d_in[9];
  const float* w1b = (const float*)d_in[10];
  const float* w2w = (const float*)d_in[11];
  const float* w2b = (const float*)d_in[12];
  float* out = (float*)d_out;

  char* wsb = (char*)d_ws;
  size_t off = 0;
  auto alloc = [&](size_t bytes) {
    void* p = wsb + off;
    off += (bytes + 255) & ~(size_t)255;
    return p;
  };
  float* h        = (float*)alloc((size_t)BN * HH * 4);
  float* Gh       = (float*)alloc((size_t)BN * GG * 4);
  float* Gx       = (float*)alloc((size_t)BN * GG * 4);
  float* centers  = (float*)alloc(KK * HH * 4);
  double* cnorm   = (double*)alloc(KK * 8);
  int*   codes    = (int*)alloc(BN * 4);
  int*   codeg    = (int*)alloc(BN * 4);
  uint32_t* keys  = (uint32_t*)alloc(BN * 4);
  int*   vals1    = (int*)alloc(BN * 4);
  int*   vals2    = (int*)alloc(BN * 4);
  uint32_t* sk    = (uint32_t*)alloc(4 * 4);
  double* psum    = (double*)alloc((size_t)UB * KK * HH * 8);
  float* pcnt     = (float*)alloc(UB * KK * 4);
  float* h1       = (float*)alloc(KK * HH * 4);
  float* h2       = (float*)alloc(KK * HH * 4);

  k_zero<<<(BN * HH + 255) / 256, 256, 0, stream>>>(h, BN * HH);

  dim3 gemm_grid(BN / GM, GG / GN);
  dim3 gemm_block(16, 16);
  for (int t = 0; t < TT; ++t) {
    // Gh = h @ whh^T   [8192 x 768], K = 256
    k_mm_nt<<<gemm_grid, gemm_block, 0, stream>>>(h, HH, 0, whh, Gh, GG, HH);
    // Gx = x_t @ wih^T [8192 x 768], K = 64 ; x row stride = T*I, offset t*I
    k_mm_nt<<<gemm_grid, gemm_block, 0, stream>>>(x, TT * II, t * II, wih, Gx, GG, II);
    k_gates<<<BN * HH / 256, 256, 0, stream>>>(Gh, Gx, bih, bhh, h);
  }

  k_prng_setup<<<1, 1, 0, stream>>>(sk);
  k_genkeys<<<32, 256, 0, stream>>>(sk, 0, keys);
  k_ranksort<<<128, 64, 0, stream>>>(keys, (const int*)nullptr, vals1);
  k_genkeys<<<32, 256, 0, stream>>>(sk, 1, keys);
  k_ranksort<<<128, 64, 0, stream>>>(keys, vals1, vals2);

  k_init_centers<<<KK, HH, 0, stream>>>(h, vals2, centers, cnorm);
  k_assign<<<BN / 128, 128, 0, stream>>>(h, centers, cnorm, codes);
  for (int it = 0; it < KM_ITERS_N; ++it) {
    k_upd_partial<<<UB, 256, 0, stream>>>(h, codes, psum, pcnt);
    k_upd_final<<<KK, HH, 0, stream>>>(psum, pcnt, centers, cnorm);
    k_assign<<<BN / 128, 128, 0, stream>>>(h, centers, cnorm, codes);
  }
  k_upd_partial<<<UB, 256, 0, stream>>>(h, codes, psum, pcnt);
  k_upd_final<<<KK, HH, 0, stream>>>(psum, pcnt, centers, cnorm);

  k_gumbel<<<BN / 128, 128, 0, stream>>>(h, centers, codeg);
  k_gcn<<<KK, HH, 0, stream>>>(centers, g1w, g1b, h1);
  k_gcn<<<KK, HH, 0, stream>>>(h1, g2w, g2b, h2);
  k_final<<<BN, HH, 0, stream>>>(h, h2, codeg, w1w, w1b, w2w, w2b, out);
}

// Round 6
// 17447.304 us; speedup vs baseline: 1.0700x; 1.0700x over previous
//
#include <hip/hip_runtime.h>
#include <hip/hip_bf16.h>
#include <stdint.h>

#define BN 8192
#define TT 128
#define II 64
#define HH 256
#define GG 768
#define KK 12
#define KM_ITERS_N 25
#define UB 64
#define UPB (BN/UB)

// ---------------- threefry2x32 (JAX-exact) ----------------
__device__ __forceinline__ uint32_t rotl32(uint32_t v, int d) {
  return (v << d) | (v >> (32 - d));
}
__device__ __forceinline__ void tf2x32(uint32_t k0, uint32_t k1,
                                       uint32_t x0, uint32_t x1,
                                       uint32_t& o0, uint32_t& o1) {
  uint32_t ks2 = k0 ^ k1 ^ 0x1BD11BDAu;
  x0 += k0; x1 += k1;
#define TFR(r) { x0 += x1; x1 = rotl32(x1, r); x1 ^= x0; }
  TFR(13); TFR(15); TFR(26); TFR(6);   x0 += k1;  x1 += ks2 + 1u;
  TFR(17); TFR(29); TFR(16); TFR(24);  x0 += ks2; x1 += k0 + 2u;
  TFR(13); TFR(15); TFR(26); TFR(6);   x0 += k0;  x1 += k1 + 3u;
  TFR(17); TFR(29); TFR(16); TFR(24);  x0 += k1;  x1 += ks2 + 4u;
  TFR(13); TFR(15); TFR(26); TFR(6);   x0 += ks2; x1 += k0 + 5u;
#undef TFR
  o0 = x0; o1 = x1;
}
__device__ __forceinline__ float bits_to_unit(uint32_t bits) {
  uint32_t u = (bits >> 9) | 0x3f800000u;
  return __uint_as_float(u) - 1.0f;
}

// ---------------- zero ----------------
__global__ void k_zero(float* p, int n) {
  int i = blockIdx.x * blockDim.x + threadIdx.x;
  if (i < n) p[i] = 0.f;
}

// ---------------- fused GRU step (h@whh.T + x_t@wih.T + gates, in-place h) ----------------
#define ROWS 32
#define RT 8
#define CT 2
#define GTHREADS 512
#define KC 8
#define SAST 36   // padded stride for transposed h/x tiles (floats); 144B rows keep float4 alignment
#define SBST 772  // padded stride for weight chunks

__global__ __launch_bounds__(GTHREADS, 1) void k_gru_step(
    const float* __restrict__ x, const float* __restrict__ wih,
    const float* __restrict__ whh, const float* __restrict__ bih,
    const float* __restrict__ bhh, float* __restrict__ h, int t) {
  __shared__ float sA[HH * SAST];   // h^T [k][row]   36,864 B
  __shared__ float sX[II * SAST];   // x^T [k][row]    9,216 B
  __shared__ float sB[KC * SBST];   // whh chunk      24,704 B
  __shared__ float sBX[KC * SBST];  // wih chunk      24,704 B
  const int tid = threadIdx.x;
  const int row0 = blockIdx.x * ROWS;
  const int colt = tid & 127;   // 0..127 -> d0 = colt*2
  const int rowt = tid >> 7;    // 0..3   -> rows rowt*8..+7
  const int d0 = colt * CT;
  const int rl0 = rowt * RT;

  for (int idx = tid; idx < ROWS * HH; idx += GTHREADS) {
    int r = idx >> 8, k = idx & 255;
    sA[k * SAST + r] = h[(size_t)(row0 + r) * HH + k];
  }
  for (int idx = tid; idx < ROWS * II; idx += GTHREADS) {
    int r = idx >> 6, k = idx & 63;
    sX[k * SAST + r] = x[(size_t)(row0 + r) * (TT * II) + (size_t)t * II + k];
  }

  float accR[RT][CT] = {}, accZ[RT][CT] = {}, accNH[RT][CT] = {}, accNX[RT][CT] = {};

  // chunks 0..7: k in [0,64): accumulate both h-part (whh) and x-part (wih)
  for (int kc = 0; kc < II / KC; ++kc) {
    __syncthreads();
    const int k0 = kc * KC;
    for (int idx = tid; idx < KC * GG; idx += GTHREADS) {
      int g = idx >> 3, kk = idx & 7;
      sB[kk * SBST + g] = whh[g * HH + k0 + kk];
      sBX[kk * SBST + g] = wih[g * II + k0 + kk];
    }
    __syncthreads();
#pragma unroll
    for (int kk = 0; kk < KC; ++kk) {
      const int k = k0 + kk;
      float4 a0 = *(const float4*)&sA[k * SAST + rl0];
      float4 a1 = *(const float4*)&sA[k * SAST + rl0 + 4];
      float av[RT] = {a0.x, a0.y, a0.z, a0.w, a1.x, a1.y, a1.z, a1.w};
      float2 bR = *(const float2*)&sB[kk * SBST + d0];
      float2 bZ = *(const float2*)&sB[kk * SBST + HH + d0];
      float2 bNv = *(const float2*)&sB[kk * SBST + 2 * HH + d0];
#pragma unroll
      for (int i = 0; i < RT; ++i) {
        accR[i][0] += av[i] * bR.x;  accR[i][1] += av[i] * bR.y;
        accZ[i][0] += av[i] * bZ.x;  accZ[i][1] += av[i] * bZ.y;
        accNH[i][0] += av[i] * bNv.x; accNH[i][1] += av[i] * bNv.y;
      }
      float4 c0 = *(const float4*)&sX[k * SAST + rl0];
      float4 c1 = *(const float4*)&sX[k * SAST + rl0 + 4];
      float cv[RT] = {c0.x, c0.y, c0.z, c0.w, c1.x, c1.y, c1.z, c1.w};
      float2 xR = *(const float2*)&sBX[kk * SBST + d0];
      float2 xZ = *(const float2*)&sBX[kk * SBST + HH + d0];
      float2 xN = *(const float2*)&sBX[kk * SBST + 2 * HH + d0];
#pragma unroll
      for (int i = 0; i < RT; ++i) {
        accR[i][0] += cv[i] * xR.x;  accR[i][1] += cv[i] * xR.y;
        accZ[i][0] += cv[i] * xZ.x;  accZ[i][1] += cv[i] * xZ.y;
        accNX[i][0] += cv[i] * xN.x; accNX[i][1] += cv[i] * xN.y;
      }
    }
  }
  // chunks 8..31: k in [64,256): h-part only
  for (int kc = II / KC; kc < HH / KC; ++kc) {
    __syncthreads();
    const int k0 = kc * KC;
    for (int idx = tid; idx < KC * GG; idx += GTHREADS) {
      int g = idx >> 3, kk = idx & 7;
      sB[kk * SBST + g] = whh[g * HH + k0 + kk];
    }
    __syncthreads();
#pragma unroll
    for (int kk = 0; kk < KC; ++kk) {
      const int k = k0 + kk;
      float4 a0 = *(const float4*)&sA[k * SAST + rl0];
      float4 a1 = *(const float4*)&sA[k * SAST + rl0 + 4];
      float av[RT] = {a0.x, a0.y, a0.z, a0.w, a1.x, a1.y, a1.z, a1.w};
      float2 bR = *(const float2*)&sB[kk * SBST + d0];
      float2 bZ = *(const float2*)&sB[kk * SBST + HH + d0];
      float2 bNv = *(const float2*)&sB[kk * SBST + 2 * HH + d0];
#pragma unroll
      for (int i = 0; i < RT; ++i) {
        accR[i][0] += av[i] * bR.x;  accR[i][1] += av[i] * bR.y;
        accZ[i][0] += av[i] * bZ.x;  accZ[i][1] += av[i] * bZ.y;
        accNH[i][0] += av[i] * bNv.x; accNH[i][1] += av[i] * bNv.y;
      }
    }
  }

  // epilogue: gates + in-place h update (sA still holds old h)
#pragma unroll
  for (int j = 0; j < CT; ++j) {
    const int d = d0 + j;
    const float biR = bih[d], bhR = bhh[d];
    const float biZ = bih[HH + d], bhZ = bhh[HH + d];
    const float biN = bih[2 * HH + d], bhN = bhh[2 * HH + d];
#pragma unroll
    for (int i = 0; i < RT; ++i) {
      const int rl = rl0 + i;
      float rr = accR[i][j] + biR + bhR;
      rr = 1.f / (1.f + expf(-rr));
      float zz = accZ[i][j] + biZ + bhZ;
      zz = 1.f / (1.f + expf(-zz));
      float nn = tanhf(accNX[i][j] + biN + rr * (accNH[i][j] + bhN));
      float hold = sA[d * SAST + rl];
      h[(size_t)(row0 + rl) * HH + d] = (1.f - zz) * nn + zz * hold;
    }
  }
}

// ---------------- PRNG (threefry_partitionable=True semantics) ----------------
__global__ void k_prng_setup(uint32_t* sk) {
  uint32_t k0, k1, s0, s1, t0, t1;
  tf2x32(0u, 7u, 0u, 0u, k0, k1);   // split(key(7))[0] -> new key
  tf2x32(0u, 7u, 0u, 1u, s0, s1);   // split(key(7))[1] -> subkey round 1
  tf2x32(k0, k1, 0u, 1u, t0, t1);   // split(new)[1]    -> subkey round 2
  sk[0] = s0; sk[1] = s1;
  sk[2] = t0; sk[3] = t1;
}

__global__ void k_genkeys(const uint32_t* __restrict__ sk, int which,
                          uint32_t* __restrict__ keys) {
  int i = blockIdx.x * blockDim.x + threadIdx.x;
  if (i < BN) {
    uint32_t o0, o1;
    tf2x32(sk[which * 2], sk[which * 2 + 1], 0u, (uint32_t)i, o0, o1);
    keys[i] = o0 ^ o1;
  }
}

__global__ __launch_bounds__(64) void k_ranksort(const uint32_t* __restrict__ keys,
                                                 const int* __restrict__ vin,
                                                 int* __restrict__ vout) {
  __shared__ uint32_t skey[BN];
  const int tid = threadIdx.x;
  const int gi = blockIdx.x * 64 + tid;
  for (int idx = tid; idx < BN; idx += 64) skey[idx] = keys[idx];
  __syncthreads();
  const uint32_t ki = skey[gi];
  int rank = 0;
  for (int j = 0; j < BN; ++j) {
    uint32_t kj = skey[j];
    rank += (kj < ki) || (kj == ki && j < gi);
  }
  vout[rank] = vin ? vin[gi] : gi;
}

// ---------------- k-means (decisions in f64) ----------------
__global__ void k_init_centers(const float* __restrict__ h, const int* __restrict__ vals2,
                               float* __restrict__ centers, double* __restrict__ cnorm) {
  const int c = blockIdx.x, d = threadIdx.x;
  const int src = vals2[c];
  float v = h[(size_t)src * HH + d];
  centers[c * HH + d] = v;
  __shared__ double red[HH];
  red[d] = (double)v * (double)v;
  __syncthreads();
  for (int s = 128; s > 0; s >>= 1) {
    if (d < s) red[d] += red[d + s];
    __syncthreads();
  }
  if (d == 0) cnorm[c] = red[0];
}

__global__ __launch_bounds__(128) void k_assign(const float* __restrict__ h,
                                                const float* __restrict__ centers,
                                                const double* __restrict__ cnorm,
                                                int* __restrict__ codes) {
  __shared__ float sc[KK * HH];
  __shared__ double sn[KK];
  const int tid = threadIdx.x;
  for (int idx = tid; idx < KK * HH; idx += 128) sc[idx] = centers[idx];
  if (tid < KK) sn[tid] = cnorm[tid];
  __syncthreads();
  const int b = blockIdx.x * 128 + tid;
  const float4* hp = (const float4*)&h[(size_t)b * HH];
  double acc[KK] = {};
  double xn = 0.0;
  for (int k4 = 0; k4 < HH / 4; ++k4) {
    float4 xv = hp[k4];
    double x0 = xv.x, x1 = xv.y, x2 = xv.z, x3 = xv.w;
    xn += x0 * x0 + x1 * x1 + x2 * x2 + x3 * x3;
#pragma unroll
    for (int c = 0; c < KK; ++c) {
      float4 cv = *(const float4*)&sc[c * HH + k4 * 4];
      acc[c] += x0 * cv.x + x1 * cv.y + x2 * cv.z + x3 * cv.w;
    }
  }
  int best = 0;
  double bd = xn - 2.0 * acc[0] + sn[0];
#pragma unroll
  for (int c = 1; c < KK; ++c) {
    double d2 = xn - 2.0 * acc[c] + sn[c];
    if (d2 < bd) { bd = d2; best = c; }
  }
  codes[b] = best;
}

__global__ __launch_bounds__(256) void k_upd_partial(const float* __restrict__ h,
                                                     const int* __restrict__ codes,
                                                     double* __restrict__ psum,
                                                     float* __restrict__ pcnt) {
  __shared__ double acc[KK * HH];   // 24 KiB
  __shared__ int lc[UPB];
  const int tid = threadIdx.x;
  for (int idx = tid; idx < KK * HH; idx += 256) acc[idx] = 0.0;
  const int p0 = blockIdx.x * UPB;
  for (int idx = tid; idx < UPB; idx += 256) lc[idx] = codes[p0 + idx];
  __syncthreads();
  const int d = tid;
  for (int p = 0; p < UPB; ++p) {
    int c = lc[p];
    acc[c * HH + d] += (double)h[(size_t)(p0 + p) * HH + d];
  }
  if (tid < KK) {
    float cnt = 0.f;
    for (int p = 0; p < UPB; ++p) cnt += (lc[p] == tid) ? 1.f : 0.f;
    pcnt[blockIdx.x * KK + tid] = cnt;
  }
  for (int c = 0; c < KK; ++c)
    psum[((size_t)blockIdx.x * KK + c) * HH + d] = acc[c * HH + d];
}

__global__ void k_upd_final(const double* __restrict__ psum, const float* __restrict__ pcnt,
                            float* __restrict__ centers, double* __restrict__ cnorm) {
  const int c = blockIdx.x, d = threadIdx.x;
  double s = 0.0;
  for (int b = 0; b < UB; ++b) s += psum[((size_t)b * KK + c) * HH + d];
  float cnt = 0.f;
  for (int b = 0; b < UB; ++b) cnt += pcnt[b * KK + c];
  if (cnt <= 0.5f) cnt = 1.f;
  float v = (float)(s / (double)cnt);
  centers[c * HH + d] = v;
  __shared__ double red[HH];
  red[d] = (double)v * (double)v;
  __syncthreads();
  for (int s2 = 128; s2 > 0; s2 >>= 1) {
    if (d < s2) red[d] += red[d + s2];
    __syncthreads();
  }
  if (d == 0) cnorm[c] = red[0];
}

// ---------------- gumbel hard assignment (f64 decisions) ----------------
__global__ __launch_bounds__(128) void k_gumbel(const float* __restrict__ h,
                                                const float* __restrict__ centers,
                                                int* __restrict__ codeg) {
  __shared__ float sc[KK * HH];
  const int tid = threadIdx.x;
  for (int idx = tid; idx < KK * HH; idx += 128) sc[idx] = centers[idx];
  __syncthreads();
  const int b = blockIdx.x * 128 + tid;
  const float4* hp = (const float4*)&h[(size_t)b * HH];
  double acc[KK] = {};
  for (int k4 = 0; k4 < HH / 4; ++k4) {
    float4 xv = hp[k4];
    double x0 = xv.x, x1 = xv.y, x2 = xv.z, x3 = xv.w;
#pragma unroll
    for (int c = 0; c < KK; ++c) {
      float4 cv = *(const float4*)&sc[c * HH + k4 * 4];
      acc[c] += x0 * cv.x + x1 * cv.y + x2 * cv.z + x3 * cv.w;
    }
  }
  int best = 0;
  double bv = -1e300;
#pragma unroll
  for (int c = 0; c < KK; ++c) {
    double e = acc[c] > 0.0 ? acc[c] : 0.0;
    uint32_t j = (uint32_t)(b * KK + c);
    uint32_t o0, o1;
    tf2x32(0u, 42u, 0u, j, o0, o1);
    double U = (double)bits_to_unit(o0 ^ o1);
    double g = -log(-log(U + 1e-20) + 1e-20);
    double v = e + g;
    if (v > bv) { bv = v; best = c; }
  }
  codeg[b] = best;
}

// ---------------- GCN layer (adj = I) ----------------
__global__ void k_gcn(const float* __restrict__ in, const float* __restrict__ w,
                      const float* __restrict__ bias, float* __restrict__ out) {
  const int c = blockIdx.x, d = threadIdx.x;
  __shared__ float si[HH];
  si[d] = in[c * HH + d];
  __syncthreads();
  float acc = 0.f;
  for (int k = 0; k < HH; ++k) acc += si[k] * w[k * HH + d];
  acc += bias[d];
  out[c * HH + d] = acc > 0.f ? acc : 0.f;
}

// ---------------- final blend (f32 output) ----------------
__global__ __launch_bounds__(256) void k_final(const float* __restrict__ h,
                                               const float* __restrict__ h2,
                                               const int* __restrict__ codeg,
                                               const float* __restrict__ w1,
                                               const float* __restrict__ w1b,
                                               const float* __restrict__ w2,
                                               const float* __restrict__ w2b,
                                               float* __restrict__ out) {
  const int b = blockIdx.x, d = threadIdx.x;
  const int cg = codeg[b];
  const float cd = h2[cg * HH + d];
  const float hd = h[(size_t)b * HH + d];
  __shared__ float r1[HH], r2[HH];
  __shared__ float wan_s;
  r1[d] = cd * w1[d];
  r2[d] = hd * w2[d];
  __syncthreads();
  for (int s = 128; s > 0; s >>= 1) {
    if (d < s) { r1[d] += r1[d + s]; r2[d] += r2[d + s]; }
    __syncthreads();
  }
  if (d == 0) {
    float wa = 1.f / (1.f + expf(-(r1[0] + w1b[0])));
    float wb = 1.f / (1.f + expf(-(r2[0] + w2b[0])));
    wan_s = wa / (wa + wb);
  }
  __syncthreads();
  float wan = wan_s;
  out[(size_t)b * HH + d] = wan * cd + (1.f - wan) * hd;
}

// ---------------- launch ----------------
extern "C" void kernel_launch(void* const* d_in, const int* in_sizes, int n_in,
                              void* d_out, int out_size, void* d_ws, size_t ws_size,
                              hipStream_t stream) {
  const float* x   = (const float*)d_in[0];
  const float* wih = (const float*)d_in[1];
  const float* whh = (const float*)d_in[2];
  const float* bih = (const float*)d_in[3];
  const float* bhh = (const float*)d_in[4];
  const float* g1w = (const float*)d_in[5];
  const float* g1b = (const float*)d_in[6];
  const float* g2w = (const float*)d_in[7];
  const float* g2b = (const float*)d_in[8];
  const float* w1w = (const float*)d_in[9];
  const float* w1b = (const float*)d_in[10];
  const float* w2w = (const float*)d_in[11];
  const float* w2b = (const float*)d_in[12];
  float* out = (float*)d_out;

  char* wsb = (char*)d_ws;
  size_t off = 0;
  auto alloc = [&](size_t bytes) {
    void* p = wsb + off;
    off += (bytes + 255) & ~(size_t)255;
    return p;
  };
  float* h        = (float*)alloc((size_t)BN * HH * 4);
  float* centers  = (float*)alloc(KK * HH * 4);
  double* cnorm   = (double*)alloc(KK * 8);
  int*   codes    = (int*)alloc(BN * 4);
  int*   codeg    = (int*)alloc(BN * 4);
  uint32_t* keys  = (uint32_t*)alloc(BN * 4);
  int*   vals1    = (int*)alloc(BN * 4);
  int*   vals2    = (int*)alloc(BN * 4);
  uint32_t* sk    = (uint32_t*)alloc(4 * 4);
  double* psum    = (double*)alloc((size_t)UB * KK * HH * 8);
  float* pcnt     = (float*)alloc(UB * KK * 4);
  float* h1       = (float*)alloc(KK * HH * 4);
  float* h2       = (float*)alloc(KK * HH * 4);

  k_zero<<<(BN * HH + 255) / 256, 256, 0, stream>>>(h, BN * HH);
  for (int t = 0; t < TT; ++t)
    k_gru_step<<<BN / ROWS, GTHREADS, 0, stream>>>(x, wih, whh, bih, bhh, h, t);

  k_prng_setup<<<1, 1, 0, stream>>>(sk);
  k_genkeys<<<32, 256, 0, stream>>>(sk, 0, keys);
  k_ranksort<<<128, 64, 0, stream>>>(keys, (const int*)nullptr, vals1);
  k_genkeys<<<32, 256, 0, stream>>>(sk, 1, keys);
  k_ranksort<<<128, 64, 0, stream>>>(keys, vals1, vals2);

  k_init_centers<<<KK, HH, 0, stream>>>(h, vals2, centers, cnorm);
  k_assign<<<BN / 128, 128, 0, stream>>>(h, centers, cnorm, codes);
  for (int it = 0; it < KM_ITERS_N; ++it) {
    k_upd_partial<<<UB, 256, 0, stream>>>(h, codes, psum, pcnt);
    k_upd_final<<<KK, HH, 0, stream>>>(psum, pcnt, centers, cnorm);
    k_assign<<<BN / 128, 128, 0, stream>>>(h, centers, cnorm, codes);
  }
  k_upd_partial<<<UB, 256, 0, stream>>>(h, codes, psum, pcnt);
  k_upd_final<<<KK, HH, 0, stream>>>(psum, pcnt, centers, cnorm);

  k_gumbel<<<BN / 128, 128, 0, stream>>>(h, centers, codeg);
  k_gcn<<<KK, HH, 0, stream>>>(centers, g1w, g1b, h1);
  k_gcn<<<KK, HH, 0, stream>>>(h1, g2w, g2b, h2);
  k_final<<<BN, HH, 0, stream>>>(h, h2, codeg, w1w, w1b, w2w, w2b, out);
}

// Round 7
// 16090.620 us; speedup vs baseline: 1.1602x; 1.0843x over previous
//
#include <hip/hip_runtime.h>
#include <hip/hip_bf16.h>
#include <stdint.h>

#define BN 8192
#define TT 128
#define II 64
#define HH 256
#define GG 768
#define KK 12
#define KM_ITERS_N 25
#define UB 64
#define UPB (BN/UB)

// ---------------- threefry2x32 (JAX-exact) ----------------
__device__ __forceinline__ uint32_t rotl32(uint32_t v, int d) {
  return (v << d) | (v >> (32 - d));
}
__device__ __forceinline__ void tf2x32(uint32_t k0, uint32_t k1,
                                       uint32_t x0, uint32_t x1,
                                       uint32_t& o0, uint32_t& o1) {
  uint32_t ks2 = k0 ^ k1 ^ 0x1BD11BDAu;
  x0 += k0; x1 += k1;
#define TFR(r) { x0 += x1; x1 = rotl32(x1, r); x1 ^= x0; }
  TFR(13); TFR(15); TFR(26); TFR(6);   x0 += k1;  x1 += ks2 + 1u;
  TFR(17); TFR(29); TFR(16); TFR(24);  x0 += ks2; x1 += k0 + 2u;
  TFR(13); TFR(15); TFR(26); TFR(6);   x0 += k0;  x1 += k1 + 3u;
  TFR(17); TFR(29); TFR(16); TFR(24);  x0 += k1;  x1 += ks2 + 4u;
  TFR(13); TFR(15); TFR(26); TFR(6);   x0 += ks2; x1 += k0 + 5u;
#undef TFR
  o0 = x0; o1 = x1;
}
__device__ __forceinline__ float bits_to_unit(uint32_t bits) {
  uint32_t u = (bits >> 9) | 0x3f800000u;
  return __uint_as_float(u) - 1.0f;
}

// ---------------- zero ----------------
__global__ void k_zero(float* p, int n) {
  int i = blockIdx.x * blockDim.x + threadIdx.x;
  if (i < n) p[i] = 0.f;
}

// ---------------- weight pack ----------------
// wpk[s][kc][kk][j], s in {0,1} d-slice, kc 0..39 (0..7 = wih k-chunks, 8..39 = whh),
// j in [0,384): gate = j>>7 (R,Z,N), local col = j&127, g = gate*256 + s*128 + (j&127)
#define NCH 40
#define CHF 3072   // 8*384 floats per chunk
#define DSL 128

__global__ void k_pack_w(const float* __restrict__ wih, const float* __restrict__ whh,
                         float* __restrict__ wpk) {
  int i = blockIdx.x * 256 + threadIdx.x;
  if (i >= 2 * NCH * CHF) return;
  int j  = i % 384;
  int kk = (i / 384) & 7;
  int kc = (i / CHF) % NCH;
  int s  = i / (NCH * CHF);
  int g  = ((j >> 7) << 8) + s * DSL + (j & 127);
  float v;
  if (kc < 8) v = wih[g * II + kc * 8 + kk];
  else        v = whh[g * HH + (kc - 8) * 8 + kk];
  wpk[i] = v;
}

// ---------------- fused GRU step ----------------
// grid (256 row-tiles, 2 d-slices); 512 thr = 64 colt x 8 rowt; RT=4 rows, CT=2 cols.
// sA row-major (broadcast reads), packed-weight chunks double-buffered, 1 barrier/chunk.
#define ROWS 32
#define GTHREADS 512
#define RT 4
#define CT 2

__global__ __launch_bounds__(GTHREADS, 4) void k_gru_step(
    const float* __restrict__ x, const float* __restrict__ wpk,
    const float* __restrict__ bih, const float* __restrict__ bhh,
    const float* __restrict__ hin, float* __restrict__ hout, int t) {
  __shared__ float sA[ROWS * HH];   // 32768 B, h tile row-major
  __shared__ float sX[ROWS * II];   //  8192 B, x tile row-major
  __shared__ float sB[2 * CHF];     // 24576 B, weight chunk double buffer
  const int tid  = threadIdx.x;
  const int row0 = blockIdx.x * ROWS;
  const int s    = blockIdx.y;
  const int colt = tid & 63;
  const int rowt = tid >> 6;
  const int dl   = colt * CT;       // local d offset, even
  const int rl0  = rowt * RT;

  const float* wbase = wpk + (size_t)s * (NCH * CHF);

  // stage sA, sX, chunk 0 (coalesced float4, linear LDS)
  {
    const float4* hs = (const float4*)(hin + (size_t)row0 * HH);
    float4* sa4 = (float4*)sA;
    for (int i = tid; i < ROWS * HH / 4; i += GTHREADS) sa4[i] = hs[i];
    float4* sx4 = (float4*)sX;
    for (int i = tid; i < ROWS * II / 4; i += GTHREADS) {
      int r = i >> 4, c = i & 15;
      sx4[i] = *(const float4*)(x + (size_t)(row0 + r) * (TT * II) + (size_t)t * II + c * 4);
    }
    const float4* w4 = (const float4*)wbase;
    float4* sb4 = (float4*)sB;
    for (int i = tid; i < CHF / 4; i += GTHREADS) sb4[i] = w4[i];
  }
  __syncthreads();

  float accR[RT][CT] = {}, accZ[RT][CT] = {}, accNH[RT][CT] = {}, accNX[RT][CT] = {};

#define GRU_COMPUTE(Aarr, ASTR, ACCN, K0)                                   \
  {                                                                         \
    _Pragma("unroll")                                                       \
    for (int kk = 0; kk < 8; ++kk) {                                        \
      const int k = (K0) + kk;                                              \
      float av0 = Aarr[(rl0 + 0) * (ASTR) + k];                             \
      float av1 = Aarr[(rl0 + 1) * (ASTR) + k];                             \
      float av2 = Aarr[(rl0 + 2) * (ASTR) + k];                             \
      float av3 = Aarr[(rl0 + 3) * (ASTR) + k];                             \
      float2 bR = *(const float2*)&sBb[kk * 384 + dl];                      \
      float2 bZ = *(const float2*)&sBb[kk * 384 + 128 + dl];                \
      float2 bN = *(const float2*)&sBb[kk * 384 + 256 + dl];                \
      accR[0][0] += av0 * bR.x;  accR[0][1] += av0 * bR.y;                  \
      accR[1][0] += av1 * bR.x;  accR[1][1] += av1 * bR.y;                  \
      accR[2][0] += av2 * bR.x;  accR[2][1] += av2 * bR.y;                  \
      accR[3][0] += av3 * bR.x;  accR[3][1] += av3 * bR.y;                  \
      accZ[0][0] += av0 * bZ.x;  accZ[0][1] += av0 * bZ.y;                  \
      accZ[1][0] += av1 * bZ.x;  accZ[1][1] += av1 * bZ.y;                  \
      accZ[2][0] += av2 * bZ.x;  accZ[2][1] += av2 * bZ.y;                  \
      accZ[3][0] += av3 * bZ.x;  accZ[3][1] += av3 * bZ.y;                  \
      ACCN[0][0] += av0 * bN.x;  ACCN[0][1] += av0 * bN.y;                  \
      ACCN[1][0] += av1 * bN.x;  ACCN[1][1] += av1 * bN.y;                  \
      ACCN[2][0] += av2 * bN.x;  ACCN[2][1] += av2 * bN.y;                  \
      ACCN[3][0] += av3 * bN.x;  ACCN[3][1] += av3 * bN.y;                  \
    }                                                                       \
  }

  int cur = 0;
  for (int kc = 0; kc < NCH; ++kc) {
    // issue next-chunk loads early (fly under compute)
    float4 pf0, pf1;
    if (kc + 1 < NCH) {
      const float4* w4 = (const float4*)(wbase + (size_t)(kc + 1) * CHF);
      pf0 = w4[tid];
      if (tid < CHF / 4 - GTHREADS) pf1 = w4[tid + GTHREADS];
    }
    const float* sBb = sB + cur * CHF;
    if (kc < 8) { GRU_COMPUTE(sX, II, accNX, kc * 8) }
    else        { GRU_COMPUTE(sA, HH, accNH, (kc - 8) * 8) }
    // write-late into the free buffer, single barrier
    if (kc + 1 < NCH) {
      float4* sb4 = (float4*)(sB + (cur ^ 1) * CHF);
      sb4[tid] = pf0;
      if (tid < CHF / 4 - GTHREADS) sb4[tid + GTHREADS] = pf1;
    }
    __syncthreads();
    cur ^= 1;
  }
#undef GRU_COMPUTE

  // epilogue: gates, read old h from sA, write hout (disjoint d-slices per block)
#pragma unroll
  for (int j = 0; j < CT; ++j) {
    const int d = s * DSL + dl + j;
    const float biR = bih[d],          bhR = bhh[d];
    const float biZ = bih[HH + d],     bhZ = bhh[HH + d];
    const float biN = bih[2 * HH + d], bhN = bhh[2 * HH + d];
#pragma unroll
    for (int i = 0; i < RT; ++i) {
      const int rl = rl0 + i;
      float rr = accR[i][j] + biR + bhR;
      rr = 1.f / (1.f + expf(-rr));
      float zz = accZ[i][j] + biZ + bhZ;
      zz = 1.f / (1.f + expf(-zz));
      float nn = tanhf(accNX[i][j] + biN + rr * (accNH[i][j] + bhN));
      float hold = sA[rl * HH + d];
      hout[(size_t)(row0 + rl) * HH + d] = (1.f - zz) * nn + zz * hold;
    }
  }
}

// ---------------- PRNG (threefry_partitionable=True semantics) ----------------
__global__ void k_prng_setup(uint32_t* sk) {
  uint32_t k0, k1, s0, s1, t0, t1;
  tf2x32(0u, 7u, 0u, 0u, k0, k1);
  tf2x32(0u, 7u, 0u, 1u, s0, s1);
  tf2x32(k0, k1, 0u, 1u, t0, t1);
  sk[0] = s0; sk[1] = s1;
  sk[2] = t0; sk[3] = t1;
}

__global__ void k_genkeys(const uint32_t* __restrict__ sk, int which,
                          uint32_t* __restrict__ keys) {
  int i = blockIdx.x * blockDim.x + threadIdx.x;
  if (i < BN) {
    uint32_t o0, o1;
    tf2x32(sk[which * 2], sk[which * 2 + 1], 0u, (uint32_t)i, o0, o1);
    keys[i] = o0 ^ o1;
  }
}

__global__ __launch_bounds__(256) void k_ranksort(const uint32_t* __restrict__ keys,
                                                  const int* __restrict__ vin,
                                                  int* __restrict__ vout) {
  __shared__ uint32_t skey[BN];
  const int tid = threadIdx.x;
  const int gi = blockIdx.x * 256 + tid;
  for (int idx = tid; idx < BN; idx += 256) skey[idx] = keys[idx];
  __syncthreads();
  const uint32_t ki = skey[gi];
  int rank = 0;
#pragma unroll 8
  for (int j = 0; j < BN; ++j) {
    uint32_t kj = skey[j];
    rank += (kj < ki) || (kj == ki && j < gi);
  }
  vout[rank] = vin ? vin[gi] : gi;
}

// ---------------- k-means (decisions in f64) ----------------
__global__ void k_init_centers(const float* __restrict__ h, const int* __restrict__ vals2,
                               float* __restrict__ centers, double* __restrict__ cnorm) {
  const int c = blockIdx.x, d = threadIdx.x;
  const int src = vals2[c];
  float v = h[(size_t)src * HH + d];
  centers[c * HH + d] = v;
  __shared__ double red[HH];
  red[d] = (double)v * (double)v;
  __syncthreads();
  for (int s = 128; s > 0; s >>= 1) {
    if (d < s) red[d] += red[d + s];
    __syncthreads();
  }
  if (d == 0) cnorm[c] = red[0];
}

__global__ __launch_bounds__(128) void k_assign(const float* __restrict__ h,
                                                const float* __restrict__ centers,
                                                const double* __restrict__ cnorm,
                                                int* __restrict__ codes) {
  __shared__ float sc[KK * HH];
  __shared__ double sn[KK];
  const int tid = threadIdx.x;
  for (int idx = tid; idx < KK * HH; idx += 128) sc[idx] = centers[idx];
  if (tid < KK) sn[tid] = cnorm[tid];
  __syncthreads();
  const int b = blockIdx.x * 128 + tid;
  const float4* hp = (const float4*)&h[(size_t)b * HH];
  double acc[KK] = {};
  double xn = 0.0;
  for (int k4 = 0; k4 < HH / 4; ++k4) {
    float4 xv = hp[k4];
    double x0 = xv.x, x1 = xv.y, x2 = xv.z, x3 = xv.w;
    xn += x0 * x0 + x1 * x1 + x2 * x2 + x3 * x3;
#pragma unroll
    for (int c = 0; c < KK; ++c) {
      float4 cv = *(const float4*)&sc[c * HH + k4 * 4];
      acc[c] += x0 * cv.x + x1 * cv.y + x2 * cv.z + x3 * cv.w;
    }
  }
  int best = 0;
  double bd = xn - 2.0 * acc[0] + sn[0];
#pragma unroll
  for (int c = 1; c < KK; ++c) {
    double d2 = xn - 2.0 * acc[c] + sn[c];
    if (d2 < bd) { bd = d2; best = c; }
  }
  codes[b] = best;
}

__global__ __launch_bounds__(256) void k_upd_partial(const float* __restrict__ h,
                                                     const int* __restrict__ codes,
                                                     double* __restrict__ psum,
                                                     float* __restrict__ pcnt) {
  __shared__ double acc[KK * HH];
  __shared__ int lc[UPB];
  const int tid = threadIdx.x;
  for (int idx = tid; idx < KK * HH; idx += 256) acc[idx] = 0.0;
  const int p0 = blockIdx.x * UPB;
  for (int idx = tid; idx < UPB; idx += 256) lc[idx] = codes[p0 + idx];
  __syncthreads();
  const int d = tid;
  for (int p = 0; p < UPB; ++p) {
    int c = lc[p];
    acc[c * HH + d] += (double)h[(size_t)(p0 + p) * HH + d];
  }
  if (tid < KK) {
    float cnt = 0.f;
    for (int p = 0; p < UPB; ++p) cnt += (lc[p] == tid) ? 1.f : 0.f;
    pcnt[blockIdx.x * KK + tid] = cnt;
  }
  for (int c = 0; c < KK; ++c)
    psum[((size_t)blockIdx.x * KK + c) * HH + d] = acc[c * HH + d];
}

__global__ void k_upd_final(const double* __restrict__ psum, const float* __restrict__ pcnt,
                            float* __restrict__ centers, double* __restrict__ cnorm) {
  const int c = blockIdx.x, d = threadIdx.x;
  double s = 0.0;
  for (int b = 0; b < UB; ++b) s += psum[((size_t)b * KK + c) * HH + d];
  float cnt = 0.f;
  for (int b = 0; b < UB; ++b) cnt += pcnt[b * KK + c];
  if (cnt <= 0.5f) cnt = 1.f;
  float v = (float)(s / (double)cnt);
  centers[c * HH + d] = v;
  __shared__ double red[HH];
  red[d] = (double)v * (double)v;
  __syncthreads();
  for (int s2 = 128; s2 > 0; s2 >>= 1) {
    if (d < s2) red[d] += red[d + s2];
    __syncthreads();
  }
  if (d == 0) cnorm[c] = red[0];
}

// ---------------- gumbel hard assignment (f64 decisions) ----------------
__global__ __launch_bounds__(128) void k_gumbel(const float* __restrict__ h,
                                                const float* __restrict__ centers,
                                                int* __restrict__ codeg) {
  __shared__ float sc[KK * HH];
  const int tid = threadIdx.x;
  for (int idx = tid; idx < KK * HH; idx += 128) sc[idx] = centers[idx];
  __syncthreads();
  const int b = blockIdx.x * 128 + tid;
  const float4* hp = (const float4*)&h[(size_t)b * HH];
  double acc[KK] = {};
  for (int k4 = 0; k4 < HH / 4; ++k4) {
    float4 xv = hp[k4];
    double x0 = xv.x, x1 = xv.y, x2 = xv.z, x3 = xv.w;
#pragma unroll
    for (int c = 0; c < KK; ++c) {
      float4 cv = *(const float4*)&sc[c * HH + k4 * 4];
      acc[c] += x0 * cv.x + x1 * cv.y + x2 * cv.z + x3 * cv.w;
    }
  }
  int best = 0;
  double bv = -1e300;
#pragma unroll
  for (int c = 0; c < KK; ++c) {
    double e = acc[c] > 0.0 ? acc[c] : 0.0;
    uint32_t j = (uint32_t)(b * KK + c);
    uint32_t o0, o1;
    tf2x32(0u, 42u, 0u, j, o0, o1);
    double U = (double)bits_to_unit(o0 ^ o1);
    double g = -log(-log(U + 1e-20) + 1e-20);
    double v = e + g;
    if (v > bv) { bv = v; best = c; }
  }
  codeg[b] = best;
}

// ---------------- GCN layer (adj = I) ----------------
__global__ void k_gcn(const float* __restrict__ in, const float* __restrict__ w,
                      const float* __restrict__ bias, float* __restrict__ out) {
  const int c = blockIdx.x, d = threadIdx.x;
  __shared__ float si[HH];
  si[d] = in[c * HH + d];
  __syncthreads();
  float acc = 0.f;
  for (int k = 0; k < HH; ++k) acc += si[k] * w[k * HH + d];
  acc += bias[d];
  out[c * HH + d] = acc > 0.f ? acc : 0.f;
}

// ---------------- final blend (f32 output) ----------------
__global__ __launch_bounds__(256) void k_final(const float* __restrict__ h,
                                               const float* __restrict__ h2,
                                               const int* __restrict__ codeg,
                                               const float* __restrict__ w1,
                                               const float* __restrict__ w1b,
                                               const float* __restrict__ w2,
                                               const float* __restrict__ w2b,
                                               float* __restrict__ out) {
  const int b = blockIdx.x, d = threadIdx.x;
  const int cg = codeg[b];
  const float cd = h2[cg * HH + d];
  const float hd = h[(size_t)b * HH + d];
  __shared__ float r1[HH], r2[HH];
  __shared__ float wan_s;
  r1[d] = cd * w1[d];
  r2[d] = hd * w2[d];
  __syncthreads();
  for (int s = 128; s > 0; s >>= 1) {
    if (d < s) { r1[d] += r1[d + s]; r2[d] += r2[d + s]; }
    __syncthreads();
  }
  if (d == 0) {
    float wa = 1.f / (1.f + expf(-(r1[0] + w1b[0])));
    float wb = 1.f / (1.f + expf(-(r2[0] + w2b[0])));
    wan_s = wa / (wa + wb);
  }
  __syncthreads();
  float wan = wan_s;
  out[(size_t)b * HH + d] = wan * cd + (1.f - wan) * hd;
}

// ---------------- launch ----------------
extern "C" void kernel_launch(void* const* d_in, const int* in_sizes, int n_in,
                              void* d_out, int out_size, void* d_ws, size_t ws_size,
                              hipStream_t stream) {
  const float* x   = (const float*)d_in[0];
  const float* wih = (const float*)d_in[1];
  const float* whh = (const float*)d_in[2];
  const float* bih = (const float*)d_in[3];
  const float* bhh = (const float*)d_in[4];
  const float* g1w = (const float*)d_in[5];
  const float* g1b = (const float*)d_in[6];
  const float* g2w = (const float*)d_in[7];
  const float* g2b = (const float*)d_in[8];
  const float* w1w = (const float*)d_in[9];
  const float* w1b = (const float*)d_in[10];
  const float* w2w = (const float*)d_in[11];
  const float* w2b = (const float*)d_in[12];
  float* out = (float*)d_out;

  char* wsb = (char*)d_ws;
  size_t off = 0;
  auto alloc = [&](size_t bytes) {
    void* p = wsb + off;
    off += (bytes + 255) & ~(size_t)255;
    return p;
  };
  float* h0       = (float*)alloc((size_t)BN * HH * 4);
  float* h1       = (float*)alloc((size_t)BN * HH * 4);
  float* wpk      = (float*)alloc((size_t)2 * NCH * CHF * 4);
  float* centers  = (float*)alloc(KK * HH * 4);
  double* cnorm   = (double*)alloc(KK * 8);
  int*   codes    = (int*)alloc(BN * 4);
  int*   codeg    = (int*)alloc(BN * 4);
  uint32_t* keys  = (uint32_t*)alloc(BN * 4);
  int*   vals1    = (int*)alloc(BN * 4);
  int*   vals2    = (int*)alloc(BN * 4);
  uint32_t* sk    = (uint32_t*)alloc(4 * 4);
  double* psum    = (double*)alloc((size_t)UB * KK * HH * 8);
  float* pcnt     = (float*)alloc(UB * KK * 4);
  float* hh1      = (float*)alloc(KK * HH * 4);
  float* hh2      = (float*)alloc(KK * HH * 4);

  k_zero<<<(BN * HH + 255) / 256, 256, 0, stream>>>(h0, BN * HH);
  k_pack_w<<<(2 * NCH * CHF + 255) / 256, 256, 0, stream>>>(wih, whh, wpk);

  dim3 gru_grid(BN / ROWS, 2);
  for (int t = 0; t < TT; ++t) {
    const float* hin = (t & 1) ? h1 : h0;
    float* hout      = (t & 1) ? h0 : h1;
    k_gru_step<<<gru_grid, GTHREADS, 0, stream>>>(x, wpk, bih, bhh, hin, hout, t);
  }
  float* h = h0;  // T=128 even -> final state lands in h0

  k_prng_setup<<<1, 1, 0, stream>>>(sk);
  k_genkeys<<<32, 256, 0, stream>>>(sk, 0, keys);
  k_ranksort<<<32, 256, 0, stream>>>(keys, (const int*)nullptr, vals1);
  k_genkeys<<<32, 256, 0, stream>>>(sk, 1, keys);
  k_ranksort<<<32, 256, 0, stream>>>(keys, vals1, vals2);

  k_init_centers<<<KK, HH, 0, stream>>>(h, vals2, centers, cnorm);
  k_assign<<<BN / 128, 128, 0, stream>>>(h, centers, cnorm, codes);
  for (int it = 0; it < KM_ITERS_N; ++it) {
    k_upd_partial<<<UB, 256, 0, stream>>>(h, codes, psum, pcnt);
    k_upd_final<<<KK, HH, 0, stream>>>(psum, pcnt, centers, cnorm);
    k_assign<<<BN / 128, 128, 0, stream>>>(h, centers, cnorm, codes);
  }
  k_upd_partial<<<UB, 256, 0, stream>>>(h, codes, psum, pcnt);
  k_upd_final<<<KK, HH, 0, stream>>>(psum, pcnt, centers, cnorm);

  k_gumbel<<<BN / 128, 128, 0, stream>>>(h, centers, codeg);
  k_gcn<<<KK, HH, 0, stream>>>(centers, g1w, g1b, hh1);
  k_gcn<<<KK, HH, 0, stream>>>(hh1, g2w, g2b, hh2);
  k_final<<<BN, HH, 0, stream>>>(h, hh2, codeg, w1w, w1b, w2w, w2b, out);
}

// Round 8
// 11840.749 us; speedup vs baseline: 1.5766x; 1.3589x over previous
//
#include <hip/hip_runtime.h>
#include <hip/hip_bf16.h>
#include <stdint.h>

#define BN 8192
#define TT 128
#define II 64
#define HH 256
#define GG 768
#define KK 12
#define KM_ITERS_N 25
#define UB 64
#define UPB (BN/UB)

// ---------------- threefry2x32 (JAX-exact) ----------------
__device__ __forceinline__ uint32_t rotl32(uint32_t v, int d) {
  return (v << d) | (v >> (32 - d));
}
__device__ __forceinline__ void tf2x32(uint32_t k0, uint32_t k1,
                                       uint32_t x0, uint32_t x1,
                                       uint32_t& o0, uint32_t& o1) {
  uint32_t ks2 = k0 ^ k1 ^ 0x1BD11BDAu;
  x0 += k0; x1 += k1;
#define TFR(r) { x0 += x1; x1 = rotl32(x1, r); x1 ^= x0; }
  TFR(13); TFR(15); TFR(26); TFR(6);   x0 += k1;  x1 += ks2 + 1u;
  TFR(17); TFR(29); TFR(16); TFR(24);  x0 += ks2; x1 += k0 + 2u;
  TFR(13); TFR(15); TFR(26); TFR(6);   x0 += k0;  x1 += k1 + 3u;
  TFR(17); TFR(29); TFR(16); TFR(24);  x0 += k1;  x1 += ks2 + 4u;
  TFR(13); TFR(15); TFR(26); TFR(6);   x0 += ks2; x1 += k0 + 5u;
#undef TFR
  o0 = x0; o1 = x1;
}
__device__ __forceinline__ float bits_to_unit(uint32_t bits) {
  uint32_t u = (bits >> 9) | 0x3f800000u;
  return __uint_as_float(u) - 1.0f;
}

// ---------------- zero ----------------
__global__ void k_zero(float* p, int n) {
  int i = blockIdx.x * blockDim.x + threadIdx.x;
  if (i < n) p[i] = 0.f;
}

// ---------------- weight pack ----------------
// wpk[s][kc][kk][j]: s = d-slice {0,1}, kc 0..39 (0..7 wih k-chunks, 8..39 whh),
// kk 0..7, j in [0,384): gate = j>>7, g = gate*256 + s*128 + (j&127)
#define NCH 40
#define CHF 3072
#define DSL 128

__global__ void k_pack_w(const float* __restrict__ wih, const float* __restrict__ whh,
                         float* __restrict__ wpk) {
  int i = blockIdx.x * 256 + threadIdx.x;
  if (i >= 2 * NCH * CHF) return;
  int j  = i % 384;
  int kk = (i / 384) & 7;
  int kc = (i / CHF) % NCH;
  int s  = i / (NCH * CHF);
  int g  = ((j >> 7) << 8) + s * DSL + (j & 127);
  float v;
  if (kc < 8) v = wih[g * II + kc * 8 + kk];
  else        v = whh[g * HH + (kc - 8) * 8 + kk];
  wpk[i] = v;
}

// ---------------- fused GRU step ----------------
// grid (256 row-tiles, 2 d-slices); 256 thr = 64 colt x 4 rowt; RT=8 rows, CT=2 cols.
// Accumulation order identical to round-7 kernel (kc asc, kk asc) -> same trajectory.
#define ROWS 32
#define GTHREADS 256
#define RT 8
#define CT 2

__global__ __launch_bounds__(GTHREADS, 2) void k_gru_step(
    const float* __restrict__ x, const float* __restrict__ wpk,
    const float* __restrict__ bih, const float* __restrict__ bhh,
    const float* __restrict__ hin, float* __restrict__ hout, int t) {
  __shared__ float sA[ROWS * HH];   // 32 KB
  __shared__ float sX[ROWS * II];   //  8 KB
  __shared__ float sB[2 * CHF];     // 24 KB
  const int tid  = threadIdx.x;
  const int row0 = blockIdx.x * ROWS;
  const int s    = blockIdx.y;
  const int colt = tid & 63;        // 0..63
  const int rowt = tid >> 6;        // 0..3
  const int dl   = colt * CT;
  const int rl0  = rowt * RT;

  const float* wbase = wpk + (size_t)s * (NCH * CHF);

  // stage sA (2048 f4), sX (512 f4), chunk 0 (768 f4) - coalesced, linear LDS
  {
    const float4* hs = (const float4*)(hin + (size_t)row0 * HH);
    float4* sa4 = (float4*)sA;
#pragma unroll
    for (int i = 0; i < 8; ++i) sa4[tid + i * GTHREADS] = hs[tid + i * GTHREADS];
    float4* sx4 = (float4*)sX;
#pragma unroll
    for (int i = 0; i < 2; ++i) {
      int idx = tid + i * GTHREADS;
      int r = idx >> 4, c = idx & 15;
      sx4[idx] = *(const float4*)(x + (size_t)(row0 + r) * (TT * II) + (size_t)t * II + c * 4);
    }
    const float4* w4 = (const float4*)wbase;
    float4* sb4 = (float4*)sB;
#pragma unroll
    for (int i = 0; i < 3; ++i) sb4[tid + i * GTHREADS] = w4[tid + i * GTHREADS];
  }
  __syncthreads();

  float accR[RT][CT] = {}, accZ[RT][CT] = {}, accNH[RT][CT] = {}, accNX[RT][CT] = {};

#define ROWFMA(r, avv)                                                       \
  { float a = ((const float*)&avv)[kk];                                      \
    accR[r][0] += a * bR.x;  accR[r][1] += a * bR.y;                         \
    accZ[r][0] += a * bZ.x;  accZ[r][1] += a * bZ.y;                         \
    ACCNM[r][0] += a * bN.x; ACCNM[r][1] += a * bN.y; }

#define GRU_CHUNK(Aarr, ASTR, K0)                                            \
  {                                                                          \
    _Pragma("unroll")                                                        \
    for (int q = 0; q < 2; ++q) {                                            \
      const int kb = (K0) + q * 4;                                           \
      float4 av0 = *(const float4*)&Aarr[(rl0 + 0) * (ASTR) + kb];           \
      float4 av1 = *(const float4*)&Aarr[(rl0 + 1) * (ASTR) + kb];           \
      float4 av2 = *(const float4*)&Aarr[(rl0 + 2) * (ASTR) + kb];           \
      float4 av3 = *(const float4*)&Aarr[(rl0 + 3) * (ASTR) + kb];           \
      float4 av4 = *(const float4*)&Aarr[(rl0 + 4) * (ASTR) + kb];           \
      float4 av5 = *(const float4*)&Aarr[(rl0 + 5) * (ASTR) + kb];           \
      float4 av6 = *(const float4*)&Aarr[(rl0 + 6) * (ASTR) + kb];           \
      float4 av7 = *(const float4*)&Aarr[(rl0 + 7) * (ASTR) + kb];           \
      _Pragma("unroll")                                                      \
      for (int kk = 0; kk < 4; ++kk) {                                       \
        const int krow = (q * 4 + kk) * 384;                                 \
        float2 bR = *(const float2*)&sBb[krow + dl];                         \
        float2 bZ = *(const float2*)&sBb[krow + 128 + dl];                   \
        float2 bN = *(const float2*)&sBb[krow + 256 + dl];                   \
        ROWFMA(0, av0) ROWFMA(1, av1) ROWFMA(2, av2) ROWFMA(3, av3)          \
        ROWFMA(4, av4) ROWFMA(5, av5) ROWFMA(6, av6) ROWFMA(7, av7)          \
      }                                                                      \
    }                                                                        \
  }

  int cur = 0;
  for (int kc = 0; kc < NCH; ++kc) {
    float4 pf0, pf1, pf2;
    if (kc + 1 < NCH) {
      const float4* w4 = (const float4*)(wbase + (size_t)(kc + 1) * CHF);
      pf0 = w4[tid];
      pf1 = w4[tid + GTHREADS];
      pf2 = w4[tid + 2 * GTHREADS];
    }
    const float* sBb = sB + cur * CHF;
    if (kc < 8) {
#define ACCNM accNX
      GRU_CHUNK(sX, II, kc * 8)
#undef ACCNM
    } else {
#define ACCNM accNH
      GRU_CHUNK(sA, HH, (kc - 8) * 8)
#undef ACCNM
    }
    if (kc + 1 < NCH) {
      float4* sb4 = (float4*)(sB + (cur ^ 1) * CHF);
      sb4[tid] = pf0;
      sb4[tid + GTHREADS] = pf1;
      sb4[tid + 2 * GTHREADS] = pf2;
    }
    __syncthreads();
    cur ^= 1;
  }
#undef GRU_CHUNK
#undef ROWFMA

  // epilogue: gates, old h from sA, write hout (disjoint d-slices per block)
#pragma unroll
  for (int j = 0; j < CT; ++j) {
    const int d = s * DSL + dl + j;
    const float biR = bih[d],          bhR = bhh[d];
    const float biZ = bih[HH + d],     bhZ = bhh[HH + d];
    const float biN = bih[2 * HH + d], bhN = bhh[2 * HH + d];
#pragma unroll
    for (int i = 0; i < RT; ++i) {
      const int rl = rl0 + i;
      float rr = accR[i][j] + biR + bhR;
      rr = 1.f / (1.f + expf(-rr));
      float zz = accZ[i][j] + biZ + bhZ;
      zz = 1.f / (1.f + expf(-zz));
      float nn = tanhf(accNX[i][j] + biN + rr * (accNH[i][j] + bhN));
      float hold = sA[rl * HH + d];
      hout[(size_t)(row0 + rl) * HH + d] = (1.f - zz) * nn + zz * hold;
    }
  }
}

// ---------------- PRNG (threefry_partitionable=True semantics) ----------------
__global__ void k_prng_setup(uint32_t* sk) {
  uint32_t k0, k1, s0, s1, t0, t1;
  tf2x32(0u, 7u, 0u, 0u, k0, k1);
  tf2x32(0u, 7u, 0u, 1u, s0, s1);
  tf2x32(k0, k1, 0u, 1u, t0, t1);
  sk[0] = s0; sk[1] = s1;
  sk[2] = t0; sk[3] = t1;
}

__global__ void k_genkeys(const uint32_t* __restrict__ sk, int which,
                          uint32_t* __restrict__ keys) {
  int i = blockIdx.x * blockDim.x + threadIdx.x;
  if (i < BN) {
    uint32_t o0, o1;
    tf2x32(sk[which * 2], sk[which * 2 + 1], 0u, (uint32_t)i, o0, o1);
    keys[i] = o0 ^ o1;
  }
}

// stable rank sort, tiled: 512 blocks x 16 elements, 16 threads/element
#define RSE 16
__global__ __launch_bounds__(256) void k_ranksort(const uint32_t* __restrict__ keys,
                                                  const int* __restrict__ vin,
                                                  int* __restrict__ vout) {
  __shared__ uint32_t skey[BN];       // 32 KB
  __shared__ int psum[RSE][17];
  const int tid = threadIdx.x;
  const int g = tid >> 4;             // element group 0..15
  const int l = tid & 15;             // lane within group
  const int gi = blockIdx.x * RSE + g;
  for (int i = tid; i < BN; i += 256) skey[i] = keys[i];
  __syncthreads();
  const uint32_t ki = skey[gi];
  int rank = 0;
#pragma unroll 8
  for (int j = l; j < BN; j += 16) {
    uint32_t kj = skey[j];
    rank += (kj < ki) || (kj == ki && j < gi);
  }
  psum[g][l] = rank;
  __syncthreads();
  if (l == 0) {
    int r = 0;
#pragma unroll
    for (int tt = 0; tt < 16; ++tt) r += psum[g][tt];
    vout[r] = vin ? vin[gi] : gi;
  }
}

// ---------------- k-means (decisions in f64) ----------------
__global__ void k_init_centers(const float* __restrict__ h, const int* __restrict__ vals2,
                               float* __restrict__ centers, double* __restrict__ cnorm) {
  const int c = blockIdx.x, d = threadIdx.x;
  const int src = vals2[c];
  float v = h[(size_t)src * HH + d];
  centers[c * HH + d] = v;
  __shared__ double red[HH];
  red[d] = (double)v * (double)v;
  __syncthreads();
  for (int s = 128; s > 0; s >>= 1) {
    if (d < s) red[d] += red[d + s];
    __syncthreads();
  }
  if (d == 0) cnorm[c] = red[0];
}

__global__ __launch_bounds__(128) void k_assign(const float* __restrict__ h,
                                                const float* __restrict__ centers,
                                                const double* __restrict__ cnorm,
                                                int* __restrict__ codes) {
  __shared__ float sc[KK * HH];
  __shared__ double sn[KK];
  const int tid = threadIdx.x;
  for (int idx = tid; idx < KK * HH; idx += 128) sc[idx] = centers[idx];
  if (tid < KK) sn[tid] = cnorm[tid];
  __syncthreads();
  const int b = blockIdx.x * 128 + tid;
  const float4* hp = (const float4*)&h[(size_t)b * HH];
  double acc[KK] = {};
  double xn = 0.0;
  for (int k4 = 0; k4 < HH / 4; ++k4) {
    float4 xv = hp[k4];
    double x0 = xv.x, x1 = xv.y, x2 = xv.z, x3 = xv.w;
    xn += x0 * x0 + x1 * x1 + x2 * x2 + x3 * x3;
#pragma unroll
    for (int c = 0; c < KK; ++c) {
      float4 cv = *(const float4*)&sc[c * HH + k4 * 4];
      acc[c] += x0 * cv.x + x1 * cv.y + x2 * cv.z + x3 * cv.w;
    }
  }
  int best = 0;
  double bd = xn - 2.0 * acc[0] + sn[0];
#pragma unroll
  for (int c = 1; c < KK; ++c) {
    double d2 = xn - 2.0 * acc[c] + sn[c];
    if (d2 < bd) { bd = d2; best = c; }
  }
  codes[b] = best;
}

__global__ __launch_bounds__(256) void k_upd_partial(const float* __restrict__ h,
                                                     const int* __restrict__ codes,
                                                     double* __restrict__ psum,
                                                     float* __restrict__ pcnt) {
  __shared__ double acc[KK * HH];
  __shared__ int lc[UPB];
  const int tid = threadIdx.x;
  for (int idx = tid; idx < KK * HH; idx += 256) acc[idx] = 0.0;
  const int p0 = blockIdx.x * UPB;
  for (int idx = tid; idx < UPB; idx += 256) lc[idx] = codes[p0 + idx];
  __syncthreads();
  const int d = tid;
  for (int p = 0; p < UPB; ++p) {
    int c = lc[p];
    acc[c * HH + d] += (double)h[(size_t)(p0 + p) * HH + d];
  }
  if (tid < KK) {
    float cnt = 0.f;
    for (int p = 0; p < UPB; ++p) cnt += (lc[p] == tid) ? 1.f : 0.f;
    pcnt[blockIdx.x * KK + tid] = cnt;
  }
  for (int c = 0; c < KK; ++c)
    psum[((size_t)blockIdx.x * KK + c) * HH + d] = acc[c * HH + d];
}

__global__ void k_upd_final(const double* __restrict__ psum, const float* __restrict__ pcnt,
                            float* __restrict__ centers, double* __restrict__ cnorm) {
  const int c = blockIdx.x, d = threadIdx.x;
  double s = 0.0;
  for (int b = 0; b < UB; ++b) s += psum[((size_t)b * KK + c) * HH + d];
  float cnt = 0.f;
  for (int b = 0; b < UB; ++b) cnt += pcnt[b * KK + c];
  if (cnt <= 0.5f) cnt = 1.f;
  float v = (float)(s / (double)cnt);
  centers[c * HH + d] = v;
  __shared__ double red[HH];
  red[d] = (double)v * (double)v;
  __syncthreads();
  for (int s2 = 128; s2 > 0; s2 >>= 1) {
    if (d < s2) red[d] += red[d + s2];
    __syncthreads();
  }
  if (d == 0) cnorm[c] = red[0];
}

// ---------------- gumbel hard assignment (f64 decisions) ----------------
__global__ __launch_bounds__(128) void k_gumbel(const float* __restrict__ h,
                                                const float* __restrict__ centers,
                                                int* __restrict__ codeg) {
  __shared__ float sc[KK * HH];
  const int tid = threadIdx.x;
  for (int idx = tid; idx < KK * HH; idx += 128) sc[idx] = centers[idx];
  __syncthreads();
  const int b = blockIdx.x * 128 + tid;
  const float4* hp = (const float4*)&h[(size_t)b * HH];
  double acc[KK] = {};
  for (int k4 = 0; k4 < HH / 4; ++k4) {
    float4 xv = hp[k4];
    double x0 = xv.x, x1 = xv.y, x2 = xv.z, x3 = xv.w;
#pragma unroll
    for (int c = 0; c < KK; ++c) {
      float4 cv = *(const float4*)&sc[c * HH + k4 * 4];
      acc[c] += x0 * cv.x + x1 * cv.y + x2 * cv.z + x3 * cv.w;
    }
  }
  int best = 0;
  double bv = -1e300;
#pragma unroll
  for (int c = 0; c < KK; ++c) {
    double e = acc[c] > 0.0 ? acc[c] : 0.0;
    uint32_t j = (uint32_t)(b * KK + c);
    uint32_t o0, o1;
    tf2x32(0u, 42u, 0u, j, o0, o1);
    double U = (double)bits_to_unit(o0 ^ o1);
    double g = -log(-log(U + 1e-20) + 1e-20);
    double v = e + g;
    if (v > bv) { bv = v; best = c; }
  }
  codeg[b] = best;
}

// ---------------- GCN layer (adj = I) ----------------
__global__ void k_gcn(const float* __restrict__ in, const float* __restrict__ w,
                      const float* __restrict__ bias, float* __restrict__ out) {
  const int c = blockIdx.x, d = threadIdx.x;
  __shared__ float si[HH];
  si[d] = in[c * HH + d];
  __syncthreads();
  float acc = 0.f;
  for (int k = 0; k < HH; ++k) acc += si[k] * w[k * HH + d];
  acc += bias[d];
  out[c * HH + d] = acc > 0.f ? acc : 0.f;
}

// ---------------- final blend (f32 output) ----------------
__global__ __launch_bounds__(256) void k_final(const float* __restrict__ h,
                                               const float* __restrict__ h2,
                                               const int* __restrict__ codeg,
                                               const float* __restrict__ w1,
                                               const float* __restrict__ w1b,
                                               const float* __restrict__ w2,
                                               const float* __restrict__ w2b,
                                               float* __restrict__ out) {
  const int b = blockIdx.x, d = threadIdx.x;
  const int cg = codeg[b];
  const float cd = h2[cg * HH + d];
  const float hd = h[(size_t)b * HH + d];
  __shared__ float r1[HH], r2[HH];
  __shared__ float wan_s;
  r1[d] = cd * w1[d];
  r2[d] = hd * w2[d];
  __syncthreads();
  for (int s = 128; s > 0; s >>= 1) {
    if (d < s) { r1[d] += r1[d + s]; r2[d] += r2[d + s]; }
    __syncthreads();
  }
  if (d == 0) {
    float wa = 1.f / (1.f + expf(-(r1[0] + w1b[0])));
    float wb = 1.f / (1.f + expf(-(r2[0] + w2b[0])));
    wan_s = wa / (wa + wb);
  }
  __syncthreads();
  float wan = wan_s;
  out[(size_t)b * HH + d] = wan * cd + (1.f - wan) * hd;
}

// ---------------- launch ----------------
extern "C" void kernel_launch(void* const* d_in, const int* in_sizes, int n_in,
                              void* d_out, int out_size, void* d_ws, size_t ws_size,
                              hipStream_t stream) {
  const float* x   = (const float*)d_in[0];
  const float* wih = (const float*)d_in[1];
  const float* whh = (const float*)d_in[2];
  const float* bih = (const float*)d_in[3];
  const float* bhh = (const float*)d_in[4];
  const float* g1w = (const float*)d_in[5];
  const float* g1b = (const float*)d_in[6];
  const float* g2w = (const float*)d_in[7];
  const float* g2b = (const float*)d_in[8];
  const float* w1w = (const float*)d_in[9];
  const float* w1b = (const float*)d_in[10];
  const float* w2w = (const float*)d_in[11];
  const float* w2b = (const float*)d_in[12];
  float* out = (float*)d_out;

  char* wsb = (char*)d_ws;
  size_t off = 0;
  auto alloc = [&](size_t bytes) {
    void* p = wsb + off;
    off += (bytes + 255) & ~(size_t)255;
    return p;
  };
  float* h0       = (float*)alloc((size_t)BN * HH * 4);
  float* h1       = (float*)alloc((size_t)BN * HH * 4);
  float* wpk      = (float*)alloc((size_t)2 * NCH * CHF * 4);
  float* centers  = (float*)alloc(KK * HH * 4);
  double* cnorm   = (double*)alloc(KK * 8);
  int*   codes    = (int*)alloc(BN * 4);
  int*   codeg    = (int*)alloc(BN * 4);
  uint32_t* keys  = (uint32_t*)alloc(BN * 4);
  int*   vals1    = (int*)alloc(BN * 4);
  int*   vals2    = (int*)alloc(BN * 4);
  uint32_t* sk    = (uint32_t*)alloc(4 * 4);
  double* psum    = (double*)alloc((size_t)UB * KK * HH * 8);
  float* pcnt     = (float*)alloc(UB * KK * 4);
  float* hh1      = (float*)alloc(KK * HH * 4);
  float* hh2      = (float*)alloc(KK * HH * 4);

  k_zero<<<(BN * HH + 255) / 256, 256, 0, stream>>>(h0, BN * HH);
  k_pack_w<<<(2 * NCH * CHF + 255) / 256, 256, 0, stream>>>(wih, whh, wpk);

  dim3 gru_grid(BN / ROWS, 2);
  for (int t = 0; t < TT; ++t) {
    const float* hin = (t & 1) ? h1 : h0;
    float* hout      = (t & 1) ? h0 : h1;
    k_gru_step<<<gru_grid, GTHREADS, 0, stream>>>(x, wpk, bih, bhh, hin, hout, t);
  }
  float* h = h0;  // T even -> final state in h0

  k_prng_setup<<<1, 1, 0, stream>>>(sk);
  k_genkeys<<<32, 256, 0, stream>>>(sk, 0, keys);
  k_ranksort<<<BN / RSE, 256, 0, stream>>>(keys, (const int*)nullptr, vals1);
  k_genkeys<<<32, 256, 0, stream>>>(sk, 1, keys);
  k_ranksort<<<BN / RSE, 256, 0, stream>>>(keys, vals1, vals2);

  k_init_centers<<<KK, HH, 0, stream>>>(h, vals2, centers, cnorm);
  k_assign<<<BN / 128, 128, 0, stream>>>(h, centers, cnorm, codes);
  for (int it = 0; it < KM_ITERS_N; ++it) {
    k_upd_partial<<<UB, 256, 0, stream>>>(h, codes, psum, pcnt);
    k_upd_final<<<KK, HH, 0, stream>>>(psum, pcnt, centers, cnorm);
    k_assign<<<BN / 128, 128, 0, stream>>>(h, centers, cnorm, codes);
  }
  k_upd_partial<<<UB, 256, 0, stream>>>(h, codes, psum, pcnt);
  k_upd_final<<<KK, HH, 0, stream>>>(psum, pcnt, centers, cnorm);

  k_gumbel<<<BN / 128, 128, 0, stream>>>(h, centers, codeg);
  k_gcn<<<KK, HH, 0, stream>>>(centers, g1w, g1b, hh1);
  k_gcn<<<KK, HH, 0, stream>>>(hh1, g2w, g2b, hh2);
  k_final<<<BN, HH, 0, stream>>>(h, hh2, codeg, w1w, w1b, w2w, w2b, out);
}

// Round 9
// 11351.166 us; speedup vs baseline: 1.6446x; 1.0431x over previous
//
#include <hip/hip_runtime.h>
#include <hip/hip_bf16.h>
#include <stdint.h>

#define BN 8192
#define TT 128
#define II 64
#define HH 256
#define GG 768
#define KK 12
#define KM_ITERS_N 25
#define UB 64
#define UPB (BN/UB)

typedef __attribute__((ext_vector_type(8))) short bf16x8;
typedef __attribute__((ext_vector_type(16))) float f32x16;

// ---------------- threefry2x32 (JAX-exact) ----------------
__device__ __forceinline__ uint32_t rotl32(uint32_t v, int d) {
  return (v << d) | (v >> (32 - d));
}
__device__ __forceinline__ void tf2x32(uint32_t k0, uint32_t k1,
                                       uint32_t x0, uint32_t x1,
                                       uint32_t& o0, uint32_t& o1) {
  uint32_t ks2 = k0 ^ k1 ^ 0x1BD11BDAu;
  x0 += k0; x1 += k1;
#define TFR(r) { x0 += x1; x1 = rotl32(x1, r); x1 ^= x0; }
  TFR(13); TFR(15); TFR(26); TFR(6);   x0 += k1;  x1 += ks2 + 1u;
  TFR(17); TFR(29); TFR(16); TFR(24);  x0 += ks2; x1 += k0 + 2u;
  TFR(13); TFR(15); TFR(26); TFR(6);   x0 += k0;  x1 += k1 + 3u;
  TFR(17); TFR(29); TFR(16); TFR(24);  x0 += k1;  x1 += ks2 + 4u;
  TFR(13); TFR(15); TFR(26); TFR(6);   x0 += ks2; x1 += k0 + 5u;
#undef TFR
  o0 = x0; o1 = x1;
}
__device__ __forceinline__ float bits_to_unit(uint32_t bits) {
  uint32_t u = (bits >> 9) | 0x3f800000u;
  return __uint_as_float(u) - 1.0f;
}

// ---------------- bf16 3-way split helpers ----------------
__device__ __forceinline__ short f2bf(float f) {
  uint32_t u = __float_as_uint(f);
  uint32_t r = (u + 0x7fffu + ((u >> 16) & 1u)) >> 16;  // RNE
  return (short)r;
}
__device__ __forceinline__ float bf2f(short s) {
  return __uint_as_float(((uint32_t)(uint16_t)s) << 16);
}
__device__ __forceinline__ void split3(float v, short& a, short& b, short& c) {
  a = f2bf(v); float fa = bf2f(a);
  b = f2bf(v - fa); float fb = bf2f(b);
  c = f2bf(v - fa - fb);
}

// ---------------- zero ----------------
__global__ void k_zero(float* p, int n) {
  int i = blockIdx.x * blockDim.x + threadIdx.x;
  if (i < n) p[i] = 0.f;
}

// ---------------- MFMA GRU ----------------
// Per step: G[8192x768] = [x_t | h] (K=320) @ [wih | whh]^T via 32x32x16 bf16 MFMA,
// 3-way split (6 products). Block: 64 rows x 64 d (192 packed cols = gate-triple [R|Z|N]).
// Grid (128 row-blocks, 4 d-blocks), 256 threads = 4 waves.
#define RB 64
#define KSTEPS 20
#define BKBYTES 18432  // per (cb,ks): 3 planes * 192 cols * 16k * 2B

#define AOFF(buf, p, row, kh) \
  ((buf) * 6144 + (p) * 2048 + (((row) * 32 + (kh) * 16) ^ (((row) & 7) << 4)))
#define BOFF(buf, p, col, kh) \
  (12288 + (buf) * BKBYTES + (p) * 6144 + (((col) * 32 + (kh) * 16) ^ (((col) & 7) << 4)))

__global__ void k_pack_mfma(const float* __restrict__ wih, const float* __restrict__ whh,
                            char* __restrict__ wpkB) {
  int u = blockIdx.x * 256 + threadIdx.x;
  if (u >= 4 * KSTEPS * 3 * 192 * 2) return;
  int kh = u & 1; int v = u >> 1;
  int col = v % 192; v /= 192;
  int p = v % 3; v /= 3;
  int ks = v % KSTEPS; int cb = v / KSTEPS;
  int g = col >> 6, dl = col & 63;
  int grow = (g << 8) + cb * 64 + dl;
  short s[8];
#pragma unroll
  for (int j = 0; j < 8; ++j) {
    int k = kh * 8 + j;
    float wv = (ks < 4) ? wih[grow * II + ks * 16 + k]
                        : whh[grow * HH + (ks - 4) * 16 + k];
    short a, b, c;
    split3(wv, a, b, c);
    s[j] = (p == 0) ? a : (p == 1) ? b : c;
  }
  char* dst = wpkB + ((size_t)cb * KSTEPS + ks) * BKBYTES + p * 6144 +
              (((col * 32 + kh * 16)) ^ ((col & 7) << 4));
  short4 lo = {s[0], s[1], s[2], s[3]};
  short4 hi = {s[4], s[5], s[6], s[7]};
  *(short4*)dst = lo;
  *(short4*)(dst + 8) = hi;
}

__global__ __launch_bounds__(256, 2) void k_gru_mfma(
    const float* __restrict__ x, const char* __restrict__ wpkB,
    const float* __restrict__ bih, const float* __restrict__ bhh,
    const float* __restrict__ hf_in,
    const short* __restrict__ hp0, const short* __restrict__ hp1,
    const short* __restrict__ hp2,
    float* __restrict__ hf_out,
    short* __restrict__ hq0, short* __restrict__ hq1, short* __restrict__ hq2,
    int t) {
  __shared__ __align__(16) char smem[49152];  // A: [0,12288) 2buf x 3p x 64r x 16k bf16
                                              // B: [12288,49152) 2buf x 18432
  const int tid = threadIdx.x;
  const int rb = blockIdx.x, cb = blockIdx.y;
  const int row0 = rb * RB;
  const int lane31 = tid & 31;
  const int kh5 = (tid >> 5) & 1;
  const int w = tid >> 6;
  const int rt = w & 1;      // row-tile (32 rows)
  const int dh = w >> 1;     // d-half (32 cols)
  const int arow = rt * 32 + lane31;

  f32x16 accR = (f32x16)0.f, accZ = (f32x16)0.f, accNx = (f32x16)0.f, accNh = (f32x16)0.f;

  auto stage = [&](int ks, int buf) {
    if (ks < 4) {
      // x-phase: read f32, split in-register, write 3 planes
      int i = tid;  // 256 units = 64 rows x 4 quads
      int row = i >> 2, kq = i & 3;
      float4 xv = *(const float4*)(x + (size_t)(row0 + row) * (TT * II) +
                                   (size_t)t * II + ks * 16 + kq * 4);
      short4 s0, s1, s2;
      split3(xv.x, s0.x, s1.x, s2.x);
      split3(xv.y, s0.y, s1.y, s2.y);
      split3(xv.z, s0.z, s1.z, s2.z);
      split3(xv.w, s0.w, s1.w, s2.w);
      int kh = kq >> 1, sub = (kq & 1) * 8;
      *(short4*)(smem + AOFF(buf, 0, row, kh) + sub) = s0;
      *(short4*)(smem + AOFF(buf, 1, row, kh) + sub) = s1;
      *(short4*)(smem + AOFF(buf, 2, row, kh) + sub) = s2;
    } else {
      int kw = (ks - 4) * 16;
      for (int i = tid; i < 384; i += 256) {  // 3p x 64r x 2kh 16B units
        int p = i >> 7, r2 = i & 127, row = r2 >> 1, kh = r2 & 1;
        const short* hp = (p == 0) ? hp0 : (p == 1) ? hp1 : hp2;
        int4 v = *(const int4*)(hp + (size_t)(row0 + row) * HH + kw + kh * 8);
        *(int4*)(smem + AOFF(buf, p, row, kh)) = v;
      }
    }
    const int4* bs = (const int4*)(wpkB + ((size_t)cb * KSTEPS + ks) * BKBYTES);
    int4* bd = (int4*)(smem + 12288 + buf * BKBYTES);
    for (int i = tid; i < BKBYTES / 16; i += 256) bd[i] = bs[i];
  };

  auto compute = [&](int ks, int buf) {
    bf16x8 a0 = *(const bf16x8*)(smem + AOFF(buf, 0, arow, kh5));
    bf16x8 a1 = *(const bf16x8*)(smem + AOFF(buf, 1, arow, kh5));
    bf16x8 a2 = *(const bf16x8*)(smem + AOFF(buf, 2, arow, kh5));
#define SIXMFMA(ACC, COL)                                                          \
    {                                                                              \
      bf16x8 b0 = *(const bf16x8*)(smem + BOFF(buf, 0, (COL), kh5));               \
      bf16x8 b1 = *(const bf16x8*)(smem + BOFF(buf, 1, (COL), kh5));               \
      bf16x8 b2 = *(const bf16x8*)(smem + BOFF(buf, 2, (COL), kh5));               \
      ACC = __builtin_amdgcn_mfma_f32_32x32x16_bf16(a0, b0, ACC, 0, 0, 0);         \
      ACC = __builtin_amdgcn_mfma_f32_32x32x16_bf16(a0, b1, ACC, 0, 0, 0);         \
      ACC = __builtin_amdgcn_mfma_f32_32x32x16_bf16(a1, b0, ACC, 0, 0, 0);         \
      ACC = __builtin_amdgcn_mfma_f32_32x32x16_bf16(a0, b2, ACC, 0, 0, 0);         \
      ACC = __builtin_amdgcn_mfma_f32_32x32x16_bf16(a2, b0, ACC, 0, 0, 0);         \
      ACC = __builtin_amdgcn_mfma_f32_32x32x16_bf16(a1, b1, ACC, 0, 0, 0);         \
    }
    const int colb = dh * 32 + lane31;
    SIXMFMA(accR, colb)
    SIXMFMA(accZ, 64 + colb)
    if (ks < 4) { SIXMFMA(accNx, 128 + colb) }
    else        { SIXMFMA(accNh, 128 + colb) }
#undef SIXMFMA
  };

  stage(0, 0);
  __syncthreads();
  for (int ks = 0; ks < KSTEPS; ++ks) {
    if (ks + 1 < KSTEPS) stage(ks + 1, (ks + 1) & 1);  // other buffer: safe overlap
    compute(ks, ks & 1);
    __syncthreads();
  }

  // epilogue: gates per lane, transpose via LDS, coalesced write + 3-way split
  const int d0 = cb * 64;
  const int dl = dh * 32 + lane31;
  const int d = d0 + dl;
  const float biR = bih[d],          bhR = bhh[d];
  const float biZ = bih[HH + d],     bhZ = bhh[HH + d];
  const float biN = bih[2 * HH + d], bhN = bhh[2 * HH + d];
  float* tr = (float*)smem;  // 64 x 64 f32 = 16 KB
#pragma unroll
  for (int j = 0; j < 16; ++j) {
    int rl = rt * 32 + (j & 3) + ((j >> 2) << 3) + kh5 * 4;
    int grow = row0 + rl;
    float hold = hf_in[(size_t)grow * HH + d];
    float rr = accR[j] + biR + bhR;
    rr = 1.f / (1.f + expf(-rr));
    float zz = accZ[j] + biZ + bhZ;
    zz = 1.f / (1.f + expf(-zz));
    float nn = tanhf(accNx[j] + biN + rr * (accNh[j] + bhN));
    tr[rl * 64 + dl] = (1.f - zz) * nn + zz * hold;
  }
  __syncthreads();
  for (int u = tid; u < 1024; u += 256) {  // 64 rows x 16 float4
    int row = u >> 4, dq = u & 15;
    float4 v = *(const float4*)&tr[row * 64 + dq * 4];
    int grow = row0 + row;
    size_t ob = (size_t)grow * HH + d0 + dq * 4;
    *(float4*)(hf_out + ob) = v;
    short4 sa, sb, sc;
    split3(v.x, sa.x, sb.x, sc.x);
    split3(v.y, sa.y, sb.y, sc.y);
    split3(v.z, sa.z, sb.z, sc.z);
    split3(v.w, sa.w, sb.w, sc.w);
    *(short4*)(hq0 + ob) = sa;
    *(short4*)(hq1 + ob) = sb;
    *(short4*)(hq2 + ob) = sc;
  }
}

// ---------------- PRNG (threefry_partitionable=True semantics) ----------------
__global__ void k_prng_setup(uint32_t* sk) {
  uint32_t k0, k1, s0, s1, t0, t1;
  tf2x32(0u, 7u, 0u, 0u, k0, k1);
  tf2x32(0u, 7u, 0u, 1u, s0, s1);
  tf2x32(k0, k1, 0u, 1u, t0, t1);
  sk[0] = s0; sk[1] = s1;
  sk[2] = t0; sk[3] = t1;
}

__global__ void k_genkeys(const uint32_t* __restrict__ sk, int which,
                          uint32_t* __restrict__ keys) {
  int i = blockIdx.x * blockDim.x + threadIdx.x;
  if (i < BN) {
    uint32_t o0, o1;
    tf2x32(sk[which * 2], sk[which * 2 + 1], 0u, (uint32_t)i, o0, o1);
    keys[i] = o0 ^ o1;
  }
}

// stable rank sort, tiled: 512 blocks x 16 elements, 16 threads/element
#define RSE 16
__global__ __launch_bounds__(256) void k_ranksort(const uint32_t* __restrict__ keys,
                                                  const int* __restrict__ vin,
                                                  int* __restrict__ vout) {
  __shared__ uint32_t skey[BN];
  __shared__ int psum[RSE][17];
  const int tid = threadIdx.x;
  const int g = tid >> 4;
  const int l = tid & 15;
  const int gi = blockIdx.x * RSE + g;
  for (int i = tid; i < BN; i += 256) skey[i] = keys[i];
  __syncthreads();
  const uint32_t ki = skey[gi];
  int rank = 0;
#pragma unroll 8
  for (int j = l; j < BN; j += 16) {
    uint32_t kj = skey[j];
    rank += (kj < ki) || (kj == ki && j < gi);
  }
  psum[g][l] = rank;
  __syncthreads();
  if (l == 0) {
    int r = 0;
#pragma unroll
    for (int tt = 0; tt < 16; ++tt) r += psum[g][tt];
    vout[r] = vin ? vin[gi] : gi;
  }
}

// ---------------- k-means (decisions in f64) ----------------
__global__ void k_init_centers(const float* __restrict__ h, const int* __restrict__ vals2,
                               float* __restrict__ centers, double* __restrict__ cnorm) {
  const int c = blockIdx.x, d = threadIdx.x;
  const int src = vals2[c];
  float v = h[(size_t)src * HH + d];
  centers[c * HH + d] = v;
  __shared__ double red[HH];
  red[d] = (double)v * (double)v;
  __syncthreads();
  for (int s = 128; s > 0; s >>= 1) {
    if (d < s) red[d] += red[d + s];
    __syncthreads();
  }
  if (d == 0) cnorm[c] = red[0];
}

__global__ __launch_bounds__(128) void k_assign(const float* __restrict__ h,
                                                const float* __restrict__ centers,
                                                const double* __restrict__ cnorm,
                                                int* __restrict__ codes) {
  __shared__ float sc[KK * HH];
  __shared__ double sn[KK];
  const int tid = threadIdx.x;
  for (int idx = tid; idx < KK * HH; idx += 128) sc[idx] = centers[idx];
  if (tid < KK) sn[tid] = cnorm[tid];
  __syncthreads();
  const int b = blockIdx.x * 128 + tid;
  const float4* hp = (const float4*)&h[(size_t)b * HH];
  double acc[KK] = {};
  double xn = 0.0;
  for (int k4 = 0; k4 < HH / 4; ++k4) {
    float4 xv = hp[k4];
    double x0 = xv.x, x1 = xv.y, x2 = xv.z, x3 = xv.w;
    xn += x0 * x0 + x1 * x1 + x2 * x2 + x3 * x3;
#pragma unroll
    for (int c = 0; c < KK; ++c) {
      float4 cv = *(const float4*)&sc[c * HH + k4 * 4];
      acc[c] += x0 * cv.x + x1 * cv.y + x2 * cv.z + x3 * cv.w;
    }
  }
  int best = 0;
  double bd = xn - 2.0 * acc[0] + sn[0];
#pragma unroll
  for (int c = 1; c < KK; ++c) {
    double d2 = xn - 2.0 * acc[c] + sn[c];
    if (d2 < bd) { bd = d2; best = c; }
  }
  codes[b] = best;
}

__global__ __launch_bounds__(256) void k_upd_partial(const float* __restrict__ h,
                                                     const int* __restrict__ codes,
                                                     double* __restrict__ psum,
                                                     float* __restrict__ pcnt) {
  __shared__ double acc[KK * HH];
  __shared__ int lc[UPB];
  const int tid = threadIdx.x;
  for (int idx = tid; idx < KK * HH; idx += 256) acc[idx] = 0.0;
  const int p0 = blockIdx.x * UPB;
  for (int idx = tid; idx < UPB; idx += 256) lc[idx] = codes[p0 + idx];
  __syncthreads();
  const int d = tid;
  for (int p = 0; p < UPB; ++p) {
    int c = lc[p];
    acc[c * HH + d] += (double)h[(size_t)(p0 + p) * HH + d];
  }
  if (tid < KK) {
    float cnt = 0.f;
    for (int p = 0; p < UPB; ++p) cnt += (lc[p] == tid) ? 1.f : 0.f;
    pcnt[blockIdx.x * KK + tid] = cnt;
  }
  for (int c = 0; c < KK; ++c)
    psum[((size_t)blockIdx.x * KK + c) * HH + d] = acc[c * HH + d];
}

__global__ void k_upd_final(const double* __restrict__ psum, const float* __restrict__ pcnt,
                            float* __restrict__ centers, double* __restrict__ cnorm) {
  const int c = blockIdx.x, d = threadIdx.x;
  double s = 0.0;
  for (int b = 0; b < UB; ++b) s += psum[((size_t)b * KK + c) * HH + d];
  float cnt = 0.f;
  for (int b = 0; b < UB; ++b) cnt += pcnt[b * KK + c];
  if (cnt <= 0.5f) cnt = 1.f;
  float v = (float)(s / (double)cnt);
  centers[c * HH + d] = v;
  __shared__ double red[HH];
  red[d] = (double)v * (double)v;
  __syncthreads();
  for (int s2 = 128; s2 > 0; s2 >>= 1) {
    if (d < s2) red[d] += red[d + s2];
    __syncthreads();
  }
  if (d == 0) cnorm[c] = red[0];
}

// ---------------- gumbel hard assignment (f64 decisions) ----------------
__global__ __launch_bounds__(128) void k_gumbel(const float* __restrict__ h,
                                                const float* __restrict__ centers,
                                                int* __restrict__ codeg) {
  __shared__ float sc[KK * HH];
  const int tid = threadIdx.x;
  for (int idx = tid; idx < KK * HH; idx += 128) sc[idx] = centers[idx];
  __syncthreads();
  const int b = blockIdx.x * 128 + tid;
  const float4* hp = (const float4*)&h[(size_t)b * HH];
  double acc[KK] = {};
  for (int k4 = 0; k4 < HH / 4; ++k4) {
    float4 xv = hp[k4];
    double x0 = xv.x, x1 = xv.y, x2 = xv.z, x3 = xv.w;
#pragma unroll
    for (int c = 0; c < KK; ++c) {
      float4 cv = *(const float4*)&sc[c * HH + k4 * 4];
      acc[c] += x0 * cv.x + x1 * cv.y + x2 * cv.z + x3 * cv.w;
    }
  }
  int best = 0;
  double bv = -1e300;
#pragma unroll
  for (int c = 0; c < KK; ++c) {
    double e = acc[c] > 0.0 ? acc[c] : 0.0;
    uint32_t j = (uint32_t)(b * KK + c);
    uint32_t o0, o1;
    tf2x32(0u, 42u, 0u, j, o0, o1);
    double U = (double)bits_to_unit(o0 ^ o1);
    double g = -log(-log(U + 1e-20) + 1e-20);
    double v = e + g;
    if (v > bv) { bv = v; best = c; }
  }
  codeg[b] = best;
}

// ---------------- GCN layer (adj = I) ----------------
__global__ void k_gcn(const float* __restrict__ in, const float* __restrict__ w,
                      const float* __restrict__ bias, float* __restrict__ out) {
  const int c = blockIdx.x, d = threadIdx.x;
  __shared__ float si[HH];
  si[d] = in[c * HH + d];
  __syncthreads();
  float acc = 0.f;
  for (int k = 0; k < HH; ++k) acc += si[k] * w[k * HH + d];
  acc += bias[d];
  out[c * HH + d] = acc > 0.f ? acc : 0.f;
}

// ---------------- final blend (f32 output) ----------------
__global__ __launch_bounds__(256) void k_final(const float* __restrict__ h,
                                               const float* __restrict__ h2,
                                               const int* __restrict__ codeg,
                                               const float* __restrict__ w1,
                                               const float* __restrict__ w1b,
                                               const float* __restrict__ w2,
                                               const float* __restrict__ w2b,
                                               float* __restrict__ out) {
  const int b = blockIdx.x, d = threadIdx.x;
  const int cg = codeg[b];
  const float cd = h2[cg * HH + d];
  const float hd = h[(size_t)b * HH + d];
  __shared__ float r1[HH], r2[HH];
  __shared__ float wan_s;
  r1[d] = cd * w1[d];
  r2[d] = hd * w2[d];
  __syncthreads();
  for (int s = 128; s > 0; s >>= 1) {
    if (d < s) { r1[d] += r1[d + s]; r2[d] += r2[d + s]; }
    __syncthreads();
  }
  if (d == 0) {
    float wa = 1.f / (1.f + expf(-(r1[0] + w1b[0])));
    float wb = 1.f / (1.f + expf(-(r2[0] + w2b[0])));
    wan_s = wa / (wa + wb);
  }
  __syncthreads();
  float wan = wan_s;
  out[(size_t)b * HH + d] = wan * cd + (1.f - wan) * hd;
}

// ---------------- launch ----------------
extern "C" void kernel_launch(void* const* d_in, const int* in_sizes, int n_in,
                              void* d_out, int out_size, void* d_ws, size_t ws_size,
                              hipStream_t stream) {
  const float* x   = (const float*)d_in[0];
  const float* wih = (const float*)d_in[1];
  const float* whh = (const float*)d_in[2];
  const float* bih = (const float*)d_in[3];
  const float* bhh = (const float*)d_in[4];
  const float* g1w = (const float*)d_in[5];
  const float* g1b = (const float*)d_in[6];
  const float* g2w = (const float*)d_in[7];
  const float* g2b = (const float*)d_in[8];
  const float* w1w = (const float*)d_in[9];
  const float* w1b = (const float*)d_in[10];
  const float* w2w = (const float*)d_in[11];
  const float* w2b = (const float*)d_in[12];
  float* out = (float*)d_out;

  char* wsb = (char*)d_ws;
  size_t off = 0;
  auto alloc = [&](size_t bytes) {
    void* p = wsb + off;
    off += (bytes + 255) & ~(size_t)255;
    return p;
  };
  float* hf0      = (float*)alloc((size_t)BN * HH * 4);
  float* hf1      = (float*)alloc((size_t)BN * HH * 4);
  short* hpa0     = (short*)alloc((size_t)BN * HH * 2);
  short* hpa1     = (short*)alloc((size_t)BN * HH * 2);
  short* hpa2     = (short*)alloc((size_t)BN * HH * 2);
  short* hpb0     = (short*)alloc((size_t)BN * HH * 2);
  short* hpb1     = (short*)alloc((size_t)BN * HH * 2);
  short* hpb2     = (short*)alloc((size_t)BN * HH * 2);
  char*  wpkB     = (char*)alloc((size_t)4 * KSTEPS * BKBYTES);
  float* centers  = (float*)alloc(KK * HH * 4);
  double* cnorm   = (double*)alloc(KK * 8);
  int*   codes    = (int*)alloc(BN * 4);
  int*   codeg    = (int*)alloc(BN * 4);
  uint32_t* keys  = (uint32_t*)alloc(BN * 4);
  int*   vals1    = (int*)alloc(BN * 4);
  int*   vals2    = (int*)alloc(BN * 4);
  uint32_t* sk    = (uint32_t*)alloc(4 * 4);
  double* psum    = (double*)alloc((size_t)UB * KK * HH * 8);
  float* pcnt     = (float*)alloc(UB * KK * 4);
  float* hh1      = (float*)alloc(KK * HH * 4);
  float* hh2      = (float*)alloc(KK * HH * 4);

  k_zero<<<(BN * HH + 255) / 256, 256, 0, stream>>>(hf0, BN * HH);
  k_zero<<<(BN * HH / 2 + 255) / 256, 256, 0, stream>>>((float*)hpa0, BN * HH / 2);
  k_zero<<<(BN * HH / 2 + 255) / 256, 256, 0, stream>>>((float*)hpa1, BN * HH / 2);
  k_zero<<<(BN * HH / 2 + 255) / 256, 256, 0, stream>>>((float*)hpa2, BN * HH / 2);
  k_pack_mfma<<<(4 * KSTEPS * 3 * 192 * 2 + 255) / 256, 256, 0, stream>>>(wih, whh, wpkB);

  dim3 gru_grid(BN / RB, 4);
  for (int t = 0; t < TT; ++t) {
    if ((t & 1) == 0)
      k_gru_mfma<<<gru_grid, 256, 0, stream>>>(x, wpkB, bih, bhh,
          hf0, hpa0, hpa1, hpa2, hf1, hpb0, hpb1, hpb2, t);
    else
      k_gru_mfma<<<gru_grid, 256, 0, stream>>>(x, wpkB, bih, bhh,
          hf1, hpb0, hpb1, hpb2, hf0, hpa0, hpa1, hpa2, t);
  }
  float* h = hf0;  // T=128 even -> final state in hf0

  k_prng_setup<<<1, 1, 0, stream>>>(sk);
  k_genkeys<<<32, 256, 0, stream>>>(sk, 0, keys);
  k_ranksort<<<BN / RSE, 256, 0, stream>>>(keys, (const int*)nullptr, vals1);
  k_genkeys<<<32, 256, 0, stream>>>(sk, 1, keys);
  k_ranksort<<<BN / RSE, 256, 0, stream>>>(keys, vals1, vals2);

  k_init_centers<<<KK, HH, 0, stream>>>(h, vals2, centers, cnorm);
  k_assign<<<BN / 128, 128, 0, stream>>>(h, centers, cnorm, codes);
  for (int it = 0; it < KM_ITERS_N; ++it) {
    k_upd_partial<<<UB, 256, 0, stream>>>(h, codes, psum, pcnt);
    k_upd_final<<<KK, HH, 0, stream>>>(psum, pcnt, centers, cnorm);
    k_assign<<<BN / 128, 128, 0, stream>>>(h, centers, cnorm, codes);
  }
  k_upd_partial<<<UB, 256, 0, stream>>>(h, codes, psum, pcnt);
  k_upd_final<<<KK, HH, 0, stream>>>(psum, pcnt, centers, cnorm);

  k_gumbel<<<BN / 128, 128, 0, stream>>>(h, centers, codeg);
  k_gcn<<<KK, HH, 0, stream>>>(centers, g1w, g1b, hh1);
  k_gcn<<<KK, HH, 0, stream>>>(hh1, g2w, g2b, hh2);
  k_final<<<BN, HH, 0, stream>>>(h, hh2, codeg, w1w, w1b, w2w, w2b, out);
}

// Round 10
// 7544.316 us; speedup vs baseline: 2.4744x; 1.5046x over previous
//
#include <hip/hip_runtime.h>
#include <hip/hip_bf16.h>
#include <stdint.h>

#define BN 8192
#define TT 128
#define II 64
#define HH 256
#define GG 768
#define KK 12
#define KM_ITERS_N 25
#define UB 64
#define UPB (BN/UB)
#define KSTEPS 20

typedef __attribute__((ext_vector_type(8))) short bf16x8;
typedef __attribute__((ext_vector_type(16))) float f32x16;

// ---------------- threefry2x32 (JAX-exact) ----------------
__device__ __forceinline__ uint32_t rotl32(uint32_t v, int d) {
  return (v << d) | (v >> (32 - d));
}
__device__ __forceinline__ void tf2x32(uint32_t k0, uint32_t k1,
                                       uint32_t x0, uint32_t x1,
                                       uint32_t& o0, uint32_t& o1) {
  uint32_t ks2 = k0 ^ k1 ^ 0x1BD11BDAu;
  x0 += k0; x1 += k1;
#define TFR(r) { x0 += x1; x1 = rotl32(x1, r); x1 ^= x0; }
  TFR(13); TFR(15); TFR(26); TFR(6);   x0 += k1;  x1 += ks2 + 1u;
  TFR(17); TFR(29); TFR(16); TFR(24);  x0 += ks2; x1 += k0 + 2u;
  TFR(13); TFR(15); TFR(26); TFR(6);   x0 += k0;  x1 += k1 + 3u;
  TFR(17); TFR(29); TFR(16); TFR(24);  x0 += k1;  x1 += ks2 + 4u;
  TFR(13); TFR(15); TFR(26); TFR(6);   x0 += ks2; x1 += k0 + 5u;
#undef TFR
  o0 = x0; o1 = x1;
}
__device__ __forceinline__ float bits_to_unit(uint32_t bits) {
  uint32_t u = (bits >> 9) | 0x3f800000u;
  return __uint_as_float(u) - 1.0f;
}

// ---------------- bf16 3-way split helpers ----------------
__device__ __forceinline__ short f2bf(float f) {
  uint32_t u = __float_as_uint(f);
  uint32_t r = (u + 0x7fffu + ((u >> 16) & 1u)) >> 16;  // RNE
  return (short)r;
}
__device__ __forceinline__ float bf2f(short s) {
  return __uint_as_float(((uint32_t)(uint16_t)s) << 16);
}
__device__ __forceinline__ void split3(float v, short& a, short& b, short& c) {
  a = f2bf(v); float fa = bf2f(a);
  b = f2bf(v - fa); float fb = bf2f(b);
  c = f2bf(v - fa - fb);
}

// ---------------- zero ----------------
__global__ void k_zero(float* p, int n) {
  int i = blockIdx.x * blockDim.x + threadIdx.x;
  if (i < n) p[i] = 0.f;
}

// ---------------- weight pack: per-fragment contiguous 1KB blocks ----------------
// wpk2[cb(2)][ks(20)][cf(12)][p(3)][lane(64)*16B]
// lane<32: col=cf*32+lane, k-low 8; lane>=32: col=lane-32+cf*32, k-high 8.
// col in [0,384): gate=col>>7, dl=col&127, grow=gate*256+cb*128+dl.
__global__ void k_pack2(const float* __restrict__ wih, const float* __restrict__ whh,
                        char* __restrict__ wpk2) {
  int u = blockIdx.x * 256 + threadIdx.x;
  if (u >= 2 * KSTEPS * 12 * 3 * 64) return;
  int lane = u & 63; int rest = u >> 6;
  int p = rest % 3; rest /= 3;
  int cf = rest % 12; rest /= 12;
  int ks = rest % KSTEPS; int cb = rest / KSTEPS;
  int l31 = lane & 31, khalf = lane >> 5;
  int col = cf * 32 + l31;
  int gate = col >> 7, dl = col & 127;
  int grow = gate * 256 + cb * 128 + dl;
  short s[8];
#pragma unroll
  for (int j = 0; j < 8; ++j) {
    int k = khalf * 8 + j;
    float wv = (ks < 4) ? wih[grow * II + ks * 16 + k]
                        : whh[grow * HH + (ks - 4) * 16 + k];
    short a, b, c;
    split3(wv, a, b, c);
    s[j] = (p == 0) ? a : (p == 1) ? b : c;
  }
  char* dst = wpk2 + (size_t)u * 16;
  short4 lo = {s[0], s[1], s[2], s[3]};
  short4 hi = {s[4], s[5], s[6], s[7]};
  *(short4*)dst = lo;
  *(short4*)(dst + 8) = hi;
}

// ---------------- MFMA GRU v2 ----------------
// grid (256 rowblocks x 2 cb), 256 thr = 4 waves. Block = 32 rows x 384 packed cols.
// Wave w covers cols w*96..+95 (3 fragments). B direct from L2 (no LDS).
// A (x/h 3-plane tile) via 6KB LDS dbuf, layout [buf][p][kh][row]*16B (conflict-free).
// aX/aH separate accs; R/Z summed in epilogue (additive), N kept split.
#define AADDR(buf, p, kh, row) (((((buf) * 3 + (p)) * 2 + (kh)) * 32 + (row)) * 16)

__global__ __launch_bounds__(256, 2) void k_gru_v2(
    const float* __restrict__ x, const char* __restrict__ wpk2,
    const float* __restrict__ bih, const float* __restrict__ bhh,
    const float* __restrict__ hf_in,
    const short* __restrict__ hp0, const short* __restrict__ hp1,
    const short* __restrict__ hp2,
    float* __restrict__ hf_out,
    short* __restrict__ hq0, short* __restrict__ hq1, short* __restrict__ hq2,
    int t) {
  __shared__ __align__(16) char smem[73728];  // A dbuf [0,6144); gl at 8192 (64KB)
  float* gl = (float*)(smem + 8192);          // [32 rows][512]: R,Z,Nx,Nh slots
  const int tid = threadIdx.x;
  const int rb = blockIdx.x, cb = blockIdx.y;
  const int row0 = rb * 32;
  const int l = tid & 63, l31 = l & 31, kh5 = l >> 5;
  const int w = tid >> 6;

  f32x16 aX[3], aH[3];
#pragma unroll
  for (int c = 0; c < 3; ++c) { aX[c] = (f32x16)0.f; aH[c] = (f32x16)0.f; }

  auto stage = [&](int ks, int buf) {
    if (ks < 4) {
      if (tid < 64) {
        int row = tid >> 1, kh = tid & 1;
        const float* xp = x + (size_t)(row0 + row) * (TT * II) + (size_t)t * II +
                          ks * 16 + kh * 8;
        float4 v0 = *(const float4*)xp;
        float4 v1 = *(const float4*)(xp + 4);
        short4 a0, b0, c0, a1, b1, c1;
        split3(v0.x, a0.x, b0.x, c0.x); split3(v0.y, a0.y, b0.y, c0.y);
        split3(v0.z, a0.z, b0.z, c0.z); split3(v0.w, a0.w, b0.w, c0.w);
        split3(v1.x, a1.x, b1.x, c1.x); split3(v1.y, a1.y, b1.y, c1.y);
        split3(v1.z, a1.z, b1.z, c1.z); split3(v1.w, a1.w, b1.w, c1.w);
        char* d0 = smem + AADDR(buf, 0, kh, row);
        char* d1 = smem + AADDR(buf, 1, kh, row);
        char* d2 = smem + AADDR(buf, 2, kh, row);
        *(short4*)d0 = a0; *(short4*)(d0 + 8) = a1;
        *(short4*)d1 = b0; *(short4*)(d1 + 8) = b1;
        *(short4*)d2 = c0; *(short4*)(d2 + 8) = c1;
      }
    } else {
      if (tid < 192) {
        int p = tid >> 6;          // wave-uniform
        int r2 = tid & 63, row = r2 >> 1, kh = r2 & 1;
        const short* hp = (p == 0) ? hp0 : (p == 1) ? hp1 : hp2;
        int4 v = *(const int4*)(hp + (size_t)(row0 + row) * HH + (ks - 4) * 16 + kh * 8);
        *(int4*)(smem + AADDR(buf, p, kh, row)) = v;
      }
    }
  };

  stage(0, 0);
  __syncthreads();

  for (int ks = 0; ks < KSTEPS; ++ks) {
    const int buf = ks & 1;
    bf16x8 a0 = *(const bf16x8*)(smem + AADDR(buf, 0, kh5, l31));
    bf16x8 a1 = *(const bf16x8*)(smem + AADDR(buf, 1, kh5, l31));
    bf16x8 a2 = *(const bf16x8*)(smem + AADDR(buf, 2, kh5, l31));
    const char* bks = wpk2 + (((size_t)cb * KSTEPS + ks) * 12) * 3072;
#pragma unroll
    for (int c = 0; c < 3; ++c) {
      const char* bf = bks + (size_t)(w * 3 + c) * 3072 + (size_t)l * 16;
      bf16x8 b0 = *(const bf16x8*)(bf);
      bf16x8 b1 = *(const bf16x8*)(bf + 1024);
      bf16x8 b2 = *(const bf16x8*)(bf + 2048);
      f32x16 acc = (ks < 4) ? aX[c] : aH[c];
      acc = __builtin_amdgcn_mfma_f32_32x32x16_bf16(a0, b0, acc, 0, 0, 0);
      acc = __builtin_amdgcn_mfma_f32_32x32x16_bf16(a0, b1, acc, 0, 0, 0);
      acc = __builtin_amdgcn_mfma_f32_32x32x16_bf16(a1, b0, acc, 0, 0, 0);
      acc = __builtin_amdgcn_mfma_f32_32x32x16_bf16(a0, b2, acc, 0, 0, 0);
      acc = __builtin_amdgcn_mfma_f32_32x32x16_bf16(a2, b0, acc, 0, 0, 0);
      acc = __builtin_amdgcn_mfma_f32_32x32x16_bf16(a1, b1, acc, 0, 0, 0);
      if (ks < 4) aX[c] = acc; else aH[c] = acc;
    }
    if (ks + 1 < KSTEPS) stage(ks + 1, buf ^ 1);
    __syncthreads();
  }

  // ---- epilogue: accs -> gl, then gates + stores ----
#pragma unroll
  for (int c = 0; c < 3; ++c) {
    const int gcol = w * 96 + c * 32 + l31;
#pragma unroll
    for (int j = 0; j < 16; ++j) {
      int row = (j & 3) + ((j >> 2) << 3) + kh5 * 4;
      float vx = aX[c][j], vh = aH[c][j];
      if (gcol < 256) {
        gl[row * 512 + gcol] = vx + vh;
      } else {
        gl[row * 512 + gcol] = vx;
        gl[row * 512 + gcol + 128] = vh;
      }
    }
  }
  __syncthreads();

  {
    const int dl = tid & 127, rh = tid >> 7;
    const int d = cb * 128 + dl;
    const float biR = bih[d],          bhR = bhh[d];
    const float biZ = bih[HH + d],     bhZ = bhh[HH + d];
    const float biN = bih[2 * HH + d], bhN = bhh[2 * HH + d];
#pragma unroll
    for (int e = 0; e < 16; ++e) {
      int row = rh * 16 + e;
      float R  = gl[row * 512 + dl];
      float Z  = gl[row * 512 + 128 + dl];
      float Nx = gl[row * 512 + 256 + dl];
      float Nh = gl[row * 512 + 384 + dl];
      size_t ob = (size_t)(row0 + row) * HH + d;
      float hold = hf_in[ob];
      float rr = 1.f / (1.f + expf(-(R + biR + bhR)));
      float zz = 1.f / (1.f + expf(-(Z + biZ + bhZ)));
      float nn = tanhf(Nx + biN + rr * (Nh + bhN));
      float hnew = (1.f - zz) * nn + zz * hold;
      hf_out[ob] = hnew;
      short a, b, c2;
      split3(hnew, a, b, c2);
      hq0[ob] = a; hq1[ob] = b; hq2[ob] = c2;
    }
  }
}

// ---------------- PRNG (threefry_partitionable=True semantics) ----------------
__global__ void k_prng_setup(uint32_t* sk) {
  uint32_t k0, k1, s0, s1, t0, t1;
  tf2x32(0u, 7u, 0u, 0u, k0, k1);
  tf2x32(0u, 7u, 0u, 1u, s0, s1);
  tf2x32(k0, k1, 0u, 1u, t0, t1);
  sk[0] = s0; sk[1] = s1;
  sk[2] = t0; sk[3] = t1;
}

__global__ void k_genkeys(const uint32_t* __restrict__ sk, int which,
                          uint32_t* __restrict__ keys) {
  int i = blockIdx.x * blockDim.x + threadIdx.x;
  if (i < BN) {
    uint32_t o0, o1;
    tf2x32(sk[which * 2], sk[which * 2 + 1], 0u, (uint32_t)i, o0, o1);
    keys[i] = o0 ^ o1;
  }
}

// stable rank sort, tiled: 512 blocks x 16 elements, 16 threads/element
#define RSE 16
__global__ __launch_bounds__(256) void k_ranksort(const uint32_t* __restrict__ keys,
                                                  const int* __restrict__ vin,
                                                  int* __restrict__ vout) {
  __shared__ uint32_t skey[BN];
  __shared__ int psum[RSE][17];
  const int tid = threadIdx.x;
  const int g = tid >> 4;
  const int l = tid & 15;
  const int gi = blockIdx.x * RSE + g;
  for (int i = tid; i < BN; i += 256) skey[i] = keys[i];
  __syncthreads();
  const uint32_t ki = skey[gi];
  int rank = 0;
#pragma unroll 8
  for (int j = l; j < BN; j += 16) {
    uint32_t kj = skey[j];
    rank += (kj < ki) || (kj == ki && j < gi);
  }
  psum[g][l] = rank;
  __syncthreads();
  if (l == 0) {
    int r = 0;
#pragma unroll
    for (int tt = 0; tt < 16; ++tt) r += psum[g][tt];
    vout[r] = vin ? vin[gi] : gi;
  }
}

// ---------------- k-means (decisions in f64) ----------------
__global__ void k_init_centers(const float* __restrict__ h, const int* __restrict__ vals2,
                               float* __restrict__ centers, double* __restrict__ cnorm) {
  const int c = blockIdx.x, d = threadIdx.x;
  const int src = vals2[c];
  float v = h[(size_t)src * HH + d];
  centers[c * HH + d] = v;
  __shared__ double red[HH];
  red[d] = (double)v * (double)v;
  __syncthreads();
  for (int s = 128; s > 0; s >>= 1) {
    if (d < s) red[d] += red[d + s];
    __syncthreads();
  }
  if (d == 0) cnorm[c] = red[0];
}

__global__ __launch_bounds__(128) void k_assign(const float* __restrict__ h,
                                                const float* __restrict__ centers,
                                                const double* __restrict__ cnorm,
                                                int* __restrict__ codes) {
  __shared__ float sc[KK * HH];
  __shared__ double sn[KK];
  const int tid = threadIdx.x;
  for (int idx = tid; idx < KK * HH; idx += 128) sc[idx] = centers[idx];
  if (tid < KK) sn[tid] = cnorm[tid];
  __syncthreads();
  const int b = blockIdx.x * 128 + tid;
  const float4* hp = (const float4*)&h[(size_t)b * HH];
  double acc[KK] = {};
  double xn = 0.0;
  for (int k4 = 0; k4 < HH / 4; ++k4) {
    float4 xv = hp[k4];
    double x0 = xv.x, x1 = xv.y, x2 = xv.z, x3 = xv.w;
    xn += x0 * x0 + x1 * x1 + x2 * x2 + x3 * x3;
#pragma unroll
    for (int c = 0; c < KK; ++c) {
      float4 cv = *(const float4*)&sc[c * HH + k4 * 4];
      acc[c] += x0 * cv.x + x1 * cv.y + x2 * cv.z + x3 * cv.w;
    }
  }
  int best = 0;
  double bd = xn - 2.0 * acc[0] + sn[0];
#pragma unroll
  for (int c = 1; c < KK; ++c) {
    double d2 = xn - 2.0 * acc[c] + sn[c];
    if (d2 < bd) { bd = d2; best = c; }
  }
  codes[b] = best;
}

__global__ __launch_bounds__(256) void k_upd_partial(const float* __restrict__ h,
                                                     const int* __restrict__ codes,
                                                     double* __restrict__ psum,
                                                     float* __restrict__ pcnt) {
  __shared__ double acc[KK * HH];
  __shared__ int lc[UPB];
  const int tid = threadIdx.x;
  for (int idx = tid; idx < KK * HH; idx += 256) acc[idx] = 0.0;
  const int p0 = blockIdx.x * UPB;
  for (int idx = tid; idx < UPB; idx += 256) lc[idx] = codes[p0 + idx];
  __syncthreads();
  const int d = tid;
  for (int p = 0; p < UPB; ++p) {
    int c = lc[p];
    acc[c * HH + d] += (double)h[(size_t)(p0 + p) * HH + d];
  }
  if (tid < KK) {
    float cnt = 0.f;
    for (int p = 0; p < UPB; ++p) cnt += (lc[p] == tid) ? 1.f : 0.f;
    pcnt[blockIdx.x * KK + tid] = cnt;
  }
  for (int c = 0; c < KK; ++c)
    psum[((size_t)blockIdx.x * KK + c) * HH + d] = acc[c * HH + d];
}

__global__ void k_upd_final(const double* __restrict__ psum, const float* __restrict__ pcnt,
                            float* __restrict__ centers, double* __restrict__ cnorm) {
  const int c = blockIdx.x, d = threadIdx.x;
  double s = 0.0;
  for (int b = 0; b < UB; ++b) s += psum[((size_t)b * KK + c) * HH + d];
  float cnt = 0.f;
  for (int b = 0; b < UB; ++b) cnt += pcnt[b * KK + c];
  if (cnt <= 0.5f) cnt = 1.f;
  float v = (float)(s / (double)cnt);
  centers[c * HH + d] = v;
  __shared__ double red[HH];
  red[d] = (double)v * (double)v;
  __syncthreads();
  for (int s2 = 128; s2 > 0; s2 >>= 1) {
    if (d < s2) red[d] += red[d + s2];
    __syncthreads();
  }
  if (d == 0) cnorm[c] = red[0];
}

// ---------------- gumbel hard assignment (f64 decisions) ----------------
__global__ __launch_bounds__(128) void k_gumbel(const float* __restrict__ h,
                                                const float* __restrict__ centers,
                                                int* __restrict__ codeg) {
  __shared__ float sc[KK * HH];
  const int tid = threadIdx.x;
  for (int idx = tid; idx < KK * HH; idx += 128) sc[idx] = centers[idx];
  __syncthreads();
  const int b = blockIdx.x * 128 + tid;
  const float4* hp = (const float4*)&h[(size_t)b * HH];
  double acc[KK] = {};
  for (int k4 = 0; k4 < HH / 4; ++k4) {
    float4 xv = hp[k4];
    double x0 = xv.x, x1 = xv.y, x2 = xv.z, x3 = xv.w;
#pragma unroll
    for (int c = 0; c < KK; ++c) {
      float4 cv = *(const float4*)&sc[c * HH + k4 * 4];
      acc[c] += x0 * cv.x + x1 * cv.y + x2 * cv.z + x3 * cv.w;
    }
  }
  int best = 0;
  double bv = -1e300;
#pragma unroll
  for (int c = 0; c < KK; ++c) {
    double e = acc[c] > 0.0 ? acc[c] : 0.0;
    uint32_t j = (uint32_t)(b * KK + c);
    uint32_t o0, o1;
    tf2x32(0u, 42u, 0u, j, o0, o1);
    double U = (double)bits_to_unit(o0 ^ o1);
    double g = -log(-log(U + 1e-20) + 1e-20);
    double v = e + g;
    if (v > bv) { bv = v; best = c; }
  }
  codeg[b] = best;
}

// ---------------- GCN layer (adj = I) ----------------
__global__ void k_gcn(const float* __restrict__ in, const float* __restrict__ w,
                      const float* __restrict__ bias, float* __restrict__ out) {
  const int c = blockIdx.x, d = threadIdx.x;
  __shared__ float si[HH];
  si[d] = in[c * HH + d];
  __syncthreads();
  float acc = 0.f;
  for (int k = 0; k < HH; ++k) acc += si[k] * w[k * HH + d];
  acc += bias[d];
  out[c * HH + d] = acc > 0.f ? acc : 0.f;
}

// ---------------- final blend (f32 output) ----------------
__global__ __launch_bounds__(256) void k_final(const float* __restrict__ h,
                                               const float* __restrict__ h2,
                                               const int* __restrict__ codeg,
                                               const float* __restrict__ w1,
                                               const float* __restrict__ w1b,
                                               const float* __restrict__ w2,
                                               const float* __restrict__ w2b,
                                               float* __restrict__ out) {
  const int b = blockIdx.x, d = threadIdx.x;
  const int cg = codeg[b];
  const float cd = h2[cg * HH + d];
  const float hd = h[(size_t)b * HH + d];
  __shared__ float r1[HH], r2[HH];
  __shared__ float wan_s;
  r1[d] = cd * w1[d];
  r2[d] = hd * w2[d];
  __syncthreads();
  for (int s = 128; s > 0; s >>= 1) {
    if (d < s) { r1[d] += r1[d + s]; r2[d] += r2[d + s]; }
    __syncthreads();
  }
  if (d == 0) {
    float wa = 1.f / (1.f + expf(-(r1[0] + w1b[0])));
    float wb = 1.f / (1.f + expf(-(r2[0] + w2b[0])));
    wan_s = wa / (wa + wb);
  }
  __syncthreads();
  float wan = wan_s;
  out[(size_t)b * HH + d] = wan * cd + (1.f - wan) * hd;
}

// ---------------- launch ----------------
extern "C" void kernel_launch(void* const* d_in, const int* in_sizes, int n_in,
                              void* d_out, int out_size, void* d_ws, size_t ws_size,
                              hipStream_t stream) {
  const float* x   = (const float*)d_in[0];
  const float* wih = (const float*)d_in[1];
  const float* whh = (const float*)d_in[2];
  const float* bih = (const float*)d_in[3];
  const float* bhh = (const float*)d_in[4];
  const float* g1w = (const float*)d_in[5];
  const float* g1b = (const float*)d_in[6];
  const float* g2w = (const float*)d_in[7];
  const float* g2b = (const float*)d_in[8];
  const float* w1w = (const float*)d_in[9];
  const float* w1b = (const float*)d_in[10];
  const float* w2w = (const float*)d_in[11];
  const float* w2b = (const float*)d_in[12];
  float* out = (float*)d_out;

  char* wsb = (char*)d_ws;
  size_t off = 0;
  auto alloc = [&](size_t bytes) {
    void* p = wsb + off;
    off += (bytes + 255) & ~(size_t)255;
    return p;
  };
  float* hf0      = (float*)alloc((size_t)BN * HH * 4);
  float* hf1      = (float*)alloc((size_t)BN * HH * 4);
  short* hpa0     = (short*)alloc((size_t)BN * HH * 2);
  short* hpa1     = (short*)alloc((size_t)BN * HH * 2);
  short* hpa2     = (short*)alloc((size_t)BN * HH * 2);
  short* hpb0     = (short*)alloc((size_t)BN * HH * 2);
  short* hpb1     = (short*)alloc((size_t)BN * HH * 2);
  short* hpb2     = (short*)alloc((size_t)BN * HH * 2);
  char*  wpk2     = (char*)alloc((size_t)2 * KSTEPS * 12 * 3 * 64 * 16);
  float* centers  = (float*)alloc(KK * HH * 4);
  double* cnorm   = (double*)alloc(KK * 8);
  int*   codes    = (int*)alloc(BN * 4);
  int*   codeg    = (int*)alloc(BN * 4);
  uint32_t* keys  = (uint32_t*)alloc(BN * 4);
  int*   vals1    = (int*)alloc(BN * 4);
  int*   vals2    = (int*)alloc(BN * 4);
  uint32_t* sk    = (uint32_t*)alloc(4 * 4);
  double* psum    = (double*)alloc((size_t)UB * KK * HH * 8);
  float* pcnt     = (float*)alloc(UB * KK * 4);
  float* hh1      = (float*)alloc(KK * HH * 4);
  float* hh2      = (float*)alloc(KK * HH * 4);

  k_zero<<<(BN * HH + 255) / 256, 256, 0, stream>>>(hf0, BN * HH);
  k_zero<<<(BN * HH / 2 + 255) / 256, 256, 0, stream>>>((float*)hpa0, BN * HH / 2);
  k_zero<<<(BN * HH / 2 + 255) / 256, 256, 0, stream>>>((float*)hpa1, BN * HH / 2);
  k_zero<<<(BN * HH / 2 + 255) / 256, 256, 0, stream>>>((float*)hpa2, BN * HH / 2);
  k_pack2<<<(2 * KSTEPS * 12 * 3 * 64 + 255) / 256, 256, 0, stream>>>(wih, whh, wpk2);

  dim3 gru_grid(BN / 32, 2);
  for (int t = 0; t < TT; ++t) {
    if ((t & 1) == 0)
      k_gru_v2<<<gru_grid, 256, 0, stream>>>(x, wpk2, bih, bhh,
          hf0, hpa0, hpa1, hpa2, hf1, hpb0, hpb1, hpb2, t);
    else
      k_gru_v2<<<gru_grid, 256, 0, stream>>>(x, wpk2, bih, bhh,
          hf1, hpb0, hpb1, hpb2, hf0, hpa0, hpa1, hpa2, t);
  }
  float* h = hf0;  // T=128 even -> final state in hf0

  k_prng_setup<<<1, 1, 0, stream>>>(sk);
  k_genkeys<<<32, 256, 0, stream>>>(sk, 0, keys);
  k_ranksort<<<BN / RSE, 256, 0, stream>>>(keys, (const int*)nullptr, vals1);
  k_genkeys<<<32, 256, 0, stream>>>(sk, 1, keys);
  k_ranksort<<<BN / RSE, 256, 0, stream>>>(keys, vals1, vals2);

  k_init_centers<<<KK, HH, 0, stream>>>(h, vals2, centers, cnorm);
  k_assign<<<BN / 128, 128, 0, stream>>>(h, centers, cnorm, codes);
  for (int it = 0; it < KM_ITERS_N; ++it) {
    k_upd_partial<<<UB, 256, 0, stream>>>(h, codes, psum, pcnt);
    k_upd_final<<<KK, HH, 0, stream>>>(psum, pcnt, centers, cnorm);
    k_assign<<<BN / 128, 128, 0, stream>>>(h, centers, cnorm, codes);
  }
  k_upd_partial<<<UB, 256, 0, stream>>>(h, codes, psum, pcnt);
  k_upd_final<<<KK, HH, 0, stream>>>(psum, pcnt, centers, cnorm);

  k_gumbel<<<BN / 128, 128, 0, stream>>>(h, centers, codeg);
  k_gcn<<<KK, HH, 0, stream>>>(centers, g1w, g1b, hh1);
  k_gcn<<<KK, HH, 0, stream>>>(hh1, g2w, g2b, hh2);
  k_final<<<BN, HH, 0, stream>>>(h, hh2, codeg, w1w, w1b, w2w, w2b, out);
}

// Round 11
// 6332.458 us; speedup vs baseline: 2.9480x; 1.1914x over previous
//
#include <hip/hip_runtime.h>
#include <hip/hip_bf16.h>
#include <stdint.h>

#define BN 8192
#define TT 128
#define II 64
#define HH 256
#define GG 768
#define KK 12
#define KM_ITERS_N 25
#define UB 64
#define UPB (BN/UB)
#define KSTEPS 20

typedef __attribute__((ext_vector_type(8))) short bf16x8;
typedef __attribute__((ext_vector_type(16))) float f32x16;

// ---------------- threefry2x32 (JAX-exact) ----------------
__device__ __forceinline__ uint32_t rotl32(uint32_t v, int d) {
  return (v << d) | (v >> (32 - d));
}
__device__ __forceinline__ void tf2x32(uint32_t k0, uint32_t k1,
                                       uint32_t x0, uint32_t x1,
                                       uint32_t& o0, uint32_t& o1) {
  uint32_t ks2 = k0 ^ k1 ^ 0x1BD11BDAu;
  x0 += k0; x1 += k1;
#define TFR(r) { x0 += x1; x1 = rotl32(x1, r); x1 ^= x0; }
  TFR(13); TFR(15); TFR(26); TFR(6);   x0 += k1;  x1 += ks2 + 1u;
  TFR(17); TFR(29); TFR(16); TFR(24);  x0 += ks2; x1 += k0 + 2u;
  TFR(13); TFR(15); TFR(26); TFR(6);   x0 += k0;  x1 += k1 + 3u;
  TFR(17); TFR(29); TFR(16); TFR(24);  x0 += k1;  x1 += ks2 + 4u;
  TFR(13); TFR(15); TFR(26); TFR(6);   x0 += ks2; x1 += k0 + 5u;
#undef TFR
  o0 = x0; o1 = x1;
}
__device__ __forceinline__ float bits_to_unit(uint32_t bits) {
  uint32_t u = (bits >> 9) | 0x3f800000u;
  return __uint_as_float(u) - 1.0f;
}

// ---------------- bf16 3-way split helpers ----------------
__device__ __forceinline__ short f2bf(float f) {
  uint32_t u = __float_as_uint(f);
  uint32_t r = (u + 0x7fffu + ((u >> 16) & 1u)) >> 16;  // RNE
  return (short)r;
}
__device__ __forceinline__ float bf2f(short s) {
  return __uint_as_float(((uint32_t)(uint16_t)s) << 16);
}
__device__ __forceinline__ void split3(float v, short& a, short& b, short& c) {
  a = f2bf(v); float fa = bf2f(a);
  b = f2bf(v - fa); float fb = bf2f(b);
  c = f2bf(v - fa - fb);
}

// ---------------- zero ----------------
__global__ void k_zero(float* p, int n) {
  int i = blockIdx.x * blockDim.x + threadIdx.x;
  if (i < n) p[i] = 0.f;
}

// ---------------- weight pack: per-fragment contiguous 1KB blocks ----------------
// wpk2[cb(2)][ks(20)][cf(12)][p(3)][lane(64)*16B]
__global__ void k_pack2(const float* __restrict__ wih, const float* __restrict__ whh,
                        char* __restrict__ wpk2) {
  int u = blockIdx.x * 256 + threadIdx.x;
  if (u >= 2 * KSTEPS * 12 * 3 * 64) return;
  int lane = u & 63; int rest = u >> 6;
  int p = rest % 3; rest /= 3;
  int cf = rest % 12; rest /= 12;
  int ks = rest % KSTEPS; int cb = rest / KSTEPS;
  int l31 = lane & 31, khalf = lane >> 5;
  int col = cf * 32 + l31;
  int gate = col >> 7, dl = col & 127;
  int grow = gate * 256 + cb * 128 + dl;
  short s[8];
#pragma unroll
  for (int j = 0; j < 8; ++j) {
    int k = khalf * 8 + j;
    float wv = (ks < 4) ? wih[grow * II + ks * 16 + k]
                        : whh[grow * HH + (ks - 4) * 16 + k];
    short a, b, c;
    split3(wv, a, b, c);
    s[j] = (p == 0) ? a : (p == 1) ? b : c;
  }
  char* dst = wpk2 + (size_t)u * 16;
  short4 lo = {s[0], s[1], s[2], s[3]};
  short4 hi = {s[4], s[5], s[6], s[7]};
  *(short4*)dst = lo;
  *(short4*)(dst + 8) = hi;
}

// ---------------- MFMA GRU v3: barrier-free main loop ----------------
// grid (256 rb x 2 cb), 256 thr = 4 waves. Block = 32 rows x 384 packed cols.
// Full A-tile (x split + 3 h planes, all 20 ksteps) staged ONCE into LDS (60KB),
// then K-loop has NO barriers: ds_read A + global B (L2) + MFMA, compiler-pipelined.
// hold reconstructed from planes (p0+p1+p2); hf written only at final step.
#define AOFF3(ks, p, kh, row) (((((ks) * 3 + (p)) * 2 + (kh)) * 32 + (row)) * 16)

__global__ __launch_bounds__(256, 2) void k_gru_v3(
    const float* __restrict__ x, const char* __restrict__ wpk2,
    const float* __restrict__ bih, const float* __restrict__ bhh,
    const short* __restrict__ hp0, const short* __restrict__ hp1,
    const short* __restrict__ hp2,
    float* __restrict__ hf_out,
    short* __restrict__ hq0, short* __restrict__ hq1, short* __restrict__ hq2,
    int t) {
  __shared__ __align__(16) char smem[65536];  // A-tile [0,61440); epilogue gl overlays
  const int tid = threadIdx.x;
  const int rb = blockIdx.x, cb = blockIdx.y;
  const int row0 = rb * 32;
  const int l = tid & 63, l31 = l & 31, kh5 = l >> 5;
  const int w = tid >> 6;

  // ---- stage full A-tile (one pass, coalesced) ----
  {
    // x part: ks 0..3. thread: row=tid>>3, kq=tid&7 -> 8 floats at k=kq*8
    int row = tid >> 3, kq = tid & 7;
    const float* xp = x + (size_t)(row0 + row) * (TT * II) + (size_t)t * II + kq * 8;
    float4 v0 = *(const float4*)xp;
    float4 v1 = *(const float4*)(xp + 4);
    short4 a0, b0, c0, a1, b1, c1;
    split3(v0.x, a0.x, b0.x, c0.x); split3(v0.y, a0.y, b0.y, c0.y);
    split3(v0.z, a0.z, b0.z, c0.z); split3(v0.w, a0.w, b0.w, c0.w);
    split3(v1.x, a1.x, b1.x, c1.x); split3(v1.y, a1.y, b1.y, c1.y);
    split3(v1.z, a1.z, b1.z, c1.z); split3(v1.w, a1.w, b1.w, c1.w);
    int ks = kq >> 1, kh = kq & 1;
    char* d0 = smem + AOFF3(ks, 0, kh, row);
    char* d1 = smem + AOFF3(ks, 1, kh, row);
    char* d2 = smem + AOFF3(ks, 2, kh, row);
    *(short4*)d0 = a0; *(short4*)(d0 + 8) = a1;
    *(short4*)d1 = b0; *(short4*)(d1 + 8) = b1;
    *(short4*)d2 = c0; *(short4*)(d2 + 8) = c1;
    // h part: 3 planes x 32 rows x 32 ksegs of 16B; u = p*1024 + row*32 + kseg
#pragma unroll
    for (int it = 0; it < 12; ++it) {
      int u = tid + it * 256;
      int p = u >> 10, r2 = u & 1023, hrow = r2 >> 5, kseg = r2 & 31;
      const short* hp = (p == 0) ? hp0 : (p == 1) ? hp1 : hp2;
      int4 v = *(const int4*)(hp + (size_t)(row0 + hrow) * HH + kseg * 8);
      *(int4*)(smem + AOFF3(4 + (kseg >> 1), p, kseg & 1, hrow)) = v;
    }
  }
  __syncthreads();

  f32x16 aX[3], aH[3];
#pragma unroll
  for (int c = 0; c < 3; ++c) { aX[c] = (f32x16)0.f; aH[c] = (f32x16)0.f; }

#define KSTEP_BODY(ACCARR, KS)                                                     \
  {                                                                                \
    bf16x8 a0 = *(const bf16x8*)(smem + AOFF3((KS), 0, kh5, l31));                 \
    bf16x8 a1 = *(const bf16x8*)(smem + AOFF3((KS), 1, kh5, l31));                 \
    bf16x8 a2 = *(const bf16x8*)(smem + AOFF3((KS), 2, kh5, l31));                 \
    const char* bks = wpk2 + (((size_t)cb * KSTEPS + (KS)) * 12) * 3072;           \
    _Pragma("unroll")                                                              \
    for (int c = 0; c < 3; ++c) {                                                  \
      const char* bf = bks + (size_t)(w * 3 + c) * 3072 + (size_t)l * 16;          \
      bf16x8 b0 = *(const bf16x8*)(bf);                                            \
      bf16x8 b1 = *(const bf16x8*)(bf + 1024);                                     \
      bf16x8 b2 = *(const bf16x8*)(bf + 2048);                                     \
      f32x16 acc = ACCARR[c];                                                      \
      acc = __builtin_amdgcn_mfma_f32_32x32x16_bf16(a0, b0, acc, 0, 0, 0);         \
      acc = __builtin_amdgcn_mfma_f32_32x32x16_bf16(a0, b1, acc, 0, 0, 0);         \
      acc = __builtin_amdgcn_mfma_f32_32x32x16_bf16(a1, b0, acc, 0, 0, 0);         \
      acc = __builtin_amdgcn_mfma_f32_32x32x16_bf16(a0, b2, acc, 0, 0, 0);         \
      acc = __builtin_amdgcn_mfma_f32_32x32x16_bf16(a2, b0, acc, 0, 0, 0);         \
      acc = __builtin_amdgcn_mfma_f32_32x32x16_bf16(a1, b1, acc, 0, 0, 0);         \
      ACCARR[c] = acc;                                                             \
    }                                                                              \
  }

#pragma unroll
  for (int ks = 0; ks < 4; ++ks) KSTEP_BODY(aX, ks)
#pragma unroll 4
  for (int ks = 4; ks < KSTEPS; ++ks) KSTEP_BODY(aH, ks)
#undef KSTEP_BODY

  // ---- epilogue ----
  __syncthreads();  // all A ds_reads done; reuse smem as gl
  float* gl = (float*)smem;  // [32 rows][512]: R, Z, Nx, Nh
#pragma unroll
  for (int c = 0; c < 3; ++c) {
    const int gcol = w * 96 + c * 32 + l31;
#pragma unroll
    for (int j = 0; j < 16; ++j) {
      int row = (j & 3) + ((j >> 2) << 3) + kh5 * 4;
      float vx = aX[c][j], vh = aH[c][j];
      if (gcol < 256) {
        gl[row * 512 + gcol] = vx + vh;
      } else {
        gl[row * 512 + gcol] = vx;
        gl[row * 512 + gcol + 128] = vh;
      }
    }
  }
  __syncthreads();

  {
    const int dl = tid & 127, rh = tid >> 7;
    const int d = cb * 128 + dl;
    const float biR = bih[d],          bhR = bhh[d];
    const float biZ = bih[HH + d],     bhZ = bhh[HH + d];
    const float biN = bih[2 * HH + d], bhN = bhh[2 * HH + d];
    const bool lastT = (t == TT - 1);
#pragma unroll
    for (int e = 0; e < 16; ++e) {
      int row = rh * 16 + e;
      float R  = gl[row * 512 + dl];
      float Z  = gl[row * 512 + 128 + dl];
      float Nx = gl[row * 512 + 256 + dl];
      float Nh = gl[row * 512 + 384 + dl];
      size_t ob = (size_t)(row0 + row) * HH + d;
      float hold = bf2f(hp0[ob]) + bf2f(hp1[ob]) + bf2f(hp2[ob]);
      float rr = 1.f / (1.f + expf(-(R + biR + bhR)));
      float zz = 1.f / (1.f + expf(-(Z + biZ + bhZ)));
      float nn = tanhf(Nx + biN + rr * (Nh + bhN));
      float hnew = (1.f - zz) * nn + zz * hold;
      if (lastT) hf_out[ob] = hnew;
      short a, b, c2;
      split3(hnew, a, b, c2);
      hq0[ob] = a; hq1[ob] = b; hq2[ob] = c2;
    }
  }
}

// ---------------- PRNG (threefry_partitionable=True semantics) ----------------
__global__ void k_prng_setup(uint32_t* sk) {
  uint32_t k0, k1, s0, s1, t0, t1;
  tf2x32(0u, 7u, 0u, 0u, k0, k1);
  tf2x32(0u, 7u, 0u, 1u, s0, s1);
  tf2x32(k0, k1, 0u, 1u, t0, t1);
  sk[0] = s0; sk[1] = s1;
  sk[2] = t0; sk[3] = t1;
}

__global__ void k_genkeys(const uint32_t* __restrict__ sk, int which,
                          uint32_t* __restrict__ keys) {
  int i = blockIdx.x * blockDim.x + threadIdx.x;
  if (i < BN) {
    uint32_t o0, o1;
    tf2x32(sk[which * 2], sk[which * 2 + 1], 0u, (uint32_t)i, o0, o1);
    keys[i] = o0 ^ o1;
  }
}

// stable rank sort, tiled: 512 blocks x 16 elements, 16 threads/element
#define RSE 16
__global__ __launch_bounds__(256) void k_ranksort(const uint32_t* __restrict__ keys,
                                                  const int* __restrict__ vin,
                                                  int* __restrict__ vout) {
  __shared__ uint32_t skey[BN];
  __shared__ int psum[RSE][17];
  const int tid = threadIdx.x;
  const int g = tid >> 4;
  const int l = tid & 15;
  const int gi = blockIdx.x * RSE + g;
  for (int i = tid; i < BN; i += 256) skey[i] = keys[i];
  __syncthreads();
  const uint32_t ki = skey[gi];
  int rank = 0;
#pragma unroll 8
  for (int j = l; j < BN; j += 16) {
    uint32_t kj = skey[j];
    rank += (kj < ki) || (kj == ki && j < gi);
  }
  psum[g][l] = rank;
  __syncthreads();
  if (l == 0) {
    int r = 0;
#pragma unroll
    for (int tt = 0; tt < 16; ++tt) r += psum[g][tt];
    vout[r] = vin ? vin[gi] : gi;
  }
}

// ---------------- k-means (decisions in f64) ----------------
__global__ void k_init_centers(const float* __restrict__ h, const int* __restrict__ vals2,
                               float* __restrict__ centers, double* __restrict__ cnorm) {
  const int c = blockIdx.x, d = threadIdx.x;
  const int src = vals2[c];
  float v = h[(size_t)src * HH + d];
  centers[c * HH + d] = v;
  __shared__ double red[HH];
  red[d] = (double)v * (double)v;
  __syncthreads();
  for (int s = 128; s > 0; s >>= 1) {
    if (d < s) red[d] += red[d + s];
    __syncthreads();
  }
  if (d == 0) cnorm[c] = red[0];
}

__global__ __launch_bounds__(128) void k_assign(const float* __restrict__ h,
                                                const float* __restrict__ centers,
                                                const double* __restrict__ cnorm,
                                                int* __restrict__ codes) {
  __shared__ float sc[KK * HH];
  __shared__ double sn[KK];
  const int tid = threadIdx.x;
  for (int idx = tid; idx < KK * HH; idx += 128) sc[idx] = centers[idx];
  if (tid < KK) sn[tid] = cnorm[tid];
  __syncthreads();
  const int b = blockIdx.x * 128 + tid;
  const float4* hp = (const float4*)&h[(size_t)b * HH];
  double acc[KK] = {};
  double xn = 0.0;
  for (int k4 = 0; k4 < HH / 4; ++k4) {
    float4 xv = hp[k4];
    double x0 = xv.x, x1 = xv.y, x2 = xv.z, x3 = xv.w;
    xn += x0 * x0 + x1 * x1 + x2 * x2 + x3 * x3;
#pragma unroll
    for (int c = 0; c < KK; ++c) {
      float4 cv = *(const float4*)&sc[c * HH + k4 * 4];
      acc[c] += x0 * cv.x + x1 * cv.y + x2 * cv.z + x3 * cv.w;
    }
  }
  int best = 0;
  double bd = xn - 2.0 * acc[0] + sn[0];
#pragma unroll
  for (int c = 1; c < KK; ++c) {
    double d2 = xn - 2.0 * acc[c] + sn[c];
    if (d2 < bd) { bd = d2; best = c; }
  }
  codes[b] = best;
}

__global__ __launch_bounds__(256) void k_upd_partial(const float* __restrict__ h,
                                                     const int* __restrict__ codes,
                                                     double* __restrict__ psum,
                                                     float* __restrict__ pcnt) {
  __shared__ double acc[KK * HH];
  __shared__ int lc[UPB];
  const int tid = threadIdx.x;
  for (int idx = tid; idx < KK * HH; idx += 256) acc[idx] = 0.0;
  const int p0 = blockIdx.x * UPB;
  for (int idx = tid; idx < UPB; idx += 256) lc[idx] = codes[p0 + idx];
  __syncthreads();
  const int d = tid;
  for (int p = 0; p < UPB; ++p) {
    int c = lc[p];
    acc[c * HH + d] += (double)h[(size_t)(p0 + p) * HH + d];
  }
  if (tid < KK) {
    float cnt = 0.f;
    for (int p = 0; p < UPB; ++p) cnt += (lc[p] == tid) ? 1.f : 0.f;
    pcnt[blockIdx.x * KK + tid] = cnt;
  }
  for (int c = 0; c < KK; ++c)
    psum[((size_t)blockIdx.x * KK + c) * HH + d] = acc[c * HH + d];
}

__global__ void k_upd_final(const double* __restrict__ psum, const float* __restrict__ pcnt,
                            float* __restrict__ centers, double* __restrict__ cnorm) {
  const int c = blockIdx.x, d = threadIdx.x;
  double s = 0.0;
  for (int b = 0; b < UB; ++b) s += psum[((size_t)b * KK + c) * HH + d];
  float cnt = 0.f;
  for (int b = 0; b < UB; ++b) cnt += pcnt[b * KK + c];
  if (cnt <= 0.5f) cnt = 1.f;
  float v = (float)(s / (double)cnt);
  centers[c * HH + d] = v;
  __shared__ double red[HH];
  red[d] = (double)v * (double)v;
  __syncthreads();
  for (int s2 = 128; s2 > 0; s2 >>= 1) {
    if (d < s2) red[d] += red[d + s2];
    __syncthreads();
  }
  if (d == 0) cnorm[c] = red[0];
}

// ---------------- gumbel hard assignment (f64 decisions) ----------------
__global__ __launch_bounds__(128) void k_gumbel(const float* __restrict__ h,
                                                const float* __restrict__ centers,
                                                int* __restrict__ codeg) {
  __shared__ float sc[KK * HH];
  const int tid = threadIdx.x;
  for (int idx = tid; idx < KK * HH; idx += 128) sc[idx] = centers[idx];
  __syncthreads();
  const int b = blockIdx.x * 128 + tid;
  const float4* hp = (const float4*)&h[(size_t)b * HH];
  double acc[KK] = {};
  for (int k4 = 0; k4 < HH / 4; ++k4) {
    float4 xv = hp[k4];
    double x0 = xv.x, x1 = xv.y, x2 = xv.z, x3 = xv.w;
#pragma unroll
    for (int c = 0; c < KK; ++c) {
      float4 cv = *(const float4*)&sc[c * HH + k4 * 4];
      acc[c] += x0 * cv.x + x1 * cv.y + x2 * cv.z + x3 * cv.w;
    }
  }
  int best = 0;
  double bv = -1e300;
#pragma unroll
  for (int c = 0; c < KK; ++c) {
    double e = acc[c] > 0.0 ? acc[c] : 0.0;
    uint32_t j = (uint32_t)(b * KK + c);
    uint32_t o0, o1;
    tf2x32(0u, 42u, 0u, j, o0, o1);
    double U = (double)bits_to_unit(o0 ^ o1);
    double g = -log(-log(U + 1e-20) + 1e-20);
    double v = e + g;
    if (v > bv) { bv = v; best = c; }
  }
  codeg[b] = best;
}

// ---------------- GCN layer (adj = I) ----------------
__global__ void k_gcn(const float* __restrict__ in, const float* __restrict__ w,
                      const float* __restrict__ bias, float* __restrict__ out) {
  const int c = blockIdx.x, d = threadIdx.x;
  __shared__ float si[HH];
  si[d] = in[c * HH + d];
  __syncthreads();
  float acc = 0.f;
  for (int k = 0; k < HH; ++k) acc += si[k] * w[k * HH + d];
  acc += bias[d];
  out[c * HH + d] = acc > 0.f ? acc : 0.f;
}

// ---------------- final blend (f32 output) ----------------
__global__ __launch_bounds__(256) void k_final(const float* __restrict__ h,
                                               const float* __restrict__ h2,
                                               const int* __restrict__ codeg,
                                               const float* __restrict__ w1,
                                               const float* __restrict__ w1b,
                                               const float* __restrict__ w2,
                                               const float* __restrict__ w2b,
                                               float* __restrict__ out) {
  const int b = blockIdx.x, d = threadIdx.x;
  const int cg = codeg[b];
  const float cd = h2[cg * HH + d];
  const float hd = h[(size_t)b * HH + d];
  __shared__ float r1[HH], r2[HH];
  __shared__ float wan_s;
  r1[d] = cd * w1[d];
  r2[d] = hd * w2[d];
  __syncthreads();
  for (int s = 128; s > 0; s >>= 1) {
    if (d < s) { r1[d] += r1[d + s]; r2[d] += r2[d + s]; }
    __syncthreads();
  }
  if (d == 0) {
    float wa = 1.f / (1.f + expf(-(r1[0] + w1b[0])));
    float wb = 1.f / (1.f + expf(-(r2[0] + w2b[0])));
    wan_s = wa / (wa + wb);
  }
  __syncthreads();
  float wan = wan_s;
  out[(size_t)b * HH + d] = wan * cd + (1.f - wan) * hd;
}

// ---------------- launch ----------------
extern "C" void kernel_launch(void* const* d_in, const int* in_sizes, int n_in,
                              void* d_out, int out_size, void* d_ws, size_t ws_size,
                              hipStream_t stream) {
  const float* x   = (const float*)d_in[0];
  const float* wih = (const float*)d_in[1];
  const float* whh = (const float*)d_in[2];
  const float* bih = (const float*)d_in[3];
  const float* bhh = (const float*)d_in[4];
  const float* g1w = (const float*)d_in[5];
  const float* g1b = (const float*)d_in[6];
  const float* g2w = (const float*)d_in[7];
  const float* g2b = (const float*)d_in[8];
  const float* w1w = (const float*)d_in[9];
  const float* w1b = (const float*)d_in[10];
  const float* w2w = (const float*)d_in[11];
  const float* w2b = (const float*)d_in[12];
  float* out = (float*)d_out;

  char* wsb = (char*)d_ws;
  size_t off = 0;
  auto alloc = [&](size_t bytes) {
    void* p = wsb + off;
    off += (bytes + 255) & ~(size_t)255;
    return p;
  };
  float* hf0      = (float*)alloc((size_t)BN * HH * 4);
  short* hpa0     = (short*)alloc((size_t)BN * HH * 2);
  short* hpa1     = (short*)alloc((size_t)BN * HH * 2);
  short* hpa2     = (short*)alloc((size_t)BN * HH * 2);
  short* hpb0     = (short*)alloc((size_t)BN * HH * 2);
  short* hpb1     = (short*)alloc((size_t)BN * HH * 2);
  short* hpb2     = (short*)alloc((size_t)BN * HH * 2);
  char*  wpk2     = (char*)alloc((size_t)2 * KSTEPS * 12 * 3 * 64 * 16);
  float* centers  = (float*)alloc(KK * HH * 4);
  double* cnorm   = (double*)alloc(KK * 8);
  int*   codes    = (int*)alloc(BN * 4);
  int*   codeg    = (int*)alloc(BN * 4);
  uint32_t* keys  = (uint32_t*)alloc(BN * 4);
  int*   vals1    = (int*)alloc(BN * 4);
  int*   vals2    = (int*)alloc(BN * 4);
  uint32_t* sk    = (uint32_t*)alloc(4 * 4);
  double* psum    = (double*)alloc((size_t)UB * KK * HH * 8);
  float* pcnt     = (float*)alloc(UB * KK * 4);
  float* hh1      = (float*)alloc(KK * HH * 4);
  float* hh2      = (float*)alloc(KK * HH * 4);

  k_zero<<<(BN * HH / 2 + 255) / 256, 256, 0, stream>>>((float*)hpa0, BN * HH / 2);
  k_zero<<<(BN * HH / 2 + 255) / 256, 256, 0, stream>>>((float*)hpa1, BN * HH / 2);
  k_zero<<<(BN * HH / 2 + 255) / 256, 256, 0, stream>>>((float*)hpa2, BN * HH / 2);
  k_pack2<<<(2 * KSTEPS * 12 * 3 * 64 + 255) / 256, 256, 0, stream>>>(wih, whh, wpk2);

  dim3 gru_grid(BN / 32, 2);
  for (int t = 0; t < TT; ++t) {
    if ((t & 1) == 0)
      k_gru_v3<<<gru_grid, 256, 0, stream>>>(x, wpk2, bih, bhh,
          hpa0, hpa1, hpa2, hf0, hpb0, hpb1, hpb2, t);
    else
      k_gru_v3<<<gru_grid, 256, 0, stream>>>(x, wpk2, bih, bhh,
          hpb0, hpb1, hpb2, hf0, hpa0, hpa1, hpa2, t);
  }
  float* h = hf0;  // written in full at t = TT-1

  k_prng_setup<<<1, 1, 0, stream>>>(sk);
  k_genkeys<<<32, 256, 0, stream>>>(sk, 0, keys);
  k_ranksort<<<BN / RSE, 256, 0, stream>>>(keys, (const int*)nullptr, vals1);
  k_genkeys<<<32, 256, 0, stream>>>(sk, 1, keys);
  k_ranksort<<<BN / RSE, 256, 0, stream>>>(keys, vals1, vals2);

  k_init_centers<<<KK, HH, 0, stream>>>(h, vals2, centers, cnorm);
  k_assign<<<BN / 128, 128, 0, stream>>>(h, centers, cnorm, codes);
  for (int it = 0; it < KM_ITERS_N; ++it) {
    k_upd_partial<<<UB, 256, 0, stream>>>(h, codes, psum, pcnt);
    k_upd_final<<<KK, HH, 0, stream>>>(psum, pcnt, centers, cnorm);
    k_assign<<<BN / 128, 128, 0, stream>>>(h, centers, cnorm, codes);
  }
  k_upd_partial<<<UB, 256, 0, stream>>>(h, codes, psum, pcnt);
  k_upd_final<<<KK, HH, 0, stream>>>(psum, pcnt, centers, cnorm);

  k_gumbel<<<BN / 128, 128, 0, stream>>>(h, centers, codeg);
  k_gcn<<<KK, HH, 0, stream>>>(centers, g1w, g1b, hh1);
  k_gcn<<<KK, HH, 0, stream>>>(hh1, g2w, g2b, hh2);
  k_final<<<BN, HH, 0, stream>>>(h, hh2, codeg, w1w, w1b, w2w, w2b, out);
}

// Round 12
// 5813.541 us; speedup vs baseline: 3.2111x; 1.0893x over previous
//
#include <hip/hip_runtime.h>
#include <hip/hip_bf16.h>
#include <stdint.h>

#define BN 8192
#define TT 128
#define II 64
#define HH 256
#define GG 768
#define KK 12
#define KM_ITERS_N 25
#define UB 64
#define UPB (BN/UB)
#define KSTEPS 20

typedef __attribute__((ext_vector_type(8))) short bf16x8;
typedef __attribute__((ext_vector_type(16))) float f32x16;

// ---------------- threefry2x32 (JAX-exact) ----------------
__device__ __forceinline__ uint32_t rotl32(uint32_t v, int d) {
  return (v << d) | (v >> (32 - d));
}
__device__ __forceinline__ void tf2x32(uint32_t k0, uint32_t k1,
                                       uint32_t x0, uint32_t x1,
                                       uint32_t& o0, uint32_t& o1) {
  uint32_t ks2 = k0 ^ k1 ^ 0x1BD11BDAu;
  x0 += k0; x1 += k1;
#define TFR(r) { x0 += x1; x1 = rotl32(x1, r); x1 ^= x0; }
  TFR(13); TFR(15); TFR(26); TFR(6);   x0 += k1;  x1 += ks2 + 1u;
  TFR(17); TFR(29); TFR(16); TFR(24);  x0 += ks2; x1 += k0 + 2u;
  TFR(13); TFR(15); TFR(26); TFR(6);   x0 += k0;  x1 += k1 + 3u;
  TFR(17); TFR(29); TFR(16); TFR(24);  x0 += k1;  x1 += ks2 + 4u;
  TFR(13); TFR(15); TFR(26); TFR(6);   x0 += ks2; x1 += k0 + 5u;
#undef TFR
  o0 = x0; o1 = x1;
}
__device__ __forceinline__ float bits_to_unit(uint32_t bits) {
  uint32_t u = (bits >> 9) | 0x3f800000u;
  return __uint_as_float(u) - 1.0f;
}

// ---------------- bf16 3-way split helpers ----------------
__device__ __forceinline__ short f2bf(float f) {
  uint32_t u = __float_as_uint(f);
  uint32_t r = (u + 0x7fffu + ((u >> 16) & 1u)) >> 16;  // RNE
  return (short)r;
}
__device__ __forceinline__ float bf2f(short s) {
  return __uint_as_float(((uint32_t)(uint16_t)s) << 16);
}
__device__ __forceinline__ void split3(float v, short& a, short& b, short& c) {
  a = f2bf(v); float fa = bf2f(a);
  b = f2bf(v - fa); float fb = bf2f(b);
  c = f2bf(v - fa - fb);
}

// ---------------- zero ----------------
__global__ void k_zero(float* p, int n) {
  int i = blockIdx.x * blockDim.x + threadIdx.x;
  if (i < n) p[i] = 0.f;
}

// ---------------- weight pack: per-fragment contiguous 1KB blocks ----------------
// wpk2[cb(2)][ks(20)][cf(12)][p(3)][lane(64)*16B]
__global__ void k_pack2(const float* __restrict__ wih, const float* __restrict__ whh,
                        char* __restrict__ wpk2) {
  int u = blockIdx.x * 256 + threadIdx.x;
  if (u >= 2 * KSTEPS * 12 * 3 * 64) return;
  int lane = u & 63; int rest = u >> 6;
  int p = rest % 3; rest /= 3;
  int cf = rest % 12; rest /= 12;
  int ks = rest % KSTEPS; int cb = rest / KSTEPS;
  int l31 = lane & 31, khalf = lane >> 5;
  int col = cf * 32 + l31;
  int gate = col >> 7, dl = col & 127;
  int grow = gate * 256 + cb * 128 + dl;
  short s[8];
#pragma unroll
  for (int j = 0; j < 8; ++j) {
    int k = khalf * 8 + j;
    float wv = (ks < 4) ? wih[grow * II + ks * 16 + k]
                        : whh[grow * HH + (ks - 4) * 16 + k];
    short a, b, c;
    split3(wv, a, b, c);
    s[j] = (p == 0) ? a : (p == 1) ? b : c;
  }
  char* dst = wpk2 + (size_t)u * 16;
  short4 lo = {s[0], s[1], s[2], s[3]};
  short4 hi = {s[4], s[5], s[6], s[7]};
  *(short4*)dst = lo;
  *(short4*)(dst + 8) = hi;
}

// ---------------- MFMA GRU v4: 64-row blocks, barrier-free main loop ----------------
// grid (128 rb x 2 cb), 512 thr = 8 waves = 2 row-subtiles x 4 col-groups.
// Full A-tile (64 rows, x split + 3 h planes, 20 ksteps) staged once (120KB LDS);
// epilogue gl [64][512] f32 (128KB) overlays it. B direct from L2 (wpk2, 1.44MB).
#define AOFF4(ks, p, kh, row) (((((ks) * 3 + (p)) * 2 + (kh)) * 64 + (row)) * 16)

__global__ __launch_bounds__(512, 2) void k_gru_v4(
    const float* __restrict__ x, const char* __restrict__ wpk2,
    const float* __restrict__ bih, const float* __restrict__ bhh,
    const short* __restrict__ hp0, const short* __restrict__ hp1,
    const short* __restrict__ hp2,
    float* __restrict__ hf_out,
    short* __restrict__ hq0, short* __restrict__ hq1, short* __restrict__ hq2,
    int t) {
  __shared__ __align__(16) char smem[131072];  // A-tile [0,122880); gl overlays
  const int tid = threadIdx.x;
  const int rb = blockIdx.x, cb = blockIdx.y;
  const int row0 = rb * 64;
  const int l = tid & 63, l31 = l & 31, kh5 = l >> 5;
  const int w = tid >> 6;          // 0..7
  const int rt = w & 1;            // row subtile (32 rows)
  const int cw = w >> 1;           // col group (96 packed cols)
  const int arow = rt * 32 + l31;

  // ---- stage full A-tile (one pass, coalesced) ----
  {
    // x part: 64 rows x 8 k-quads; exactly 512 units
    int row = tid >> 3, kq = tid & 7;
    const float* xp = x + (size_t)(row0 + row) * (TT * II) + (size_t)t * II + kq * 8;
    float4 v0 = *(const float4*)xp;
    float4 v1 = *(const float4*)(xp + 4);
    short4 a0, b0, c0, a1, b1, c1;
    split3(v0.x, a0.x, b0.x, c0.x); split3(v0.y, a0.y, b0.y, c0.y);
    split3(v0.z, a0.z, b0.z, c0.z); split3(v0.w, a0.w, b0.w, c0.w);
    split3(v1.x, a1.x, b1.x, c1.x); split3(v1.y, a1.y, b1.y, c1.y);
    split3(v1.z, a1.z, b1.z, c1.z); split3(v1.w, a1.w, b1.w, c1.w);
    int ks = kq >> 1, kh = kq & 1;
    char* d0 = smem + AOFF4(ks, 0, kh, row);
    char* d1 = smem + AOFF4(ks, 1, kh, row);
    char* d2 = smem + AOFF4(ks, 2, kh, row);
    *(short4*)d0 = a0; *(short4*)(d0 + 8) = a1;
    *(short4*)d1 = b0; *(short4*)(d1 + 8) = b1;
    *(short4*)d2 = c0; *(short4*)(d2 + 8) = c1;
    // h part: 3 planes x 64 rows x 32 ksegs = 6144 16B-units; 512 thr x 12 iters
#pragma unroll
    for (int it = 0; it < 12; ++it) {
      int u = tid + it * 512;
      int p = u >> 11, r2 = u & 2047, hrow = r2 >> 5, kseg = r2 & 31;
      const short* hp = (p == 0) ? hp0 : (p == 1) ? hp1 : hp2;
      int4 v = *(const int4*)(hp + (size_t)(row0 + hrow) * HH + kseg * 8);
      *(int4*)(smem + AOFF4(4 + (kseg >> 1), p, kseg & 1, hrow)) = v;
    }
  }
  __syncthreads();

  f32x16 aX[3], aH[3];
#pragma unroll
  for (int c = 0; c < 3; ++c) { aX[c] = (f32x16)0.f; aH[c] = (f32x16)0.f; }

#define KSTEP_BODY(ACCARR, KS)                                                     \
  {                                                                                \
    bf16x8 a0 = *(const bf16x8*)(smem + AOFF4((KS), 0, kh5, arow));                \
    bf16x8 a1 = *(const bf16x8*)(smem + AOFF4((KS), 1, kh5, arow));                \
    bf16x8 a2 = *(const bf16x8*)(smem + AOFF4((KS), 2, kh5, arow));                \
    const char* bks = wpk2 + (((size_t)cb * KSTEPS + (KS)) * 12) * 3072;           \
    _Pragma("unroll")                                                              \
    for (int c = 0; c < 3; ++c) {                                                  \
      const char* bf = bks + (size_t)(cw * 3 + c) * 3072 + (size_t)l * 16;         \
      bf16x8 b0 = *(const bf16x8*)(bf);                                            \
      bf16x8 b1 = *(const bf16x8*)(bf + 1024);                                     \
      bf16x8 b2 = *(const bf16x8*)(bf + 2048);                                     \
      f32x16 acc = ACCARR[c];                                                      \
      acc = __builtin_amdgcn_mfma_f32_32x32x16_bf16(a0, b0, acc, 0, 0, 0);         \
      acc = __builtin_amdgcn_mfma_f32_32x32x16_bf16(a0, b1, acc, 0, 0, 0);         \
      acc = __builtin_amdgcn_mfma_f32_32x32x16_bf16(a1, b0, acc, 0, 0, 0);         \
      acc = __builtin_amdgcn_mfma_f32_32x32x16_bf16(a0, b2, acc, 0, 0, 0);         \
      acc = __builtin_amdgcn_mfma_f32_32x32x16_bf16(a2, b0, acc, 0, 0, 0);         \
      acc = __builtin_amdgcn_mfma_f32_32x32x16_bf16(a1, b1, acc, 0, 0, 0);         \
      ACCARR[c] = acc;                                                             \
    }                                                                              \
  }

#pragma unroll
  for (int ks = 0; ks < 4; ++ks) KSTEP_BODY(aX, ks)
#pragma unroll 4
  for (int ks = 4; ks < KSTEPS; ++ks) KSTEP_BODY(aH, ks)
#undef KSTEP_BODY

  // ---- epilogue ----
  __syncthreads();  // A-tile dead; reuse smem as gl
  float* gl = (float*)smem;  // [64 rows][512]: R, Z, Nx, Nh
#pragma unroll
  for (int c = 0; c < 3; ++c) {
    const int gcol = cw * 96 + c * 32 + l31;
#pragma unroll
    for (int j = 0; j < 16; ++j) {
      int row = rt * 32 + (j & 3) + ((j >> 2) << 3) + kh5 * 4;
      float vx = aX[c][j], vh = aH[c][j];
      if (gcol < 256) {
        gl[row * 512 + gcol] = vx + vh;
      } else {
        gl[row * 512 + gcol] = vx;
        gl[row * 512 + gcol + 128] = vh;
      }
    }
  }
  __syncthreads();

  {
    const int dl = tid & 127, rh = tid >> 7;   // rh 0..3 -> 16 rows each
    const int d = cb * 128 + dl;
    const float biR = bih[d],          bhR = bhh[d];
    const float biZ = bih[HH + d],     bhZ = bhh[HH + d];
    const float biN = bih[2 * HH + d], bhN = bhh[2 * HH + d];
    const bool lastT = (t == TT - 1);
#pragma unroll
    for (int e = 0; e < 16; ++e) {
      int row = rh * 16 + e;
      float R  = gl[row * 512 + dl];
      float Z  = gl[row * 512 + 128 + dl];
      float Nx = gl[row * 512 + 256 + dl];
      float Nh = gl[row * 512 + 384 + dl];
      size_t ob = (size_t)(row0 + row) * HH + d;
      float hold = bf2f(hp0[ob]) + bf2f(hp1[ob]) + bf2f(hp2[ob]);
      float rr = 1.f / (1.f + expf(-(R + biR + bhR)));
      float zz = 1.f / (1.f + expf(-(Z + biZ + bhZ)));
      float nn = tanhf(Nx + biN + rr * (Nh + bhN));
      float hnew = (1.f - zz) * nn + zz * hold;
      if (lastT) hf_out[ob] = hnew;
      short a, b, c2;
      split3(hnew, a, b, c2);
      hq0[ob] = a; hq1[ob] = b; hq2[ob] = c2;
    }
  }
}

// ---------------- PRNG (threefry_partitionable=True semantics) ----------------
__global__ void k_prng_setup(uint32_t* sk) {
  uint32_t k0, k1, s0, s1, t0, t1;
  tf2x32(0u, 7u, 0u, 0u, k0, k1);
  tf2x32(0u, 7u, 0u, 1u, s0, s1);
  tf2x32(k0, k1, 0u, 1u, t0, t1);
  sk[0] = s0; sk[1] = s1;
  sk[2] = t0; sk[3] = t1;
}

__global__ void k_genkeys(const uint32_t* __restrict__ sk, int which,
                          uint32_t* __restrict__ keys) {
  int i = blockIdx.x * blockDim.x + threadIdx.x;
  if (i < BN) {
    uint32_t o0, o1;
    tf2x32(sk[which * 2], sk[which * 2 + 1], 0u, (uint32_t)i, o0, o1);
    keys[i] = o0 ^ o1;
  }
}

// stable rank sort, tiled: 512 blocks x 16 elements, 16 threads/element
#define RSE 16
__global__ __launch_bounds__(256) void k_ranksort(const uint32_t* __restrict__ keys,
                                                  const int* __restrict__ vin,
                                                  int* __restrict__ vout) {
  __shared__ uint32_t skey[BN];
  __shared__ int psum[RSE][17];
  const int tid = threadIdx.x;
  const int g = tid >> 4;
  const int l = tid & 15;
  const int gi = blockIdx.x * RSE + g;
  for (int i = tid; i < BN; i += 256) skey[i] = keys[i];
  __syncthreads();
  const uint32_t ki = skey[gi];
  int rank = 0;
#pragma unroll 8
  for (int j = l; j < BN; j += 16) {
    uint32_t kj = skey[j];
    rank += (kj < ki) || (kj == ki && j < gi);
  }
  psum[g][l] = rank;
  __syncthreads();
  if (l == 0) {
    int r = 0;
#pragma unroll
    for (int tt = 0; tt < 16; ++tt) r += psum[g][tt];
    vout[r] = vin ? vin[gi] : gi;
  }
}

// ---------------- k-means (decisions in f64) ----------------
__global__ void k_init_centers(const float* __restrict__ h, const int* __restrict__ vals2,
                               float* __restrict__ centers, double* __restrict__ cnorm) {
  const int c = blockIdx.x, d = threadIdx.x;
  const int src = vals2[c];
  float v = h[(size_t)src * HH + d];
  centers[c * HH + d] = v;
  __shared__ double red[HH];
  red[d] = (double)v * (double)v;
  __syncthreads();
  for (int s = 128; s > 0; s >>= 1) {
    if (d < s) red[d] += red[d + s];
    __syncthreads();
  }
  if (d == 0) cnorm[c] = red[0];
}

// 2 threads per row: each sums half of K, f64 shfl_xor combine, even lane decides.
__global__ __launch_bounds__(128) void k_assign(const float* __restrict__ h,
                                                const float* __restrict__ centers,
                                                const double* __restrict__ cnorm,
                                                int* __restrict__ codes) {
  __shared__ float sc[KK * HH];
  __shared__ double sn[KK];
  const int tid = threadIdx.x;
  for (int idx = tid; idx < KK * HH; idx += 128) sc[idx] = centers[idx];
  if (tid < KK) sn[tid] = cnorm[tid];
  __syncthreads();
  const int gid = blockIdx.x * 128 + tid;
  const int b = gid >> 1, half = gid & 1;
  const float4* hp = (const float4*)&h[(size_t)b * HH + half * 128];
  const float* sch = sc + half * 128;
  double acc[KK] = {};
  double xn = 0.0;
  for (int k4 = 0; k4 < 32; ++k4) {
    float4 xv = hp[k4];
    double x0 = xv.x, x1 = xv.y, x2 = xv.z, x3 = xv.w;
    xn += x0 * x0 + x1 * x1 + x2 * x2 + x3 * x3;
#pragma unroll
    for (int c = 0; c < KK; ++c) {
      float4 cv = *(const float4*)&sch[c * HH + k4 * 4];
      acc[c] += x0 * cv.x + x1 * cv.y + x2 * cv.z + x3 * cv.w;
    }
  }
  xn += __shfl_xor(xn, 1);
#pragma unroll
  for (int c = 0; c < KK; ++c) acc[c] += __shfl_xor(acc[c], 1);
  if (half == 0) {
    int best = 0;
    double bd = xn - 2.0 * acc[0] + sn[0];
#pragma unroll
    for (int c = 1; c < KK; ++c) {
      double d2 = xn - 2.0 * acc[c] + sn[c];
      if (d2 < bd) { bd = d2; best = c; }
    }
    codes[b] = best;
  }
}

__global__ __launch_bounds__(256) void k_upd_partial(const float* __restrict__ h,
                                                     const int* __restrict__ codes,
                                                     double* __restrict__ psum,
                                                     float* __restrict__ pcnt) {
  __shared__ double acc[KK * HH];
  __shared__ int lc[UPB];
  const int tid = threadIdx.x;
  for (int idx = tid; idx < KK * HH; idx += 256) acc[idx] = 0.0;
  const int p0 = blockIdx.x * UPB;
  for (int idx = tid; idx < UPB; idx += 256) lc[idx] = codes[p0 + idx];
  __syncthreads();
  const int d = tid;
  for (int p = 0; p < UPB; ++p) {
    int c = lc[p];
    acc[c * HH + d] += (double)h[(size_t)(p0 + p) * HH + d];
  }
  if (tid < KK) {
    float cnt = 0.f;
    for (int p = 0; p < UPB; ++p) cnt += (lc[p] == tid) ? 1.f : 0.f;
    pcnt[blockIdx.x * KK + tid] = cnt;
  }
  for (int c = 0; c < KK; ++c)
    psum[((size_t)blockIdx.x * KK + c) * HH + d] = acc[c * HH + d];
}

__global__ void k_upd_final(const double* __restrict__ psum, const float* __restrict__ pcnt,
                            float* __restrict__ centers, double* __restrict__ cnorm) {
  const int c = blockIdx.x, d = threadIdx.x;
  double s = 0.0;
  for (int b = 0; b < UB; ++b) s += psum[((size_t)b * KK + c) * HH + d];
  float cnt = 0.f;
  for (int b = 0; b < UB; ++b) cnt += pcnt[b * KK + c];
  if (cnt <= 0.5f) cnt = 1.f;
  float v = (float)(s / (double)cnt);
  centers[c * HH + d] = v;
  __shared__ double red[HH];
  red[d] = (double)v * (double)v;
  __syncthreads();
  for (int s2 = 128; s2 > 0; s2 >>= 1) {
    if (d < s2) red[d] += red[d + s2];
    __syncthreads();
  }
  if (d == 0) cnorm[c] = red[0];
}

// ---------------- gumbel hard assignment (f64 decisions) ----------------
__global__ __launch_bounds__(128) void k_gumbel(const float* __restrict__ h,
                                                const float* __restrict__ centers,
                                                int* __restrict__ codeg) {
  __shared__ float sc[KK * HH];
  const int tid = threadIdx.x;
  for (int idx = tid; idx < KK * HH; idx += 128) sc[idx] = centers[idx];
  __syncthreads();
  const int b = blockIdx.x * 128 + tid;
  const float4* hp = (const float4*)&h[(size_t)b * HH];
  double acc[KK] = {};
  for (int k4 = 0; k4 < HH / 4; ++k4) {
    float4 xv = hp[k4];
    double x0 = xv.x, x1 = xv.y, x2 = xv.z, x3 = xv.w;
#pragma unroll
    for (int c = 0; c < KK; ++c) {
      float4 cv = *(const float4*)&sc[c * HH + k4 * 4];
      acc[c] += x0 * cv.x + x1 * cv.y + x2 * cv.z + x3 * cv.w;
    }
  }
  int best = 0;
  double bv = -1e300;
#pragma unroll
  for (int c = 0; c < KK; ++c) {
    double e = acc[c] > 0.0 ? acc[c] : 0.0;
    uint32_t j = (uint32_t)(b * KK + c);
    uint32_t o0, o1;
    tf2x32(0u, 42u, 0u, j, o0, o1);
    double U = (double)bits_to_unit(o0 ^ o1);
    double g = -log(-log(U + 1e-20) + 1e-20);
    double v = e + g;
    if (v > bv) { bv = v; best = c; }
  }
  codeg[b] = best;
}

// ---------------- GCN layer (adj = I) ----------------
__global__ void k_gcn(const float* __restrict__ in, const float* __restrict__ w,
                      const float* __restrict__ bias, float* __restrict__ out) {
  const int c = blockIdx.x, d = threadIdx.x;
  __shared__ float si[HH];
  si[d] = in[c * HH + d];
  __syncthreads();
  float acc = 0.f;
  for (int k = 0; k < HH; ++k) acc += si[k] * w[k * HH + d];
  acc += bias[d];
  out[c * HH + d] = acc > 0.f ? acc : 0.f;
}

// ---------------- final blend (f32 output) ----------------
__global__ __launch_bounds__(256) void k_final(const float* __restrict__ h,
                                               const float* __restrict__ h2,
                                               const int* __restrict__ codeg,
                                               const float* __restrict__ w1,
                                               const float* __restrict__ w1b,
                                               const float* __restrict__ w2,
                                               const float* __restrict__ w2b,
                                               float* __restrict__ out) {
  const int b = blockIdx.x, d = threadIdx.x;
  const int cg = codeg[b];
  const float cd = h2[cg * HH + d];
  const float hd = h[(size_t)b * HH + d];
  __shared__ float r1[HH], r2[HH];
  __shared__ float wan_s;
  r1[d] = cd * w1[d];
  r2[d] = hd * w2[d];
  __syncthreads();
  for (int s = 128; s > 0; s >>= 1) {
    if (d < s) { r1[d] += r1[d + s]; r2[d] += r2[d + s]; }
    __syncthreads();
  }
  if (d == 0) {
    float wa = 1.f / (1.f + expf(-(r1[0] + w1b[0])));
    float wb = 1.f / (1.f + expf(-(r2[0] + w2b[0])));
    wan_s = wa / (wa + wb);
  }
  __syncthreads();
  float wan = wan_s;
  out[(size_t)b * HH + d] = wan * cd + (1.f - wan) * hd;
}

// ---------------- launch ----------------
extern "C" void kernel_launch(void* const* d_in, const int* in_sizes, int n_in,
                              void* d_out, int out_size, void* d_ws, size_t ws_size,
                              hipStream_t stream) {
  const float* x   = (const float*)d_in[0];
  const float* wih = (const float*)d_in[1];
  const float* whh = (const float*)d_in[2];
  const float* bih = (const float*)d_in[3];
  const float* bhh = (const float*)d_in[4];
  const float* g1w = (const float*)d_in[5];
  const float* g1b = (const float*)d_in[6];
  const float* g2w = (const float*)d_in[7];
  const float* g2b = (const float*)d_in[8];
  const float* w1w = (const float*)d_in[9];
  const float* w1b = (const float*)d_in[10];
  const float* w2w = (const float*)d_in[11];
  const float* w2b = (const float*)d_in[12];
  float* out = (float*)d_out;

  char* wsb = (char*)d_ws;
  size_t off = 0;
  auto alloc = [&](size_t bytes) {
    void* p = wsb + off;
    off += (bytes + 255) & ~(size_t)255;
    return p;
  };
  float* hf0      = (float*)alloc((size_t)BN * HH * 4);
  short* hpa0     = (short*)alloc((size_t)BN * HH * 2);
  short* hpa1     = (short*)alloc((size_t)BN * HH * 2);
  short* hpa2     = (short*)alloc((size_t)BN * HH * 2);
  short* hpb0     = (short*)alloc((size_t)BN * HH * 2);
  short* hpb1     = (short*)alloc((size_t)BN * HH * 2);
  short* hpb2     = (short*)alloc((size_t)BN * HH * 2);
  char*  wpk2     = (char*)alloc((size_t)2 * KSTEPS * 12 * 3 * 64 * 16);
  float* centers  = (float*)alloc(KK * HH * 4);
  double* cnorm   = (double*)alloc(KK * 8);
  int*   codes    = (int*)alloc(BN * 4);
  int*   codeg    = (int*)alloc(BN * 4);
  uint32_t* keys  = (uint32_t*)alloc(BN * 4);
  int*   vals1    = (int*)alloc(BN * 4);
  int*   vals2    = (int*)alloc(BN * 4);
  uint32_t* sk    = (uint32_t*)alloc(4 * 4);
  double* psum    = (double*)alloc((size_t)UB * KK * HH * 8);
  float* pcnt     = (float*)alloc(UB * KK * 4);
  float* hh1      = (float*)alloc(KK * HH * 4);
  float* hh2      = (float*)alloc(KK * HH * 4);

  k_zero<<<(BN * HH / 2 + 255) / 256, 256, 0, stream>>>((float*)hpa0, BN * HH / 2);
  k_zero<<<(BN * HH / 2 + 255) / 256, 256, 0, stream>>>((float*)hpa1, BN * HH / 2);
  k_zero<<<(BN * HH / 2 + 255) / 256, 256, 0, stream>>>((float*)hpa2, BN * HH / 2);
  k_pack2<<<(2 * KSTEPS * 12 * 3 * 64 + 255) / 256, 256, 0, stream>>>(wih, whh, wpk2);

  dim3 gru_grid(BN / 64, 2);
  for (int t = 0; t < TT; ++t) {
    if ((t & 1) == 0)
      k_gru_v4<<<gru_grid, 512, 0, stream>>>(x, wpk2, bih, bhh,
          hpa0, hpa1, hpa2, hf0, hpb0, hpb1, hpb2, t);
    else
      k_gru_v4<<<gru_grid, 512, 0, stream>>>(x, wpk2, bih, bhh,
          hpb0, hpb1, hpb2, hf0, hpa0, hpa1, hpa2, t);
  }
  float* h = hf0;  // written in full at t = TT-1

  k_prng_setup<<<1, 1, 0, stream>>>(sk);
  k_genkeys<<<32, 256, 0, stream>>>(sk, 0, keys);
  k_ranksort<<<BN / RSE, 256, 0, stream>>>(keys, (const int*)nullptr, vals1);
  k_genkeys<<<32, 256, 0, stream>>>(sk, 1, keys);
  k_ranksort<<<BN / RSE, 256, 0, stream>>>(keys, vals1, vals2);

  k_init_centers<<<KK, HH, 0, stream>>>(h, vals2, centers, cnorm);
  k_assign<<<BN * 2 / 128, 128, 0, stream>>>(h, centers, cnorm, codes);
  for (int it = 0; it < KM_ITERS_N; ++it) {
    k_upd_partial<<<UB, 256, 0, stream>>>(h, codes, psum, pcnt);
    k_upd_final<<<KK, HH, 0, stream>>>(psum, pcnt, centers, cnorm);
    k_assign<<<BN * 2 / 128, 128, 0, stream>>>(h, centers, cnorm, codes);
  }
  k_upd_partial<<<UB, 256, 0, stream>>>(h, codes, psum, pcnt);
  k_upd_final<<<KK, HH, 0, stream>>>(psum, pcnt, centers, cnorm);

  k_gumbel<<<BN / 128, 128, 0, stream>>>(h, centers, codeg);
  k_gcn<<<KK, HH, 0, stream>>>(centers, g1w, g1b, hh1);
  k_gcn<<<KK, HH, 0, stream>>>(hh1, g2w, g2b, hh2);
  k_final<<<BN, HH, 0, stream>>>(h, hh2, codeg, w1w, w1b, w2w, w2b, out);
}

// Round 13
// 4685.539 us; speedup vs baseline: 3.9841x; 1.2407x over previous
//
#include <hip/hip_runtime.h>
#include <hip/hip_bf16.h>
#include <stdint.h>

#define BN 8192
#define TT 128
#define II 64
#define HH 256
#define GG 768
#define KK 12
#define KM_ITERS_N 25
#define UB 64
#define UPB (BN/UB)
#define KSTEPS 20

typedef __attribute__((ext_vector_type(8))) short bf16x8;
typedef __attribute__((ext_vector_type(16))) float f32x16;

// ---------------- threefry2x32 (JAX-exact) ----------------
__device__ __forceinline__ uint32_t rotl32(uint32_t v, int d) {
  return (v << d) | (v >> (32 - d));
}
__device__ __forceinline__ void tf2x32(uint32_t k0, uint32_t k1,
                                       uint32_t x0, uint32_t x1,
                                       uint32_t& o0, uint32_t& o1) {
  uint32_t ks2 = k0 ^ k1 ^ 0x1BD11BDAu;
  x0 += k0; x1 += k1;
#define TFR(r) { x0 += x1; x1 = rotl32(x1, r); x1 ^= x0; }
  TFR(13); TFR(15); TFR(26); TFR(6);   x0 += k1;  x1 += ks2 + 1u;
  TFR(17); TFR(29); TFR(16); TFR(24);  x0 += ks2; x1 += k0 + 2u;
  TFR(13); TFR(15); TFR(26); TFR(6);   x0 += k0;  x1 += k1 + 3u;
  TFR(17); TFR(29); TFR(16); TFR(24);  x0 += k1;  x1 += ks2 + 4u;
  TFR(13); TFR(15); TFR(26); TFR(6);   x0 += ks2; x1 += k0 + 5u;
#undef TFR
  o0 = x0; o1 = x1;
}
__device__ __forceinline__ float bits_to_unit(uint32_t bits) {
  uint32_t u = (bits >> 9) | 0x3f800000u;
  return __uint_as_float(u) - 1.0f;
}

// ---------------- bf16 3-way split helpers ----------------
__device__ __forceinline__ short f2bf(float f) {
  uint32_t u = __float_as_uint(f);
  uint32_t r = (u + 0x7fffu + ((u >> 16) & 1u)) >> 16;  // RNE
  return (short)r;
}
__device__ __forceinline__ float bf2f(short s) {
  return __uint_as_float(((uint32_t)(uint16_t)s) << 16);
}
__device__ __forceinline__ void split3(float v, short& a, short& b, short& c) {
  a = f2bf(v); float fa = bf2f(a);
  b = f2bf(v - fa); float fb = bf2f(b);
  c = f2bf(v - fa - fb);
}

// ---------------- weight pack: [ks 20][cf 24][p 3][lane 64]*16B ----------------
// col = cf*32 + (lane&31) in [0,768): gate = col>>8, d = col&255; k = (lane>>5)*8 + j
__global__ void k_pack3(const float* __restrict__ wih, const float* __restrict__ whh,
                        char* __restrict__ wpk3) {
  int u = blockIdx.x * 256 + threadIdx.x;
  if (u >= KSTEPS * 24 * 3 * 64) return;
  int lane = u & 63; int rest = u >> 6;
  int p = rest % 3; rest /= 3;
  int cf = rest % 24; int ks = rest / 24;
  int l31 = lane & 31, khalf = lane >> 5;
  int col = cf * 32 + l31;
  int gate = col >> 8, d = col & 255;
  int grow = gate * 256 + d;
  short s[8];
#pragma unroll
  for (int j = 0; j < 8; ++j) {
    int k = khalf * 8 + j;
    float wv = (ks < 4) ? wih[grow * II + ks * 16 + k]
                        : whh[grow * HH + (ks - 4) * 16 + k];
    short a, b, c;
    split3(wv, a, b, c);
    s[j] = (p == 0) ? a : (p == 1) ? b : c;
  }
  char* dst = wpk3 + (size_t)u * 16;
  short4 lo = {s[0], s[1], s[2], s[3]};
  short4 hi = {s[4], s[5], s[6], s[7]};
  *(short4*)dst = lo;
  *(short4*)(dst + 8) = hi;
}

// ---------------- persistent MFMA GRU v5 ----------------
// grid 256 x 512 thr (8 waves). Block = 32 rows x FULL 768 packed cols, loops all T.
// h planes live in LDS [hks 16][p 3][kh 2][row 32]*16B (48 KB); x staged per step
// at +49152 ([xks 4][p][kh][row]*16B, 12 KB). Wave w owns frags {w, 8+w, 16+w} =
// R,Z,N at d = w*32+(l&31), so gates are lane-local (no transpose buffer).
__global__ __launch_bounds__(512, 2) void k_gru_v5(
    const float* __restrict__ x, const char* __restrict__ wpk3,
    const float* __restrict__ bih, const float* __restrict__ bhh,
    float* __restrict__ hf_out) {
  __shared__ __align__(16) char smem[61440];
  const int tid = threadIdx.x;
  const int w = tid >> 6;
  const int l = tid & 63, l31 = l & 31, kh5 = l >> 5;
  const int row0 = blockIdx.x * 32;

  {  // zero h planes (48 KB = 3072 int4)
    int4 z = {0, 0, 0, 0};
    int4* s4 = (int4*)smem;
#pragma unroll
    for (int i = 0; i < 6; ++i) s4[tid + i * 512] = z;
  }
  const int d = w * 32 + l31;
  const float biR = bih[d],          bhR = bhh[d];
  const float biZ = bih[HH + d],     bhZ = bhh[HH + d];
  const float biN = bih[2 * HH + d], bhN = bhh[2 * HH + d];
  // lane-constant h-LDS byte offsets (row 0) per plane
  const int hk = d >> 4, hkh = (d >> 3) & 1, hby = (d & 7) * 2;
  const int hb0 = (hk * 3 + 0) * 1024 + hkh * 512 + hby;
  const int hb1 = (hk * 3 + 1) * 1024 + hkh * 512 + hby;
  const int hb2 = (hk * 3 + 2) * 1024 + hkh * 512 + hby;
  __syncthreads();

  for (int t = 0; t < TT; ++t) {
    // ---- stage x_t (split3 into 3 planes, MFMA-A layout) ----
    if (tid < 256) {
      int row = tid >> 3, ko = tid & 7;
      const float* xp = x + (size_t)(row0 + row) * (TT * II) + (size_t)t * II + ko * 8;
      float4 v0 = *(const float4*)xp;
      float4 v1 = *(const float4*)(xp + 4);
      short4 a0, b0, c0, a1, b1, c1;
      split3(v0.x, a0.x, b0.x, c0.x); split3(v0.y, a0.y, b0.y, c0.y);
      split3(v0.z, a0.z, b0.z, c0.z); split3(v0.w, a0.w, b0.w, c0.w);
      split3(v1.x, a1.x, b1.x, c1.x); split3(v1.y, a1.y, b1.y, c1.y);
      split3(v1.z, a1.z, b1.z, c1.z); split3(v1.w, a1.w, b1.w, c1.w);
      int xks = ko >> 1, xkh = ko & 1;
      char* base = smem + 49152 + xks * 3072 + xkh * 512 + row * 16;
      *(short4*)(base) = a0;        *(short4*)(base + 8) = a1;
      *(short4*)(base + 1024) = b0; *(short4*)(base + 1032) = b1;
      *(short4*)(base + 2048) = c0; *(short4*)(base + 2056) = c1;
    }
    __syncthreads();

    f32x16 aR = (f32x16)0.f, aZ = (f32x16)0.f, aNx = (f32x16)0.f, aNh = (f32x16)0.f;

#define FRAG6(ACC, CF, KS)                                                         \
    {                                                                              \
      const char* bf = wpk3 + (((size_t)(KS) * 24 + (CF)) * 3) * 1024 +            \
                       (size_t)l * 16;                                             \
      bf16x8 b0 = *(const bf16x8*)(bf);                                            \
      bf16x8 b1 = *(const bf16x8*)(bf + 1024);                                     \
      bf16x8 b2 = *(const bf16x8*)(bf + 2048);                                     \
      ACC = __builtin_amdgcn_mfma_f32_32x32x16_bf16(a0, b0, ACC, 0, 0, 0);         \
      ACC = __builtin_amdgcn_mfma_f32_32x32x16_bf16(a0, b1, ACC, 0, 0, 0);         \
      ACC = __builtin_amdgcn_mfma_f32_32x32x16_bf16(a1, b0, ACC, 0, 0, 0);         \
      ACC = __builtin_amdgcn_mfma_f32_32x32x16_bf16(a0, b2, ACC, 0, 0, 0);         \
      ACC = __builtin_amdgcn_mfma_f32_32x32x16_bf16(a2, b0, ACC, 0, 0, 0);         \
      ACC = __builtin_amdgcn_mfma_f32_32x32x16_bf16(a1, b1, ACC, 0, 0, 0);         \
    }

#pragma unroll
    for (int ks = 0; ks < 4; ++ks) {
      const char* ab = smem + 49152 + ks * 3072 + kh5 * 512 + l31 * 16;
      bf16x8 a0 = *(const bf16x8*)(ab);
      bf16x8 a1 = *(const bf16x8*)(ab + 1024);
      bf16x8 a2 = *(const bf16x8*)(ab + 2048);
      FRAG6(aR, w, ks) FRAG6(aZ, 8 + w, ks) FRAG6(aNx, 16 + w, ks)
    }
#pragma unroll 4
    for (int ks = 4; ks < KSTEPS; ++ks) {
      const char* ab = smem + (ks - 4) * 3072 + kh5 * 512 + l31 * 16;
      bf16x8 a0 = *(const bf16x8*)(ab);
      bf16x8 a1 = *(const bf16x8*)(ab + 1024);
      bf16x8 a2 = *(const bf16x8*)(ab + 2048);
      FRAG6(aR, w, ks) FRAG6(aZ, 8 + w, ks) FRAG6(aNh, 16 + w, ks)
    }
#undef FRAG6
    __syncthreads();  // all h/x ds_reads done before h planes are overwritten

    // ---- epilogue: lane-local gates, in-place LDS h update ----
    const bool lastT = (t == TT - 1);
#pragma unroll
    for (int j = 0; j < 16; ++j) {
      int row = (j & 3) + ((j >> 2) << 3) + kh5 * 4;
      float rr = 1.f / (1.f + expf(-(aR[j] + biR + bhR)));
      float zz = 1.f / (1.f + expf(-(aZ[j] + biZ + bhZ)));
      float nn = tanhf(aNx[j] + biN + rr * (aNh[j] + bhN));
      char* p0a = smem + hb0 + row * 16;
      char* p1a = smem + hb1 + row * 16;
      char* p2a = smem + hb2 + row * 16;
      float hold = bf2f(*(short*)p0a) + bf2f(*(short*)p1a) + bf2f(*(short*)p2a);
      float hnew = (1.f - zz) * nn + zz * hold;
      short sa, sb, sc;
      split3(hnew, sa, sb, sc);
      *(short*)p0a = sa; *(short*)p1a = sb; *(short*)p2a = sc;
      if (lastT) hf_out[(size_t)(row0 + row) * HH + d] = hnew;
    }
    __syncthreads();  // h planes committed before next step's k-loop
  }
}

// ---------------- PRNG (threefry_partitionable=True semantics) ----------------
__global__ void k_prng_setup(uint32_t* sk) {
  uint32_t k0, k1, s0, s1, t0, t1;
  tf2x32(0u, 7u, 0u, 0u, k0, k1);
  tf2x32(0u, 7u, 0u, 1u, s0, s1);
  tf2x32(k0, k1, 0u, 1u, t0, t1);
  sk[0] = s0; sk[1] = s1;
  sk[2] = t0; sk[3] = t1;
}

__global__ void k_genkeys(const uint32_t* __restrict__ sk, int which,
                          uint32_t* __restrict__ keys) {
  int i = blockIdx.x * blockDim.x + threadIdx.x;
  if (i < BN) {
    uint32_t o0, o1;
    tf2x32(sk[which * 2], sk[which * 2 + 1], 0u, (uint32_t)i, o0, o1);
    keys[i] = o0 ^ o1;
  }
}

// stable rank sort, tiled: 512 blocks x 16 elements, 16 threads/element
#define RSE 16
__global__ __launch_bounds__(256) void k_ranksort(const uint32_t* __restrict__ keys,
                                                  const int* __restrict__ vin,
                                                  int* __restrict__ vout) {
  __shared__ uint32_t skey[BN];
  __shared__ int psum[RSE][17];
  const int tid = threadIdx.x;
  const int g = tid >> 4;
  const int l = tid & 15;
  const int gi = blockIdx.x * RSE + g;
  for (int i = tid; i < BN; i += 256) skey[i] = keys[i];
  __syncthreads();
  const uint32_t ki = skey[gi];
  int rank = 0;
#pragma unroll 8
  for (int j = l; j < BN; j += 16) {
    uint32_t kj = skey[j];
    rank += (kj < ki) || (kj == ki && j < gi);
  }
  psum[g][l] = rank;
  __syncthreads();
  if (l == 0) {
    int r = 0;
#pragma unroll
    for (int tt = 0; tt < 16; ++tt) r += psum[g][tt];
    vout[r] = vin ? vin[gi] : gi;
  }
}

// ---------------- k-means (decisions in f64) ----------------
__global__ void k_init_centers(const float* __restrict__ h, const int* __restrict__ vals2,
                               float* __restrict__ centers, double* __restrict__ cnorm) {
  const int c = blockIdx.x, d = threadIdx.x;
  const int src = vals2[c];
  float v = h[(size_t)src * HH + d];
  centers[c * HH + d] = v;
  __shared__ double red[HH];
  red[d] = (double)v * (double)v;
  __syncthreads();
  for (int s = 128; s > 0; s >>= 1) {
    if (d < s) red[d] += red[d + s];
    __syncthreads();
  }
  if (d == 0) cnorm[c] = red[0];
}

// 2 threads per row: each sums half of K, f64 shfl_xor combine, even lane decides.
__global__ __launch_bounds__(128) void k_assign(const float* __restrict__ h,
                                                const float* __restrict__ centers,
                                                const double* __restrict__ cnorm,
                                                int* __restrict__ codes) {
  __shared__ float sc[KK * HH];
  __shared__ double sn[KK];
  const int tid = threadIdx.x;
  for (int idx = tid; idx < KK * HH; idx += 128) sc[idx] = centers[idx];
  if (tid < KK) sn[tid] = cnorm[tid];
  __syncthreads();
  const int gid = blockIdx.x * 128 + tid;
  const int b = gid >> 1, half = gid & 1;
  const float4* hp = (const float4*)&h[(size_t)b * HH + half * 128];
  const float* sch = sc + half * 128;
  double acc[KK] = {};
  double xn = 0.0;
  for (int k4 = 0; k4 < 32; ++k4) {
    float4 xv = hp[k4];
    double x0 = xv.x, x1 = xv.y, x2 = xv.z, x3 = xv.w;
    xn += x0 * x0 + x1 * x1 + x2 * x2 + x3 * x3;
#pragma unroll
    for (int c = 0; c < KK; ++c) {
      float4 cv = *(const float4*)&sch[c * HH + k4 * 4];
      acc[c] += x0 * cv.x + x1 * cv.y + x2 * cv.z + x3 * cv.w;
    }
  }
  xn += __shfl_xor(xn, 1);
#pragma unroll
  for (int c = 0; c < KK; ++c) acc[c] += __shfl_xor(acc[c], 1);
  if (half == 0) {
    int best = 0;
    double bd = xn - 2.0 * acc[0] + sn[0];
#pragma unroll
    for (int c = 1; c < KK; ++c) {
      double d2 = xn - 2.0 * acc[c] + sn[c];
      if (d2 < bd) { bd = d2; best = c; }
    }
    codes[b] = best;
  }
}

__global__ __launch_bounds__(256) void k_upd_partial(const float* __restrict__ h,
                                                     const int* __restrict__ codes,
                                                     double* __restrict__ psum,
                                                     float* __restrict__ pcnt) {
  __shared__ double acc[KK * HH];
  __shared__ int lc[UPB];
  const int tid = threadIdx.x;
  for (int idx = tid; idx < KK * HH; idx += 256) acc[idx] = 0.0;
  const int p0 = blockIdx.x * UPB;
  for (int idx = tid; idx < UPB; idx += 256) lc[idx] = codes[p0 + idx];
  __syncthreads();
  const int d = tid;
  for (int p = 0; p < UPB; ++p) {
    int c = lc[p];
    acc[c * HH + d] += (double)h[(size_t)(p0 + p) * HH + d];
  }
  if (tid < KK) {
    float cnt = 0.f;
    for (int p = 0; p < UPB; ++p) cnt += (lc[p] == tid) ? 1.f : 0.f;
    pcnt[blockIdx.x * KK + tid] = cnt;
  }
  for (int c = 0; c < KK; ++c)
    psum[((size_t)blockIdx.x * KK + c) * HH + d] = acc[c * HH + d];
}

__global__ void k_upd_final(const double* __restrict__ psum, const float* __restrict__ pcnt,
                            float* __restrict__ centers, double* __restrict__ cnorm) {
  const int c = blockIdx.x, d = threadIdx.x;
  double s = 0.0;
  for (int b = 0; b < UB; ++b) s += psum[((size_t)b * KK + c) * HH + d];
  float cnt = 0.f;
  for (int b = 0; b < UB; ++b) cnt += pcnt[b * KK + c];
  if (cnt <= 0.5f) cnt = 1.f;
  float v = (float)(s / (double)cnt);
  centers[c * HH + d] = v;
  __shared__ double red[HH];
  red[d] = (double)v * (double)v;
  __syncthreads();
  for (int s2 = 128; s2 > 0; s2 >>= 1) {
    if (d < s2) red[d] += red[d + s2];
    __syncthreads();
  }
  if (d == 0) cnorm[c] = red[0];
}

// ---------------- gumbel hard assignment (f64 decisions) ----------------
__global__ __launch_bounds__(128) void k_gumbel(const float* __restrict__ h,
                                                const float* __restrict__ centers,
                                                int* __restrict__ codeg) {
  __shared__ float sc[KK * HH];
  const int tid = threadIdx.x;
  for (int idx = tid; idx < KK * HH; idx += 128) sc[idx] = centers[idx];
  __syncthreads();
  const int b = blockIdx.x * 128 + tid;
  const float4* hp = (const float4*)&h[(size_t)b * HH];
  double acc[KK] = {};
  for (int k4 = 0; k4 < HH / 4; ++k4) {
    float4 xv = hp[k4];
    double x0 = xv.x, x1 = xv.y, x2 = xv.z, x3 = xv.w;
#pragma unroll
    for (int c = 0; c < KK; ++c) {
      float4 cv = *(const float4*)&sc[c * HH + k4 * 4];
      acc[c] += x0 * cv.x + x1 * cv.y + x2 * cv.z + x3 * cv.w;
    }
  }
  int best = 0;
  double bv = -1e300;
#pragma unroll
  for (int c = 0; c < KK; ++c) {
    double e = acc[c] > 0.0 ? acc[c] : 0.0;
    uint32_t j = (uint32_t)(b * KK + c);
    uint32_t o0, o1;
    tf2x32(0u, 42u, 0u, j, o0, o1);
    double U = (double)bits_to_unit(o0 ^ o1);
    double g = -log(-log(U + 1e-20) + 1e-20);
    double v = e + g;
    if (v > bv) { bv = v; best = c; }
  }
  codeg[b] = best;
}

// ---------------- GCN layer (adj = I) ----------------
__global__ void k_gcn(const float* __restrict__ in, const float* __restrict__ w,
                      const float* __restrict__ bias, float* __restrict__ out) {
  const int c = blockIdx.x, d = threadIdx.x;
  __shared__ float si[HH];
  si[d] = in[c * HH + d];
  __syncthreads();
  float acc = 0.f;
  for (int k = 0; k < HH; ++k) acc += si[k] * w[k * HH + d];
  acc += bias[d];
  out[c * HH + d] = acc > 0.f ? acc : 0.f;
}

// ---------------- final blend (f32 output) ----------------
__global__ __launch_bounds__(256) void k_final(const float* __restrict__ h,
                                               const float* __restrict__ h2,
                                               const int* __restrict__ codeg,
                                               const float* __restrict__ w1,
                                               const float* __restrict__ w1b,
                                               const float* __restrict__ w2,
                                               const float* __restrict__ w2b,
                                               float* __restrict__ out) {
  const int b = blockIdx.x, d = threadIdx.x;
  const int cg = codeg[b];
  const float cd = h2[cg * HH + d];
  const float hd = h[(size_t)b * HH + d];
  __shared__ float r1[HH], r2[HH];
  __shared__ float wan_s;
  r1[d] = cd * w1[d];
  r2[d] = hd * w2[d];
  __syncthreads();
  for (int s = 128; s > 0; s >>= 1) {
    if (d < s) { r1[d] += r1[d + s]; r2[d] += r2[d + s]; }
    __syncthreads();
  }
  if (d == 0) {
    float wa = 1.f / (1.f + expf(-(r1[0] + w1b[0])));
    float wb = 1.f / (1.f + expf(-(r2[0] + w2b[0])));
    wan_s = wa / (wa + wb);
  }
  __syncthreads();
  float wan = wan_s;
  out[(size_t)b * HH + d] = wan * cd + (1.f - wan) * hd;
}

// ---------------- launch ----------------
extern "C" void kernel_launch(void* const* d_in, const int* in_sizes, int n_in,
                              void* d_out, int out_size, void* d_ws, size_t ws_size,
                              hipStream_t stream) {
  const float* x   = (const float*)d_in[0];
  const float* wih = (const float*)d_in[1];
  const float* whh = (const float*)d_in[2];
  const float* bih = (const float*)d_in[3];
  const float* bhh = (const float*)d_in[4];
  const float* g1w = (const float*)d_in[5];
  const float* g1b = (const float*)d_in[6];
  const float* g2w = (const float*)d_in[7];
  const float* g2b = (const float*)d_in[8];
  const float* w1w = (const float*)d_in[9];
  const float* w1b = (const float*)d_in[10];
  const float* w2w = (const float*)d_in[11];
  const float* w2b = (const float*)d_in[12];
  float* out = (float*)d_out;

  char* wsb = (char*)d_ws;
  size_t off = 0;
  auto alloc = [&](size_t bytes) {
    void* p = wsb + off;
    off += (bytes + 255) & ~(size_t)255;
    return p;
  };
  float* hf0      = (float*)alloc((size_t)BN * HH * 4);
  char*  wpk3     = (char*)alloc((size_t)KSTEPS * 24 * 3 * 64 * 16);
  float* centers  = (float*)alloc(KK * HH * 4);
  double* cnorm   = (double*)alloc(KK * 8);
  int*   codes    = (int*)alloc(BN * 4);
  int*   codeg    = (int*)alloc(BN * 4);
  uint32_t* keys  = (uint32_t*)alloc(BN * 4);
  int*   vals1    = (int*)alloc(BN * 4);
  int*   vals2    = (int*)alloc(BN * 4);
  uint32_t* sk    = (uint32_t*)alloc(4 * 4);
  double* psum    = (double*)alloc((size_t)UB * KK * HH * 8);
  float* pcnt     = (float*)alloc(UB * KK * 4);
  float* hh1      = (float*)alloc(KK * HH * 4);
  float* hh2      = (float*)alloc(KK * HH * 4);

  k_pack3<<<(KSTEPS * 24 * 3 * 64 + 255) / 256, 256, 0, stream>>>(wih, whh, wpk3);
  k_gru_v5<<<BN / 32, 512, 0, stream>>>(x, wpk3, bih, bhh, hf0);
  float* h = hf0;

  k_prng_setup<<<1, 1, 0, stream>>>(sk);
  k_genkeys<<<32, 256, 0, stream>>>(sk, 0, keys);
  k_ranksort<<<BN / RSE, 256, 0, stream>>>(keys, (const int*)nullptr, vals1);
  k_genkeys<<<32, 256, 0, stream>>>(sk, 1, keys);
  k_ranksort<<<BN / RSE, 256, 0, stream>>>(keys, vals1, vals2);

  k_init_centers<<<KK, HH, 0, stream>>>(h, vals2, centers, cnorm);
  k_assign<<<BN * 2 / 128, 128, 0, stream>>>(h, centers, cnorm, codes);
  for (int it = 0; it < KM_ITERS_N; ++it) {
    k_upd_partial<<<UB, 256, 0, stream>>>(h, codes, psum, pcnt);
    k_upd_final<<<KK, HH, 0, stream>>>(psum, pcnt, centers, cnorm);
    k_assign<<<BN * 2 / 128, 128, 0, stream>>>(h, centers, cnorm, codes);
  }
  k_upd_partial<<<UB, 256, 0, stream>>>(h, codes, psum, pcnt);
  k_upd_final<<<KK, HH, 0, stream>>>(psum, pcnt, centers, cnorm);

  k_gumbel<<<BN / 128, 128, 0, stream>>>(h, centers, codeg);
  k_gcn<<<KK, HH, 0, stream>>>(centers, g1w, g1b, hh1);
  k_gcn<<<KK, HH, 0, stream>>>(hh1, g2w, g2b, hh2);
  k_final<<<BN, HH, 0, stream>>>(h, hh2, codeg, w1w, w1b, w2w, w2b, out);
}

// Round 14
// 4663.659 us; speedup vs baseline: 4.0028x; 1.0047x over previous
//
#include <hip/hip_runtime.h>
#include <hip/hip_bf16.h>
#include <stdint.h>

#define BN 8192
#define TT 128
#define II 64
#define HH 256
#define GG 768
#define KK 12
#define KM_ITERS_N 25
#define UB 64
#define UPB (BN/UB)
#define KSTEPS 20

typedef __attribute__((ext_vector_type(8))) short bf16x8;
typedef __attribute__((ext_vector_type(16))) float f32x16;

// ---------------- threefry2x32 (JAX-exact) ----------------
__device__ __forceinline__ uint32_t rotl32(uint32_t v, int d) {
  return (v << d) | (v >> (32 - d));
}
__device__ __forceinline__ void tf2x32(uint32_t k0, uint32_t k1,
                                       uint32_t x0, uint32_t x1,
                                       uint32_t& o0, uint32_t& o1) {
  uint32_t ks2 = k0 ^ k1 ^ 0x1BD11BDAu;
  x0 += k0; x1 += k1;
#define TFR(r) { x0 += x1; x1 = rotl32(x1, r); x1 ^= x0; }
  TFR(13); TFR(15); TFR(26); TFR(6);   x0 += k1;  x1 += ks2 + 1u;
  TFR(17); TFR(29); TFR(16); TFR(24);  x0 += ks2; x1 += k0 + 2u;
  TFR(13); TFR(15); TFR(26); TFR(6);   x0 += k0;  x1 += k1 + 3u;
  TFR(17); TFR(29); TFR(16); TFR(24);  x0 += k1;  x1 += ks2 + 4u;
  TFR(13); TFR(15); TFR(26); TFR(6);   x0 += ks2; x1 += k0 + 5u;
#undef TFR
  o0 = x0; o1 = x1;
}
__device__ __forceinline__ float bits_to_unit(uint32_t bits) {
  uint32_t u = (bits >> 9) | 0x3f800000u;
  return __uint_as_float(u) - 1.0f;
}

// ---------------- bf16 3-way split helpers ----------------
__device__ __forceinline__ short f2bf(float f) {
  uint32_t u = __float_as_uint(f);
  uint32_t r = (u + 0x7fffu + ((u >> 16) & 1u)) >> 16;  // RNE
  return (short)r;
}
__device__ __forceinline__ float bf2f(short s) {
  return __uint_as_float(((uint32_t)(uint16_t)s) << 16);
}
__device__ __forceinline__ void split3(float v, short& a, short& b, short& c) {
  a = f2bf(v); float fa = bf2f(a);
  b = f2bf(v - fa); float fb = bf2f(b);
  c = f2bf(v - fa - fb);
}

// ---------------- fast gates (exp2-based; v_exp_f32 native) ----------------
__device__ __forceinline__ float sigm_f(float u) {
  return 1.f / (1.f + exp2f(u * -1.4426950408889634f));
}
__device__ __forceinline__ float tanh_f(float u) {
  return 1.f - 2.f / (1.f + exp2f(u * 2.8853900817779268f));
}

// ---------------- weight pack: [ks 20][cf 24][p 3][lane 64]*16B ----------------
__global__ void k_pack3(const float* __restrict__ wih, const float* __restrict__ whh,
                        char* __restrict__ wpk3) {
  int u = blockIdx.x * 256 + threadIdx.x;
  if (u >= KSTEPS * 24 * 3 * 64) return;
  int lane = u & 63; int rest = u >> 6;
  int p = rest % 3; rest /= 3;
  int cf = rest % 24; int ks = rest / 24;
  int l31 = lane & 31, khalf = lane >> 5;
  int col = cf * 32 + l31;
  int gate = col >> 8, d = col & 255;
  int grow = gate * 256 + d;
  short s[8];
#pragma unroll
  for (int j = 0; j < 8; ++j) {
    int k = khalf * 8 + j;
    float wv = (ks < 4) ? wih[grow * II + ks * 16 + k]
                        : whh[grow * HH + (ks - 4) * 16 + k];
    short a, b, c;
    split3(wv, a, b, c);
    s[j] = (p == 0) ? a : (p == 1) ? b : c;
  }
  char* dst = wpk3 + (size_t)u * 16;
  short4 lo = {s[0], s[1], s[2], s[3]};
  short4 hi = {s[4], s[5], s[6], s[7]};
  *(short4*)dst = lo;
  *(short4*)(dst + 8) = hi;
}

// ---------------- persistent MFMA GRU v6 ----------------
// grid 256 x 512 thr. LDS: h planes [0,49152), x planes [49152,61440),
// glh f32 h-shadow [61440, 61440+33280) = [32][260] padded.
// Phase1: lane-local gates, glh in-place (conflict-free f32).
// Phase2: glh -> 3 bf16 planes, contiguous 16B stores (conflict-free).
#define GLHS 260

__global__ __launch_bounds__(512, 2) void k_gru_v6(
    const float* __restrict__ x, const char* __restrict__ wpk3,
    const float* __restrict__ bih, const float* __restrict__ bhh,
    float* __restrict__ hf_out) {
  __shared__ __align__(16) char smem[94720];
  float* glh = (float*)(smem + 61440);
  const int tid = threadIdx.x;
  const int w = tid >> 6;
  const int l = tid & 63, l31 = l & 31, kh5 = l >> 5;
  const int row0 = blockIdx.x * 32;

  {  // zero h planes (48 KB) + glh
    int4 z = {0, 0, 0, 0};
    int4* s4 = (int4*)smem;
#pragma unroll
    for (int i = 0; i < 6; ++i) s4[tid + i * 512] = z;
    for (int i = tid; i < 32 * GLHS; i += 512) glh[i] = 0.f;
  }
  const int d = w * 32 + l31;
  const float biR = bih[d],          bhR = bhh[d];
  const float biZ = bih[HH + d],     bhZ = bhh[HH + d];
  const float biN = bih[2 * HH + d], bhN = bhh[2 * HH + d];

  // x prefetch: thread owns (xrow, 4 k's at xko4*4)
  const int xrow = tid & 31, xko4 = tid >> 5;
  const float* xbase = x + (size_t)(row0 + xrow) * (TT * II) + xko4 * 4;
  float4 xreg = *(const float4*)xbase;
  __syncthreads();

  for (int t = 0; t < TT; ++t) {
    // ---- stage x planes from register ----
    {
      short4 sa, sb, sc;
      split3(xreg.x, sa.x, sb.x, sc.x);
      split3(xreg.y, sa.y, sb.y, sc.y);
      split3(xreg.z, sa.z, sb.z, sc.z);
      split3(xreg.w, sa.w, sb.w, sc.w);
      int xks = xko4 >> 2, xkh = (xko4 >> 1) & 1, sub = (xko4 & 1) * 8;
      char* base = smem + 49152 + xks * 3072 + xkh * 512 + xrow * 16 + sub;
      *(short4*)(base) = sa;
      *(short4*)(base + 1024) = sb;
      *(short4*)(base + 2048) = sc;
    }
    if (t + 1 < TT) xreg = *(const float4*)(xbase + (size_t)(t + 1) * II);
    __syncthreads();

    f32x16 aR = (f32x16)0.f, aZ = (f32x16)0.f, aNx = (f32x16)0.f, aNh = (f32x16)0.f;

#define FRAG6(ACC, CF, KS)                                                         \
    {                                                                              \
      const char* bf = wpk3 + (((size_t)(KS) * 24 + (CF)) * 3) * 1024 +            \
                       (size_t)l * 16;                                             \
      bf16x8 b0 = *(const bf16x8*)(bf);                                            \
      bf16x8 b1 = *(const bf16x8*)(bf + 1024);                                     \
      bf16x8 b2 = *(const bf16x8*)(bf + 2048);                                     \
      ACC = __builtin_amdgcn_mfma_f32_32x32x16_bf16(a0, b0, ACC, 0, 0, 0);         \
      ACC = __builtin_amdgcn_mfma_f32_32x32x16_bf16(a0, b1, ACC, 0, 0, 0);         \
      ACC = __builtin_amdgcn_mfma_f32_32x32x16_bf16(a1, b0, ACC, 0, 0, 0);         \
      ACC = __builtin_amdgcn_mfma_f32_32x32x16_bf16(a0, b2, ACC, 0, 0, 0);         \
      ACC = __builtin_amdgcn_mfma_f32_32x32x16_bf16(a2, b0, ACC, 0, 0, 0);         \
      ACC = __builtin_amdgcn_mfma_f32_32x32x16_bf16(a1, b1, ACC, 0, 0, 0);         \
    }

#pragma unroll
    for (int ks = 0; ks < 4; ++ks) {
      const char* ab = smem + 49152 + ks * 3072 + kh5 * 512 + l31 * 16;
      bf16x8 a0 = *(const bf16x8*)(ab);
      bf16x8 a1 = *(const bf16x8*)(ab + 1024);
      bf16x8 a2 = *(const bf16x8*)(ab + 2048);
      FRAG6(aR, w, ks) FRAG6(aZ, 8 + w, ks) FRAG6(aNx, 16 + w, ks)
    }
#pragma unroll 8
    for (int ks = 4; ks < KSTEPS; ++ks) {
      const char* ab = smem + (ks - 4) * 3072 + kh5 * 512 + l31 * 16;
      bf16x8 a0 = *(const bf16x8*)(ab);
      bf16x8 a1 = *(const bf16x8*)(ab + 1024);
      bf16x8 a2 = *(const bf16x8*)(ab + 2048);
      FRAG6(aR, w, ks) FRAG6(aZ, 8 + w, ks) FRAG6(aNh, 16 + w, ks)
    }
#undef FRAG6
    __syncthreads();  // all h/x ds_reads done

    // ---- phase 1: lane-local gates, glh in-place ----
    const bool lastT = (t == TT - 1);
#pragma unroll
    for (int j = 0; j < 16; ++j) {
      int row = (j & 3) + ((j >> 2) << 3) + kh5 * 4;
      float hold = glh[row * GLHS + d];
      float rr = sigm_f(aR[j] + biR + bhR);
      float zz = sigm_f(aZ[j] + biZ + bhZ);
      float nn = tanh_f(aNx[j] + biN + rr * (aNh[j] + bhN));
      float hnew = (1.f - zz) * nn + zz * hold;
      glh[row * GLHS + d] = hnew;
      if (lastT) hf_out[(size_t)(row0 + row) * HH + d] = hnew;
    }
    __syncthreads();

    // ---- phase 2: glh -> bf16 planes (skip on last step) ----
    if (!lastT) {
#pragma unroll
      for (int i = 0; i < 2; ++i) {
        int u = tid + i * 512;
        int prow = u & 31, kunit = u >> 5;
        const float* gsrc = glh + prow * GLHS + kunit * 8;
        float4 v0 = *(const float4*)(gsrc);
        float4 v1 = *(const float4*)(gsrc + 4);
        short4 a0, b0, c0, a1, b1, c1;
        split3(v0.x, a0.x, b0.x, c0.x); split3(v0.y, a0.y, b0.y, c0.y);
        split3(v0.z, a0.z, b0.z, c0.z); split3(v0.w, a0.w, b0.w, c0.w);
        split3(v1.x, a1.x, b1.x, c1.x); split3(v1.y, a1.y, b1.y, c1.y);
        split3(v1.z, a1.z, b1.z, c1.z); split3(v1.w, a1.w, b1.w, c1.w);
        int hks = kunit >> 1, kh = kunit & 1;
        char* basep = smem + hks * 3072 + kh * 512 + prow * 16;
        *(short4*)(basep) = a0;        *(short4*)(basep + 8) = a1;
        *(short4*)(basep + 1024) = b0; *(short4*)(basep + 1032) = b1;
        *(short4*)(basep + 2048) = c0; *(short4*)(basep + 2056) = c1;
      }
    }
    // next stage's barrier orders phase-2 plane writes before k-loop reads
  }
}

// ---------------- PRNG (threefry_partitionable=True semantics) ----------------
__global__ void k_prng_setup(uint32_t* sk) {
  uint32_t k0, k1, s0, s1, t0, t1;
  tf2x32(0u, 7u, 0u, 0u, k0, k1);
  tf2x32(0u, 7u, 0u, 1u, s0, s1);
  tf2x32(k0, k1, 0u, 1u, t0, t1);
  sk[0] = s0; sk[1] = s1;
  sk[2] = t0; sk[3] = t1;
}

__global__ void k_genkeys(const uint32_t* __restrict__ sk, int which,
                          uint32_t* __restrict__ keys) {
  int i = blockIdx.x * blockDim.x + threadIdx.x;
  if (i < BN) {
    uint32_t o0, o1;
    tf2x32(sk[which * 2], sk[which * 2 + 1], 0u, (uint32_t)i, o0, o1);
    keys[i] = o0 ^ o1;
  }
}

// stable rank sort, tiled: 512 blocks x 16 elements, 16 threads/element
#define RSE 16
__global__ __launch_bounds__(256) void k_ranksort(const uint32_t* __restrict__ keys,
                                                  const int* __restrict__ vin,
                                                  int* __restrict__ vout) {
  __shared__ uint32_t skey[BN];
  __shared__ int psum[RSE][17];
  const int tid = threadIdx.x;
  const int g = tid >> 4;
  const int l = tid & 15;
  const int gi = blockIdx.x * RSE + g;
  for (int i = tid; i < BN; i += 256) skey[i] = keys[i];
  __syncthreads();
  const uint32_t ki = skey[gi];
  int rank = 0;
#pragma unroll 8
  for (int j = l; j < BN; j += 16) {
    uint32_t kj = skey[j];
    rank += (kj < ki) || (kj == ki && j < gi);
  }
  psum[g][l] = rank;
  __syncthreads();
  if (l == 0) {
    int r = 0;
#pragma unroll
    for (int tt = 0; tt < 16; ++tt) r += psum[g][tt];
    vout[r] = vin ? vin[gi] : gi;
  }
}

// ---------------- k-means (decisions in f64) ----------------
__global__ void k_init_centers(const float* __restrict__ h, const int* __restrict__ vals2,
                               float* __restrict__ centers, double* __restrict__ cnorm) {
  const int c = blockIdx.x, d = threadIdx.x;
  const int src = vals2[c];
  float v = h[(size_t)src * HH + d];
  centers[c * HH + d] = v;
  __shared__ double red[HH];
  red[d] = (double)v * (double)v;
  __syncthreads();
  for (int s = 128; s > 0; s >>= 1) {
    if (d < s) red[d] += red[d + s];
    __syncthreads();
  }
  if (d == 0) cnorm[c] = red[0];
}

// 2 threads per row: each sums half of K, f64 shfl_xor combine, even lane decides.
__global__ __launch_bounds__(128) void k_assign(const float* __restrict__ h,
                                                const float* __restrict__ centers,
                                                const double* __restrict__ cnorm,
                                                int* __restrict__ codes) {
  __shared__ float sc[KK * HH];
  __shared__ double sn[KK];
  const int tid = threadIdx.x;
  for (int idx = tid; idx < KK * HH; idx += 128) sc[idx] = centers[idx];
  if (tid < KK) sn[tid] = cnorm[tid];
  __syncthreads();
  const int gid = blockIdx.x * 128 + tid;
  const int b = gid >> 1, half = gid & 1;
  const float4* hp = (const float4*)&h[(size_t)b * HH + half * 128];
  const float* sch = sc + half * 128;
  double acc[KK] = {};
  double xn = 0.0;
  for (int k4 = 0; k4 < 32; ++k4) {
    float4 xv = hp[k4];
    double x0 = xv.x, x1 = xv.y, x2 = xv.z, x3 = xv.w;
    xn += x0 * x0 + x1 * x1 + x2 * x2 + x3 * x3;
#pragma unroll
    for (int c = 0; c < KK; ++c) {
      float4 cv = *(const float4*)&sch[c * HH + k4 * 4];
      acc[c] += x0 * cv.x + x1 * cv.y + x2 * cv.z + x3 * cv.w;
    }
  }
  xn += __shfl_xor(xn, 1);
#pragma unroll
  for (int c = 0; c < KK; ++c) acc[c] += __shfl_xor(acc[c], 1);
  if (half == 0) {
    int best = 0;
    double bd = xn - 2.0 * acc[0] + sn[0];
#pragma unroll
    for (int c = 1; c < KK; ++c) {
      double d2 = xn - 2.0 * acc[c] + sn[c];
      if (d2 < bd) { bd = d2; best = c; }
    }
    codes[b] = best;
  }
}

__global__ __launch_bounds__(256) void k_upd_partial(const float* __restrict__ h,
                                                     const int* __restrict__ codes,
                                                     double* __restrict__ psum,
                                                     float* __restrict__ pcnt) {
  __shared__ double acc[KK * HH];
  __shared__ int lc[UPB];
  const int tid = threadIdx.x;
  for (int idx = tid; idx < KK * HH; idx += 256) acc[idx] = 0.0;
  const int p0 = blockIdx.x * UPB;
  for (int idx = tid; idx < UPB; idx += 256) lc[idx] = codes[p0 + idx];
  __syncthreads();
  const int d = tid;
  for (int p = 0; p < UPB; ++p) {
    int c = lc[p];
    acc[c * HH + d] += (double)h[(size_t)(p0 + p) * HH + d];
  }
  if (tid < KK) {
    float cnt = 0.f;
    for (int p = 0; p < UPB; ++p) cnt += (lc[p] == tid) ? 1.f : 0.f;
    pcnt[blockIdx.x * KK + tid] = cnt;
  }
  for (int c = 0; c < KK; ++c)
    psum[((size_t)blockIdx.x * KK + c) * HH + d] = acc[c * HH + d];
}

__global__ void k_upd_final(const double* __restrict__ psum, const float* __restrict__ pcnt,
                            float* __restrict__ centers, double* __restrict__ cnorm) {
  const int c = blockIdx.x, d = threadIdx.x;
  double s = 0.0;
  for (int b = 0; b < UB; ++b) s += psum[((size_t)b * KK + c) * HH + d];
  float cnt = 0.f;
  for (int b = 0; b < UB; ++b) cnt += pcnt[b * KK + c];
  if (cnt <= 0.5f) cnt = 1.f;
  float v = (float)(s / (double)cnt);
  centers[c * HH + d] = v;
  __shared__ double red[HH];
  red[d] = (double)v * (double)v;
  __syncthreads();
  for (int s2 = 128; s2 > 0; s2 >>= 1) {
    if (d < s2) red[d] += red[d + s2];
    __syncthreads();
  }
  if (d == 0) cnorm[c] = red[0];
}

// ---------------- gumbel hard assignment (f64 decisions) ----------------
__global__ __launch_bounds__(128) void k_gumbel(const float* __restrict__ h,
                                                const float* __restrict__ centers,
                                                int* __restrict__ codeg) {
  __shared__ float sc[KK * HH];
  const int tid = threadIdx.x;
  for (int idx = tid; idx < KK * HH; idx += 128) sc[idx] = centers[idx];
  __syncthreads();
  const int b = blockIdx.x * 128 + tid;
  const float4* hp = (const float4*)&h[(size_t)b * HH];
  double acc[KK] = {};
  for (int k4 = 0; k4 < HH / 4; ++k4) {
    float4 xv = hp[k4];
    double x0 = xv.x, x1 = xv.y, x2 = xv.z, x3 = xv.w;
#pragma unroll
    for (int c = 0; c < KK; ++c) {
      float4 cv = *(const float4*)&sc[c * HH + k4 * 4];
      acc[c] += x0 * cv.x + x1 * cv.y + x2 * cv.z + x3 * cv.w;
    }
  }
  int best = 0;
  double bv = -1e300;
#pragma unroll
  for (int c = 0; c < KK; ++c) {
    double e = acc[c] > 0.0 ? acc[c] : 0.0;
    uint32_t j = (uint32_t)(b * KK + c);
    uint32_t o0, o1;
    tf2x32(0u, 42u, 0u, j, o0, o1);
    double U = (double)bits_to_unit(o0 ^ o1);
    double g = -log(-log(U + 1e-20) + 1e-20);
    double v = e + g;
    if (v > bv) { bv = v; best = c; }
  }
  codeg[b] = best;
}

// ---------------- GCN layer (adj = I) ----------------
__global__ void k_gcn(const float* __restrict__ in, const float* __restrict__ w,
                      const float* __restrict__ bias, float* __restrict__ out) {
  const int c = blockIdx.x, d = threadIdx.x;
  __shared__ float si[HH];
  si[d] = in[c * HH + d];
  __syncthreads();
  float acc = 0.f;
  for (int k = 0; k < HH; ++k) acc += si[k] * w[k * HH + d];
  acc += bias[d];
  out[c * HH + d] = acc > 0.f ? acc : 0.f;
}

// ---------------- final blend (f32 output) ----------------
__global__ __launch_bounds__(256) void k_final(const float* __restrict__ h,
                                               const float* __restrict__ h2,
                                               const int* __restrict__ codeg,
                                               const float* __restrict__ w1,
                                               const float* __restrict__ w1b,
                                               const float* __restrict__ w2,
                                               const float* __restrict__ w2b,
                                               float* __restrict__ out) {
  const int b = blockIdx.x, d = threadIdx.x;
  const int cg = codeg[b];
  const float cd = h2[cg * HH + d];
  const float hd = h[(size_t)b * HH + d];
  __shared__ float r1[HH], r2[HH];
  __shared__ float wan_s;
  r1[d] = cd * w1[d];
  r2[d] = hd * w2[d];
  __syncthreads();
  for (int s = 128; s > 0; s >>= 1) {
    if (d < s) { r1[d] += r1[d + s]; r2[d] += r2[d + s]; }
    __syncthreads();
  }
  if (d == 0) {
    float wa = 1.f / (1.f + expf(-(r1[0] + w1b[0])));
    float wb = 1.f / (1.f + expf(-(r2[0] + w2b[0])));
    wan_s = wa / (wa + wb);
  }
  __syncthreads();
  float wan = wan_s;
  out[(size_t)b * HH + d] = wan * cd + (1.f - wan) * hd;
}

// ---------------- launch ----------------
extern "C" void kernel_launch(void* const* d_in, const int* in_sizes, int n_in,
                              void* d_out, int out_size, void* d_ws, size_t ws_size,
                              hipStream_t stream) {
  const float* x   = (const float*)d_in[0];
  const float* wih = (const float*)d_in[1];
  const float* whh = (const float*)d_in[2];
  const float* bih = (const float*)d_in[3];
  const float* bhh = (const float*)d_in[4];
  const float* g1w = (const float*)d_in[5];
  const float* g1b = (const float*)d_in[6];
  const float* g2w = (const float*)d_in[7];
  const float* g2b = (const float*)d_in[8];
  const float* w1w = (const float*)d_in[9];
  const float* w1b = (const float*)d_in[10];
  const float* w2w = (const float*)d_in[11];
  const float* w2b = (const float*)d_in[12];
  float* out = (float*)d_out;

  char* wsb = (char*)d_ws;
  size_t off = 0;
  auto alloc = [&](size_t bytes) {
    void* p = wsb + off;
    off += (bytes + 255) & ~(size_t)255;
    return p;
  };
  float* hf0      = (float*)alloc((size_t)BN * HH * 4);
  char*  wpk3     = (char*)alloc((size_t)KSTEPS * 24 * 3 * 64 * 16);
  float* centers  = (float*)alloc(KK * HH * 4);
  double* cnorm   = (double*)alloc(KK * 8);
  int*   codes    = (int*)alloc(BN * 4);
  int*   codeg    = (int*)alloc(BN * 4);
  uint32_t* keys  = (uint32_t*)alloc(BN * 4);
  int*   vals1    = (int*)alloc(BN * 4);
  int*   vals2    = (int*)alloc(BN * 4);
  uint32_t* sk    = (uint32_t*)alloc(4 * 4);
  double* psum    = (double*)alloc((size_t)UB * KK * HH * 8);
  float* pcnt     = (float*)alloc(UB * KK * 4);
  float* hh1      = (float*)alloc(KK * HH * 4);
  float* hh2      = (float*)alloc(KK * HH * 4);

  k_pack3<<<(KSTEPS * 24 * 3 * 64 + 255) / 256, 256, 0, stream>>>(wih, whh, wpk3);
  k_gru_v6<<<BN / 32, 512, 0, stream>>>(x, wpk3, bih, bhh, hf0);
  float* h = hf0;

  k_prng_setup<<<1, 1, 0, stream>>>(sk);
  k_genkeys<<<32, 256, 0, stream>>>(sk, 0, keys);
  k_ranksort<<<BN / RSE, 256, 0, stream>>>(keys, (const int*)nullptr, vals1);
  k_genkeys<<<32, 256, 0, stream>>>(sk, 1, keys);
  k_ranksort<<<BN / RSE, 256, 0, stream>>>(keys, vals1, vals2);

  k_init_centers<<<KK, HH, 0, stream>>>(h, vals2, centers, cnorm);
  k_assign<<<BN * 2 / 128, 128, 0, stream>>>(h, centers, cnorm, codes);
  for (int it = 0; it < KM_ITERS_N; ++it) {
    k_upd_partial<<<UB, 256, 0, stream>>>(h, codes, psum, pcnt);
    k_upd_final<<<KK, HH, 0, stream>>>(psum, pcnt, centers, cnorm);
    k_assign<<<BN * 2 / 128, 128, 0, stream>>>(h, centers, cnorm, codes);
  }
  k_upd_partial<<<UB, 256, 0, stream>>>(h, codes, psum, pcnt);
  k_upd_final<<<KK, HH, 0, stream>>>(psum, pcnt, centers, cnorm);

  k_gumbel<<<BN / 128, 128, 0, stream>>>(h, centers, codeg);
  k_gcn<<<KK, HH, 0, stream>>>(centers, g1w, g1b, hh1);
  k_gcn<<<KK, HH, 0, stream>>>(hh1, g2w, g2b, hh2);
  k_final<<<BN, HH, 0, stream>>>(h, hh2, codeg, w1w, w1b, w2w, w2b, out);
}